// Round 4
// baseline (10399.668 us; speedup 1.0000x reference)
//
#include <hip/hip_runtime.h>
#include <math.h>

// ---------------- constants ----------------
#define C_DIM 128
#define HGT 192
#define WID 192
#define NB 4
#define WFD 97   // 192/2+1

// table offsets (floats)
#define T_COSW 0
#define T_SINW 18624
#define T_COSH 37248
#define T_SINH 74112
#define T_ICOS 110976
#define T_ISIN 129600
#define T_BIAS 148224
// total 164608 < 262144 reserved

__device__ __forceinline__ float gelu_f(float v){
  return 0.5f*v*(1.0f + erff(v*0.70710678118654752440f));
}

// ---------------- table build ----------------
__global__ __launch_bounds__(256) void build_tables(float* __restrict__ tab, const float* __restrict__ rpb){
  int idx = blockIdx.x*256 + threadIdx.x;
  const double TP = 6.283185307179586476925286766559;
  if (idx < 18624){ // rfft-W matrices: [wf=97][w=192]
    int i = idx/192, j = idx%192;
    double th = TP*((double)(i*j))/192.0;
    tab[T_COSW+idx] = (float)cos(th);
    tab[T_SINW+idx] = (float)sin(th);
    return;
  }
  idx -= 18624;
  if (idx < 36864){ // fft-H matrices: [hf=192][h=192]
    int i = idx/192, j = idx%192;
    double th = TP*((double)(i*j))/192.0;
    tab[T_COSH+idx] = (float)cos(th);
    tab[T_SINH+idx] = (float)sin(th);
    return;
  }
  idx -= 36864;
  if (idx < 18624){ // irfft-W matrices: [w=192][k=97], alpha/(H*W) folded
    int w = idx/97, k = idx%97;
    double th = TP*((double)(k*w))/192.0;
    double a = (k==0 || k==96) ? 1.0 : 2.0;
    double sc = a/36864.0;
    tab[T_ICOS+idx] = (float)(sc*cos(th));
    tab[T_ISIN+idx] = (float)(sc*sin(th));
    return;
  }
  idx -= 18624;
  if (idx < 16384){ // attn bias: [head][n][m]
    int head = idx>>12, n = (idx>>6)&63, m = idx&63;
    int dh = n/16 - m/16 + 3;
    int dw = (n&15) - (m&15) + 15;
    tab[T_BIAS+idx] = rpb[(dh*31+dw)*4 + head];
  }
}

// ---------------- pos depthwise conv (BCHW in -> BHWC out, + residual) ----------------
__global__ __launch_bounds__(256) void posconv_kernel(const float* __restrict__ x, const float* __restrict__ pw,
                               const float* __restrict__ pb, float* __restrict__ xt){
  __shared__ float tile[64*129];
  int w0 = blockIdx.x*64; int h = blockIdx.y; int b = blockIdx.z;
  int tid = threadIdx.x;
  int wl = tid & 63; int cg = tid >> 6;
  int w = w0 + wl;
  for (int ci = 0; ci < 32; ++ci){
    int c = cg*32 + ci;
    const float* xp = x + (size_t)(b*C_DIM + c)*HGT*WID;
    float acc = xp[(size_t)h*WID + w] + pb[c];
    #pragma unroll
    for (int ky=0; ky<3; ky++){
      int hh = h + ky - 1;
      if (hh < 0 || hh >= HGT) continue;
      #pragma unroll
      for (int kx=0; kx<3; kx++){
        int ww = w + kx - 1;
        if (ww < 0 || ww >= WID) continue;
        acc += pw[c*27 + 9 + ky*3 + kx] * xp[(size_t)hh*WID + ww];
      }
    }
    tile[wl*129 + c] = acc;
  }
  __syncthreads();
  for (int r=0; r<32; r++){
    int e = tid + 256*r; int c = e & 127; int wl2 = e >> 7;
    xt[((size_t)(b*HGT+h)*WID + w0 + wl2)*C_DIM + c] = tile[wl2*129 + c];
  }
}

// ---------------- LN row stats (mean, rstd) ----------------
__global__ __launch_bounds__(256) void ln_stats_kernel(const float* __restrict__ src, float* __restrict__ stats){
  int wave = threadIdx.x >> 6; int lane = threadIdx.x & 63;
  size_t p = (size_t)blockIdx.x*4 + wave;
  const float* s = src + p*C_DIM;
  float v0 = s[lane], v1 = s[lane+64];
  float sum = v0 + v1;
  #pragma unroll
  for (int o=1; o<64; o<<=1) sum += __shfl_xor(sum, o, 64);
  float m = sum * (1.0f/128.0f);
  float d0 = v0-m, d1 = v1-m;
  float vs = d0*d0 + d1*d1;
  #pragma unroll
  for (int o=1; o<64; o<<=1) vs += __shfl_xor(vs, o, 64);
  float rstd = rsqrtf(vs*(1.0f/128.0f) + 1e-5f);
  if (lane==0){ stats[2*p] = m; stats[2*p+1] = rstd; }
}

// ---------------- generic fp32 GEMM ----------------
template<int ACT, bool ADD, bool SPLIT, bool LNA>
__global__ __launch_bounds__(256) void gemm_kernel(const float* __restrict__ A1, const float* __restrict__ A2,
                            const float* __restrict__ Wm, const float* __restrict__ bias,
                            float* __restrict__ dst, int K, int N, int lda,
                            const float* __restrict__ stats, const float* __restrict__ lng,
                            const float* __restrict__ lnb, int prow0, int pmax){
  __shared__ float As[16*68];
  __shared__ float Bs[16*64];
  int p0 = blockIdx.y*64, n0 = blockIdx.x*64;
  int tid = threadIdx.x;
  int tx = tid & 15, ty = tid >> 4;
  float acc[4][4] = {};
  int am = tid >> 2, ak4 = (tid & 3)*4;
  int bn = tid & 63, bk = tid >> 6;
  for (int k0 = 0; k0 < K; k0 += 16){
    if constexpr (LNA){
      int gp = prow0 + p0 + am;
      gp = gp < 0 ? 0 : (gp > pmax ? pmax : gp);
      int kg = k0 + ak4;
      float4 a4 = *(const float4*)(A1 + (size_t)gp*lda + kg);
      float s0 = stats[2*gp], s1 = stats[2*gp+1];
      As[(ak4+0)*68+am] = (a4.x - s0)*s1*lng[kg+0] + lnb[kg+0];
      As[(ak4+1)*68+am] = (a4.y - s0)*s1*lng[kg+1] + lnb[kg+1];
      As[(ak4+2)*68+am] = (a4.z - s0)*s1*lng[kg+2] + lnb[kg+2];
      As[(ak4+3)*68+am] = (a4.w - s0)*s1*lng[kg+3] + lnb[kg+3];
    } else {
      int kg = k0 + ak4;
      const float* Asrc = A1; int kk = kg;
      if (SPLIT && kg >= 128){ Asrc = A2; kk = kg - 128; }
      float4 a4 = *(const float4*)(Asrc + (size_t)(p0+am)*lda + kk);
      As[(ak4+0)*68+am]=a4.x; As[(ak4+1)*68+am]=a4.y;
      As[(ak4+2)*68+am]=a4.z; As[(ak4+3)*68+am]=a4.w;
    }
    #pragma unroll
    for (int r=0; r<4; r++){
      int kk = bk + r*4;
      Bs[kk*64 + bn] = Wm[(size_t)(k0+kk)*N + n0 + bn];
    }
    __syncthreads();
    #pragma unroll
    for (int kk=0; kk<16; kk++){
      float4 a4 = *(const float4*)&As[kk*68 + ty*4];
      float4 b4 = *(const float4*)&Bs[kk*64 + tx*4];
      float av[4] = {a4.x,a4.y,a4.z,a4.w};
      float bv[4] = {b4.x,b4.y,b4.z,b4.w};
      #pragma unroll
      for (int i=0;i<4;i++)
        #pragma unroll
        for (int j=0;j<4;j++) acc[i][j] += av[i]*bv[j];
    }
    __syncthreads();
  }
  #pragma unroll
  for (int i=0;i<4;i++){
    size_t row = p0 + ty*4 + i;
    #pragma unroll
    for (int j=0;j<4;j++){
      int n = n0 + tx*4 + j;
      float v = acc[i][j] + bias[n];
      if (ACT==1) v = (v>=0.f) ? v : 0.01f*v;
      if (ACT==2) v = gelu_f(v);
      if (ADD) v += dst[row*(size_t)N + n];
      dst[row*(size_t)N + n] = v;
    }
  }
}

// ---------------- fused attention: LN1 + q/kv proj + attn + bias ----------------
__global__ __launch_bounds__(64) void attn_fused(
    const float* __restrict__ XT, const float* __restrict__ qw, const float* __restrict__ qb,
    const float* __restrict__ kvw, const float* __restrict__ kvb,
    const float* __restrict__ g1, const float* __restrict__ b1,
    const float* __restrict__ biasT, float* __restrict__ OUT, int win0, int rowoff){
  __shared__ float win_s[64*129];
  __shared__ float kb[64*36];
  __shared__ float vb[64*36];
  int win = win0 + blockIdx.x, head = blockIdx.y;
  int b = win/576, rem = win%576, whi = rem/12, wwi = rem%12;
  int lane = threadIdx.x;
  size_t rowbase = ((size_t)(b*HGT) + whi*4)*WID + wwi*16;
  for (int r = 0; r < 32; ++r){
    int e = r*64 + lane;
    int n = e >> 5, c4 = e & 31;
    size_t ga = (rowbase + (size_t)(n>>4)*WID + (n&15))*C_DIM + c4*4;
    float4 a4 = *(const float4*)(XT + ga);
    int bse = n*129 + c4*4;
    win_s[bse]=a4.x; win_s[bse+1]=a4.y; win_s[bse+2]=a4.z; win_s[bse+3]=a4.w;
  }
  __syncthreads();
  { // exact two-pass LN of row `lane`
    float s1=0.f;
    for (int c=0;c<128;c++) s1 += win_s[lane*129+c];
    float m = s1*(1.f/128.f);
    float s2=0.f;
    for (int c=0;c<128;c++){ float d=win_s[lane*129+c]-m; s2 += d*d; }
    float rstd = rsqrtf(s2*(1.f/128.f) + 1e-5f);
    for (int c=0;c<128;c++){
      float v = win_s[lane*129+c];
      win_s[lane*129+c] = (v-m)*rstd*g1[c] + b1[c];
    }
  }
  __syncthreads();
  float q_[32];
  #pragma unroll
  for (int d=0; d<32; ++d) q_[d]=0.f;
  for (int c=0;c<128;c++){
    float wv = win_s[lane*129+c];
    const float4* qp = (const float4*)(qw + (size_t)c*128 + head*32);
    #pragma unroll
    for (int d4=0; d4<8; ++d4){
      float4 w4 = qp[d4];
      q_[d4*4+0] += wv*w4.x; q_[d4*4+1] += wv*w4.y;
      q_[d4*4+2] += wv*w4.z; q_[d4*4+3] += wv*w4.w;
    }
  }
  #pragma unroll
  for (int d=0; d<32; ++d) q_[d] = (q_[d] + qb[head*32+d])*0.17677669529663688f;
  {
    float k_[32], v_[32];
    #pragma unroll
    for (int d=0; d<32; ++d){ k_[d]=0.f; v_[d]=0.f; }
    for (int c=0;c<128;c++){
      float wv = win_s[lane*129+c];
      const float4* kp = (const float4*)(kvw + (size_t)c*256 + head*32);
      const float4* vp = (const float4*)(kvw + (size_t)c*256 + 128 + head*32);
      #pragma unroll
      for (int d4=0; d4<8; ++d4){
        float4 w4 = kp[d4];
        k_[d4*4+0]+=wv*w4.x; k_[d4*4+1]+=wv*w4.y; k_[d4*4+2]+=wv*w4.z; k_[d4*4+3]+=wv*w4.w;
      }
      #pragma unroll
      for (int d4=0; d4<8; ++d4){
        float4 w4 = vp[d4];
        v_[d4*4+0]+=wv*w4.x; v_[d4*4+1]+=wv*w4.y; v_[d4*4+2]+=wv*w4.z; v_[d4*4+3]+=wv*w4.w;
      }
    }
    #pragma unroll
    for (int d=0; d<32; ++d){
      kb[lane*36+d] = k_[d] + kvb[head*32+d];
      vb[lane*36+d] = v_[d] + kvb[128+head*32+d];
    }
  }
  __syncthreads();
  float* sb = win_s;
  {
    const float* bp = biasT + head*4096 + lane*64;
    for (int m=0;m<64;m++){
      float a = bp[m];
      const float4* k4 = (const float4*)&kb[m*36];
      #pragma unroll
      for (int d4=0; d4<8; ++d4){
        float4 w4 = k4[d4];
        a += q_[d4*4+0]*w4.x + q_[d4*4+1]*w4.y + q_[d4*4+2]*w4.z + q_[d4*4+3]*w4.w;
      }
      sb[lane*65+m] = a;
    }
  }
  float mx = -1e30f;
  for (int m=0;m<64;m++) mx = fmaxf(mx, sb[lane*65+m]);
  float sum = 0.f;
  for (int m=0;m<64;m++){ float e = expf(sb[lane*65+m]-mx); sum += e; sb[lane*65+m] = e; }
  float inv = 1.f/sum;
  float acc[32];
  #pragma unroll
  for (int d=0; d<32; ++d) acc[d]=0.f;
  for (int m=0;m<64;m++){
    float pm = sb[lane*65+m]*inv;
    const float4* v4p = (const float4*)&vb[m*36];
    #pragma unroll
    for (int d4=0; d4<8; ++d4){
      float4 w4 = v4p[d4];
      acc[d4*4+0]+=pm*w4.x; acc[d4*4+1]+=pm*w4.y; acc[d4*4+2]+=pm*w4.z; acc[d4*4+3]+=pm*w4.w;
    }
  }
  size_t grow = rowbase + (size_t)(lane>>4)*WID + (lane&15);
  float* op = OUT + (grow - (size_t)rowoff)*C_DIM + head*32;
  #pragma unroll
  for (int d4=0; d4<8; ++d4) ((float4*)op)[d4] = *(float4*)&acc[d4*4];
}

// ================= DUMB (bulletproof) FFT branch =================
// A: rfft along W. out FR/FI [h][k][c], id = (h*97+k)*128+c
__global__ __launch_bounds__(256) void rfftw_dumb(const float* __restrict__ XTb, float* __restrict__ FR,
                                                  float* __restrict__ FI,
                                                  const float* __restrict__ cosW, const float* __restrict__ sinW){
  int id = blockIdx.x*256 + threadIdx.x;
  int c = id & 127; int t = id >> 7; int k = t % 97; int h = t / 97;
  const float* xp = XTb + (size_t)h*24576 + c;
  const float* cw = cosW + k*192; const float* sw = sinW + k*192;
  float ar = 0.f, ai = 0.f;
  for (int w = 0; w < 192; ++w){
    float v = xp[(size_t)w*128];
    ar += cw[w]*v; ai -= sw[w]*v;
  }
  FR[id] = ar; FI[id] = ai;
}

// B: fft along H (sign -) for k-chunk: out FF0[(kl*192+hf)*256 + {c | c+128}]
__global__ __launch_bounds__(256) void ffth_dumb(const float* __restrict__ FR, const float* __restrict__ FI,
                                                 float* __restrict__ FF0,
                                                 const float* __restrict__ cosH, const float* __restrict__ sinH,
                                                 int k0){
  int id = blockIdx.x*256 + threadIdx.x;      // (kl*192+hf)*128 + c
  int c = id & 127; int t = id >> 7; int hf = t % 192; int kl = t / 192;
  int k = k0 + kl;
  const float* fr = FR + (size_t)k*128 + c;
  const float* fi = FI + (size_t)k*128 + c;
  const float* ch = cosH + hf*192; const float* sh = sinH + hf*192;
  float re = 0.f, im = 0.f;
  for (int h = 0; h < 192; ++h){
    float a = fr[(size_t)h*12416], b = fi[(size_t)h*12416];   // 97*128=12416
    float cv = ch[h], sv = sh[h];
    re += a*cv + b*sv;
    im += b*cv - a*sv;
  }
  size_t row = (size_t)t*256;
  FF0[row + c] = re; FF0[row + c + 128] = im;
}

// C: dumb 1x1 channel mix (256->256), optional leaky
template<bool LEAKY>
__global__ __launch_bounds__(256) void mix_dumb(const float* __restrict__ IN, const float* __restrict__ W,
                                                const float* __restrict__ B, float* __restrict__ OUT, int rows){
  int id = blockIdx.x*256 + threadIdx.x;      // row*256 + o
  int o = id & 255; int row = id >> 8;
  if (row >= rows) return;
  const float* ip = IN + (size_t)row*256;
  float acc = B[o];
  for (int cc = 0; cc < 256; ++cc) acc += ip[cc]*W[(size_t)cc*256 + o];
  if (LEAKY) acc = (acc >= 0.f) ? acc : 0.01f*acc;
  OUT[id] = acc;
}

// D: ifft along H (sign +): in FF rows (kl*192+hf)*256, out GR/GI [h][kl][c] (stride CK)
__global__ __launch_bounds__(256) void iffth_dumb(const float* __restrict__ FF, float* __restrict__ GR,
                                                  float* __restrict__ GI,
                                                  const float* __restrict__ cosH, const float* __restrict__ sinH,
                                                  int CK){
  int id = blockIdx.x*256 + threadIdx.x;      // (h*CK+kl)*128 + c
  int c = id & 127; int t = id >> 7; int kl = t % CK; int h = t / CK;
  const float* base = FF + (size_t)kl*192*256;
  const float* ch = cosH + h*192; const float* sh = sinH + h*192;
  float re = 0.f, im = 0.f;
  for (int hf = 0; hf < 192; ++hf){
    float a = base[(size_t)hf*256 + c], b = base[(size_t)hf*256 + c + 128];
    float cv = ch[hf], sv = sh[hf];
    re += a*cv - b*sv;
    im += b*cv + a*sv;
  }
  GR[id] = re; GI[id] = im;
}

// E: irfft along W, chunk-accumulate into XTb
__global__ __launch_bounds__(256) void irfftw_dumb(const float* __restrict__ GR, const float* __restrict__ GI,
                                                   float* __restrict__ XTb,
                                                   const float* __restrict__ icos, const float* __restrict__ isin,
                                                   int CK, int k0){
  int id = blockIdx.x*256 + threadIdx.x;      // (h*192+w)*128 + c
  int c = id & 127; int t = id >> 7; int w = t % 192; int h = t / 192;
  const float* gr = GR + (size_t)h*CK*128 + c;
  const float* gi = GI + (size_t)h*CK*128 + c;
  const float* ic = icos + w*97 + k0;
  const float* is = isin + w*97 + k0;
  float acc = 0.f;
  for (int kl = 0; kl < CK; ++kl)
    acc += ic[kl]*gr[(size_t)kl*128] - is[kl]*gi[(size_t)kl*128];
  XTb[id] += acc;
}

// ---------------- LeFF tail: dwconv3x3 + gelu + linear2 + residual (strip) ----------------
__global__ __launch_bounds__(256) void leff_tail_kernel(const float* __restrict__ h1, const float* __restrict__ dw,
                                 const float* __restrict__ db, const float* __restrict__ l2w,
                                 const float* __restrict__ l2b, float* __restrict__ XTp,
                                 int b, int r0){
  __shared__ float t_s[8*516];
  int blk = blockIdx.x;
  int w0 = (blk % 24)*8;
  int h = r0 + blk/24;
  int tid = threadIdx.x;
  for (int r=0;r<16;r++){
    int e = tid + 256*r;
    int ch = e & 511, p = e >> 9;
    int w = w0 + p;
    float acc = db[ch];
    #pragma unroll
    for (int ky=0; ky<3; ky++){
      int hh = h+ky-1;
      if (hh<0 || hh>=HGT) continue;
      int br = hh - r0 + 1;
      #pragma unroll
      for (int kx=0; kx<3; kx++){
        int ww = w+kx-1;
        if (ww<0 || ww>=WID) continue;
        acc += dw[ch*9+ky*3+kx]*h1[((size_t)br*WID + ww)*512 + ch];
      }
    }
    t_s[p*516+ch] = gelu_f(acc);
  }
  __syncthreads();
  int c = tid & 127, pg = tid >> 7;
  #pragma unroll
  for (int pi=0; pi<4; ++pi){
    int p = pg*4 + pi;
    float acc = l2b[c];
    const float* tp = &t_s[p*516];
    for (int ch=0; ch<512; ch+=4){
      float4 t4 = *(const float4*)(tp+ch);
      acc += t4.x*l2w[(ch+0)*128+c] + t4.y*l2w[(ch+1)*128+c]
           + t4.z*l2w[(ch+2)*128+c] + t4.w*l2w[(ch+3)*128+c];
    }
    size_t row = ((size_t)(b*HGT+h))*WID + w0 + p;
    XTp[row*C_DIM + c] += acc;
  }
}

// ---------------- per-batch BHWC -> BCHW transpose (into staging) ----------------
__global__ __launch_bounds__(256) void transpose_b_kernel(const float* __restrict__ src, float* __restrict__ dst){
  __shared__ float tile[128*65];
  int w0 = blockIdx.x*64, h = blockIdx.y;
  int tid = threadIdx.x;
  for (int r=0; r<32; r++){
    int e = tid + 256*r; int c = e & 127, wl = e >> 7;
    tile[c*65 + wl] = src[((size_t)h*WID + w0 + wl)*C_DIM + c];
  }
  __syncthreads();
  for (int r=0; r<32; r++){
    int e = tid + 256*r; int wl = e & 63, c = e >> 6;
    dst[((size_t)c*HGT + h)*WID + w0 + wl] = tile[c*65 + wl];
  }
}

// ---------------- host ----------------
extern "C" void kernel_launch(void* const* d_in, const int* in_sizes, int n_in,
                              void* d_out, int out_size, void* d_ws, size_t ws_size,
                              hipStream_t stream) {
  const float* x      = (const float*)d_in[0];
  const float* pos_w  = (const float*)d_in[1];
  const float* pos_b  = (const float*)d_in[2];
  const float* ln1_g  = (const float*)d_in[3];
  const float* ln1_b  = (const float*)d_in[4];
  const float* q_w    = (const float*)d_in[5];
  const float* q_b    = (const float*)d_in[6];
  const float* kv_w   = (const float*)d_in[7];
  const float* kv_b   = (const float*)d_in[8];
  const float* rpb    = (const float*)d_in[9];
  const float* proj_w = (const float*)d_in[10];
  const float* proj_b = (const float*)d_in[11];
  const float* fft1_w = (const float*)d_in[12];
  const float* fft1_b = (const float*)d_in[13];
  const float* fft2_w = (const float*)d_in[14];
  const float* fft2_b = (const float*)d_in[15];
  const float* ln2_g  = (const float*)d_in[16];
  const float* ln2_b  = (const float*)d_in[17];
  const float* l1_w   = (const float*)d_in[18];
  const float* l1_b   = (const float*)d_in[19];
  const float* dw_w   = (const float*)d_in[20];
  const float* dw_b   = (const float*)d_in[21];
  const float* l2_w   = (const float*)d_in[22];
  const float* l2_b   = (const float*)d_in[23];

  const size_t S   = (size_t)NB*HGT*WID*C_DIM;   // 18,874,368
  const size_t Sb  = S/NB;                       //  4,718,592
  const size_t SZb = (size_t)HGT*WFD*C_DIM;      //  2,383,872
  const int    P   = (int)(NB*HGT*WID);          // 147,456

  float* XT = (float*)d_out;

  float* ws    = (float*)d_ws;
  float* TAB   = ws;
  float* STATS = ws + 262144;
  float* POOL  = ws + 262144 + 2*(size_t)P;
  size_t pool  = (ws_size/4 > 557056) ? (ws_size/4 - 557056) : 0;

  const float* cosW = TAB + T_COSW; const float* sinW = TAB + T_SINW;
  const float* cosH = TAB + T_COSH; const float* sinH = TAB + T_SINH;
  const float* icos = TAB + T_ICOS; const float* isin = TAB + T_ISIN;
  const float* biasT = TAB + T_BIAS;

  int winChunk = (int)((pool/8192/12)*12);
  if (winChunk < 12) winChunk = 12;
  if (winChunk > 2304) winChunk = 2304;
  int SH = 32;
  while ((size_t)2*(SH+2)*WID*512 > pool && SH > 8) SH >>= 1;

  build_tables<<<354, 256, 0, stream>>>(TAB, rpb);
  posconv_kernel<<<dim3(3,192,4), 256, 0, stream>>>(x, pos_w, pos_b, XT);

  // ---- attention, chunked over 12-window groups ----
  for (int w0 = 0; w0 < 2304; w0 += winChunk){
    int nw = (2304 - w0 < winChunk) ? (2304 - w0) : winChunk;
    attn_fused<<<dim3(nw, 4), 64, 0, stream>>>(XT, q_w, q_b, kv_w, kv_b,
                                               ln1_g, ln1_b, biasT, POOL,
                                               w0, w0*64);
    gemm_kernel<0,true,false,false><<<dim3(2, nw), 256, 0, stream>>>(
        POOL, nullptr, proj_w, proj_b, XT + (size_t)w0*64*C_DIM,
        128, 128, 128, nullptr, nullptr, nullptr, 0, 0);
  }

  // ---- FFT residual branch: dumb per-element DFT kernels, chunked over k ----
  {
    int CK = 1;
    if (pool > 2*SZb + 147456) CK = (int)((pool - 2*SZb)/147456);
    if (CK < 1) CK = 1;
    if (CK > WFD) CK = WFD;
    float* FR  = POOL;
    float* FI  = POOL + SZb;
    float* FF0 = POOL + 2*SZb;                 // CK*192*256
    float* FF1 = FF0 + (size_t)CK*49152;       // CK*192*256
    float* GR  = FF1 + (size_t)CK*49152;       // CK*192*128
    float* GI  = GR  + (size_t)CK*24576;       // CK*192*128
    for (int b = 0; b < NB; ++b){
      float* XTb = XT + (size_t)b*Sb;
      rfftw_dumb<<<9312, 256, 0, stream>>>(XTb, FR, FI, cosW, sinW);
      for (int k0 = 0; k0 < WFD; k0 += CK){
        int ck = (WFD - k0 < CK) ? (WFD - k0) : CK;
        int rows = ck*192;
        ffth_dumb<<<ck*96, 256, 0, stream>>>(FR, FI, FF0, cosH, sinH, k0);
        mix_dumb<true ><<<rows, 256, 0, stream>>>(FF0, fft1_w, fft1_b, FF1, rows);
        mix_dumb<false><<<rows, 256, 0, stream>>>(FF1, fft2_w, fft2_b, FF0, rows);
        iffth_dumb<<<ck*96, 256, 0, stream>>>(FF0, GR, GI, cosH, sinH, ck);
        irfftw_dumb<<<18432, 256, 0, stream>>>(GR, GI, XTb, icos, isin, ck, k0);
      }
    }
  }

  // ---- LN2 stats ----
  ln_stats_kernel<<<P/4, 256, 0, stream>>>(XT, STATS);

  // ---- LeFF, strip-mined ----
  {
    const size_t SBSZ = (size_t)(SH+2)*WID*512;
    float* SB[2] = { POOL, POOL + SBSZ };
    int nStrips = HGT/SH;
    for (int b = 0; b < NB; ++b){
      auto launch_g = [&](int s){
        int r0 = s*SH;
        int prow0 = (b*HGT + r0 - 1)*WID;
        gemm_kernel<2,false,false,true><<<dim3(8, (SH+2)*3), 256, 0, stream>>>(
            XT, nullptr, l1_w, l1_b, SB[s&1], 128, 512, 128,
            STATS, ln2_g, ln2_b, prow0, P-1);
      };
      launch_g(0);
      for (int s = 0; s < nStrips; ++s){
        if (s+1 < nStrips) launch_g(s+1);
        leff_tail_kernel<<<24*SH, 256, 0, stream>>>(SB[s&1], dw_w, dw_b, l2_w, l2_b,
                                                    XT, b, s*SH);
      }
    }
  }

  // ---- final transpose per batch: XT(BHWC, in d_out) -> POOL(BCHW) -> copy back ----
  for (int b = 0; b < NB; ++b){
    transpose_b_kernel<<<dim3(3,192), 256, 0, stream>>>(XT + (size_t)b*Sb, POOL);
    hipMemcpyAsync((float*)d_out + (size_t)b*Sb, POOL, Sb*sizeof(float),
                   hipMemcpyDeviceToDevice, stream);
  }
}

// Round 5
// 7562.257 us; speedup vs baseline: 1.3752x; 1.3752x over previous
//
#include <hip/hip_runtime.h>
#include <math.h>

// ---------------- constants ----------------
#define C_DIM 128
#define HGT 192
#define WID 192
#define NB 4
#define WFD 97   // 192/2+1

// table offsets (floats)
#define T_COSW 0
#define T_SINW 18624
#define T_COSH 37248
#define T_SINH 74112
#define T_ICOS 110976
#define T_ISIN 129600
#define T_BIAS 148224
// total 164608 < 262144 reserved

__device__ __forceinline__ float gelu_f(float v){
  return 0.5f*v*(1.0f + erff(v*0.70710678118654752440f));
}

// ---------------- table build ----------------
__global__ __launch_bounds__(256) void build_tables(float* __restrict__ tab, const float* __restrict__ rpb){
  int idx = blockIdx.x*256 + threadIdx.x;
  const double TP = 6.283185307179586476925286766559;
  if (idx < 18624){ // rfft-W matrices: [wf=97][w=192]
    int i = idx/192, j = idx%192;
    double th = TP*((double)(i*j))/192.0;
    tab[T_COSW+idx] = (float)cos(th);
    tab[T_SINW+idx] = (float)sin(th);
    return;
  }
  idx -= 18624;
  if (idx < 36864){ // fft-H matrices: [hf=192][h=192]
    int i = idx/192, j = idx%192;
    double th = TP*((double)(i*j))/192.0;
    tab[T_COSH+idx] = (float)cos(th);
    tab[T_SINH+idx] = (float)sin(th);
    return;
  }
  idx -= 36864;
  if (idx < 18624){ // irfft-W matrices: [w=192][k=97], alpha/(H*W) folded
    int w = idx/97, k = idx%97;
    double th = TP*((double)(k*w))/192.0;
    double a = (k==0 || k==96) ? 1.0 : 2.0;
    double sc = a/36864.0;
    tab[T_ICOS+idx] = (float)(sc*cos(th));
    tab[T_ISIN+idx] = (float)(sc*sin(th));
    return;
  }
  idx -= 18624;
  if (idx < 16384){ // attn bias: [head][n][m]
    int head = idx>>12, n = (idx>>6)&63, m = idx&63;
    int dh = n/16 - m/16 + 3;
    int dw = (n&15) - (m&15) + 15;
    tab[T_BIAS+idx] = rpb[(dh*31+dw)*4 + head];
  }
}

// ---------------- pos depthwise conv (BCHW in -> BHWC out, + residual) ----------------
__global__ __launch_bounds__(256) void posconv_kernel(const float* __restrict__ x, const float* __restrict__ pw,
                               const float* __restrict__ pb, float* __restrict__ xt){
  __shared__ float tile[64*129];
  int w0 = blockIdx.x*64; int h = blockIdx.y; int b = blockIdx.z;
  int tid = threadIdx.x;
  int wl = tid & 63; int cg = tid >> 6;
  int w = w0 + wl;
  for (int ci = 0; ci < 32; ++ci){
    int c = cg*32 + ci;
    const float* xp = x + (size_t)(b*C_DIM + c)*HGT*WID;
    float acc = xp[(size_t)h*WID + w] + pb[c];
    #pragma unroll
    for (int ky=0; ky<3; ky++){
      int hh = h + ky - 1;
      if (hh < 0 || hh >= HGT) continue;
      #pragma unroll
      for (int kx=0; kx<3; kx++){
        int ww = w + kx - 1;
        if (ww < 0 || ww >= WID) continue;
        acc += pw[c*27 + 9 + ky*3 + kx] * xp[(size_t)hh*WID + ww];
      }
    }
    tile[wl*129 + c] = acc;
  }
  __syncthreads();
  for (int r=0; r<32; r++){
    int e = tid + 256*r; int c = e & 127; int wl2 = e >> 7;
    xt[((size_t)(b*HGT+h)*WID + w0 + wl2)*C_DIM + c] = tile[wl2*129 + c];
  }
}

// ---------------- LN row stats (mean, rstd) ----------------
__global__ __launch_bounds__(256) void ln_stats_kernel(const float* __restrict__ src, float* __restrict__ stats){
  int wave = threadIdx.x >> 6; int lane = threadIdx.x & 63;
  size_t p = (size_t)blockIdx.x*4 + wave;
  const float* s = src + p*C_DIM;
  float v0 = s[lane], v1 = s[lane+64];
  float sum = v0 + v1;
  #pragma unroll
  for (int o=1; o<64; o<<=1) sum += __shfl_xor(sum, o, 64);
  float m = sum * (1.0f/128.0f);
  float d0 = v0-m, d1 = v1-m;
  float vs = d0*d0 + d1*d1;
  #pragma unroll
  for (int o=1; o<64; o<<=1) vs += __shfl_xor(vs, o, 64);
  float rstd = rsqrtf(vs*(1.0f/128.0f) + 1e-5f);
  if (lane==0){ stats[2*p] = m; stats[2*p+1] = rstd; }
}

// ---------------- generic fp32 GEMM ----------------
template<int ACT, bool ADD, bool SPLIT, bool LNA>
__global__ __launch_bounds__(256) void gemm_kernel(const float* __restrict__ A1, const float* __restrict__ A2,
                            const float* __restrict__ Wm, const float* __restrict__ bias,
                            float* __restrict__ dst, int K, int N, int lda,
                            const float* __restrict__ stats, const float* __restrict__ lng,
                            const float* __restrict__ lnb, int prow0, int pmax){
  __shared__ float As[16*68];
  __shared__ float Bs[16*64];
  int p0 = blockIdx.y*64, n0 = blockIdx.x*64;
  int tid = threadIdx.x;
  int tx = tid & 15, ty = tid >> 4;
  float acc[4][4] = {};
  int am = tid >> 2, ak4 = (tid & 3)*4;
  int bn = tid & 63, bk = tid >> 6;
  for (int k0 = 0; k0 < K; k0 += 16){
    if constexpr (LNA){
      int gp = prow0 + p0 + am;
      gp = gp < 0 ? 0 : (gp > pmax ? pmax : gp);
      int kg = k0 + ak4;
      float4 a4 = *(const float4*)(A1 + (size_t)gp*lda + kg);
      float s0 = stats[2*gp], s1 = stats[2*gp+1];
      As[(ak4+0)*68+am] = (a4.x - s0)*s1*lng[kg+0] + lnb[kg+0];
      As[(ak4+1)*68+am] = (a4.y - s0)*s1*lng[kg+1] + lnb[kg+1];
      As[(ak4+2)*68+am] = (a4.z - s0)*s1*lng[kg+2] + lnb[kg+2];
      As[(ak4+3)*68+am] = (a4.w - s0)*s1*lng[kg+3] + lnb[kg+3];
    } else {
      int kg = k0 + ak4;
      const float* Asrc = A1; int kk = kg;
      if (SPLIT && kg >= 128){ Asrc = A2; kk = kg - 128; }
      float4 a4 = *(const float4*)(Asrc + (size_t)(p0+am)*lda + kk);
      As[(ak4+0)*68+am]=a4.x; As[(ak4+1)*68+am]=a4.y;
      As[(ak4+2)*68+am]=a4.z; As[(ak4+3)*68+am]=a4.w;
    }
    #pragma unroll
    for (int r=0; r<4; r++){
      int kk = bk + r*4;
      Bs[kk*64 + bn] = Wm[(size_t)(k0+kk)*N + n0 + bn];
    }
    __syncthreads();
    #pragma unroll
    for (int kk=0; kk<16; kk++){
      float4 a4 = *(const float4*)&As[kk*68 + ty*4];
      float4 b4 = *(const float4*)&Bs[kk*64 + tx*4];
      float av[4] = {a4.x,a4.y,a4.z,a4.w};
      float bv[4] = {b4.x,b4.y,b4.z,b4.w};
      #pragma unroll
      for (int i=0;i<4;i++)
        #pragma unroll
        for (int j=0;j<4;j++) acc[i][j] += av[i]*bv[j];
    }
    __syncthreads();
  }
  #pragma unroll
  for (int i=0;i<4;i++){
    size_t row = p0 + ty*4 + i;
    #pragma unroll
    for (int j=0;j<4;j++){
      int n = n0 + tx*4 + j;
      float v = acc[i][j] + bias[n];
      if (ACT==1) v = (v>=0.f) ? v : 0.01f*v;
      if (ACT==2) v = gelu_f(v);
      if (ADD) v += dst[row*(size_t)N + n];
      dst[row*(size_t)N + n] = v;
    }
  }
}

// ---------------- light attention: reads precomputed Qc/KVc ----------------
// block = (window, head), 64 threads. Validated score/softmax/PV path.
__global__ __launch_bounds__(64) void attn_light(
    const float* __restrict__ Qc, const float* __restrict__ KVc,
    const float* __restrict__ biasT, float* __restrict__ OUTc,
    int win0, int prow0){
  __shared__ float kb[64*36];
  __shared__ float vb[64*36];
  int win = win0 + blockIdx.x, head = blockIdx.y;
  int b = win/576, rem = win%576, whi = rem/12, wwi = rem%12;
  int lane = threadIdx.x;
  int rowbase = (b*HGT + whi*4)*WID + wwi*16;
  int l = (rowbase - prow0) + (lane>>4)*WID + (lane&15);
  {
    const float* kp = KVc + (size_t)l*256 + head*32;
    #pragma unroll
    for (int d4=0; d4<8; ++d4){
      *(float4*)&kb[lane*36+d4*4] = *(const float4*)(kp+d4*4);
      *(float4*)&vb[lane*36+d4*4] = *(const float4*)(kp+128+d4*4);
    }
  }
  float q_[32];
  {
    const float* qp = Qc + (size_t)l*128 + head*32;
    #pragma unroll
    for (int d=0; d<32; ++d) q_[d] = qp[d]*0.17677669529663688f; // 1/sqrt(32)
  }
  __syncthreads();
  float s[64];
  const float* bp = biasT + head*4096 + lane*64;
  for (int m=0;m<64;m++){
    float a = bp[m];
    const float4* k4 = (const float4*)&kb[m*36];
    #pragma unroll
    for (int d4=0; d4<8; ++d4){
      float4 w4 = k4[d4];
      a += q_[d4*4+0]*w4.x + q_[d4*4+1]*w4.y + q_[d4*4+2]*w4.z + q_[d4*4+3]*w4.w;
    }
    s[m] = a;
  }
  float mx = -1e30f;
  for (int m=0;m<64;m++) mx = fmaxf(mx, s[m]);
  float sum = 0.f;
  for (int m=0;m<64;m++){ float e = expf(s[m]-mx); sum += e; s[m] = e; }
  float inv = 1.f/sum;
  float acc[32];
  #pragma unroll
  for (int d=0; d<32; ++d) acc[d]=0.f;
  for (int m=0;m<64;m++){
    float pm = s[m]*inv;
    const float4* v4p = (const float4*)&vb[m*36];
    #pragma unroll
    for (int d4=0; d4<8; ++d4){
      float4 w4 = v4p[d4];
      acc[d4*4+0]+=pm*w4.x; acc[d4*4+1]+=pm*w4.y; acc[d4*4+2]+=pm*w4.z; acc[d4*4+3]+=pm*w4.w;
    }
  }
  float* op = OUTc + (size_t)l*128 + head*32;
  #pragma unroll
  for (int d4=0; d4<8; ++d4) ((float4*)op)[d4] = *(float4*)&acc[d4*4];
}

// ================= DUMB (bulletproof) FFT branch =================
// A: rfft along W. out FR/FI [h][k][c], id = (h*97+k)*128+c
__global__ __launch_bounds__(256) void rfftw_dumb(const float* __restrict__ XTb, float* __restrict__ FR,
                                                  float* __restrict__ FI,
                                                  const float* __restrict__ cosW, const float* __restrict__ sinW){
  int id = blockIdx.x*256 + threadIdx.x;
  int c = id & 127; int t = id >> 7; int k = t % 97; int h = t / 97;
  const float* xp = XTb + (size_t)h*24576 + c;
  const float* cw = cosW + k*192; const float* sw = sinW + k*192;
  float ar = 0.f, ai = 0.f;
  for (int w = 0; w < 192; ++w){
    float v = xp[(size_t)w*128];
    ar += cw[w]*v; ai -= sw[w]*v;
  }
  FR[id] = ar; FI[id] = ai;
}

// B: fft along H (sign -) for k-chunk: out FF0[(kl*192+hf)*256 + {c | c+128}]
__global__ __launch_bounds__(256) void ffth_dumb(const float* __restrict__ FR, const float* __restrict__ FI,
                                                 float* __restrict__ FF0,
                                                 const float* __restrict__ cosH, const float* __restrict__ sinH,
                                                 int k0){
  int id = blockIdx.x*256 + threadIdx.x;      // (kl*192+hf)*128 + c
  int c = id & 127; int t = id >> 7; int hf = t % 192; int kl = t / 192;
  int k = k0 + kl;
  const float* fr = FR + (size_t)k*128 + c;
  const float* fi = FI + (size_t)k*128 + c;
  const float* ch = cosH + hf*192; const float* sh = sinH + hf*192;
  float re = 0.f, im = 0.f;
  for (int h = 0; h < 192; ++h){
    float a = fr[(size_t)h*12416], b = fi[(size_t)h*12416];   // 97*128=12416
    float cv = ch[h], sv = sh[h];
    re += a*cv + b*sv;
    im += b*cv - a*sv;
  }
  size_t row = (size_t)t*256;
  FF0[row + c] = re; FF0[row + c + 128] = im;
}

// D: ifft along H (sign +): in FF rows (kl*192+hf)*256, out GR/GI [h][kl][c] (stride CK)
__global__ __launch_bounds__(256) void iffth_dumb(const float* __restrict__ FF, float* __restrict__ GR,
                                                  float* __restrict__ GI,
                                                  const float* __restrict__ cosH, const float* __restrict__ sinH,
                                                  int CK){
  int id = blockIdx.x*256 + threadIdx.x;      // (h*CK+kl)*128 + c
  int c = id & 127; int t = id >> 7; int kl = t % CK; int h = t / CK;
  const float* base = FF + (size_t)kl*192*256;
  const float* ch = cosH + h*192; const float* sh = sinH + h*192;
  float re = 0.f, im = 0.f;
  for (int hf = 0; hf < 192; ++hf){
    float a = base[(size_t)hf*256 + c], b = base[(size_t)hf*256 + c + 128];
    float cv = ch[hf], sv = sh[hf];
    re += a*cv - b*sv;
    im += b*cv + a*sv;
  }
  GR[id] = re; GI[id] = im;
}

// E: irfft along W, chunk-accumulate into XTb
__global__ __launch_bounds__(256) void irfftw_dumb(const float* __restrict__ GR, const float* __restrict__ GI,
                                                   float* __restrict__ XTb,
                                                   const float* __restrict__ icos, const float* __restrict__ isin,
                                                   int CK, int k0){
  int id = blockIdx.x*256 + threadIdx.x;      // (h*192+w)*128 + c
  int c = id & 127; int t = id >> 7; int w = t % 192; int h = t / 192;
  const float* gr = GR + (size_t)h*CK*128 + c;
  const float* gi = GI + (size_t)h*CK*128 + c;
  const float* ic = icos + w*97 + k0;
  const float* is = isin + w*97 + k0;
  float acc = 0.f;
  for (int kl = 0; kl < CK; ++kl)
    acc += ic[kl]*gr[(size_t)kl*128] - is[kl]*gi[(size_t)kl*128];
  XTb[id] += acc;
}

// ---------------- LeFF tail: dwconv3x3 + gelu + linear2 + residual (strip) ----------------
__global__ __launch_bounds__(256) void leff_tail_kernel(const float* __restrict__ h1, const float* __restrict__ dw,
                                 const float* __restrict__ db, const float* __restrict__ l2w,
                                 const float* __restrict__ l2b, float* __restrict__ XTp,
                                 int b, int r0){
  __shared__ float t_s[8*516];
  int blk = blockIdx.x;
  int w0 = (blk % 24)*8;
  int h = r0 + blk/24;
  int tid = threadIdx.x;
  for (int r=0;r<16;r++){
    int e = tid + 256*r;
    int ch = e & 511, p = e >> 9;
    int w = w0 + p;
    float acc = db[ch];
    #pragma unroll
    for (int ky=0; ky<3; ky++){
      int hh = h+ky-1;
      if (hh<0 || hh>=HGT) continue;
      int br = hh - r0 + 1;
      #pragma unroll
      for (int kx=0; kx<3; kx++){
        int ww = w+kx-1;
        if (ww<0 || ww>=WID) continue;
        acc += dw[ch*9+ky*3+kx]*h1[((size_t)br*WID + ww)*512 + ch];
      }
    }
    t_s[p*516+ch] = gelu_f(acc);
  }
  __syncthreads();
  int c = tid & 127, pg = tid >> 7;
  #pragma unroll
  for (int pi=0; pi<4; ++pi){
    int p = pg*4 + pi;
    float acc = l2b[c];
    const float* tp = &t_s[p*516];
    for (int ch=0; ch<512; ch+=4){
      float4 t4 = *(const float4*)(tp+ch);
      acc += t4.x*l2w[(ch+0)*128+c] + t4.y*l2w[(ch+1)*128+c]
           + t4.z*l2w[(ch+2)*128+c] + t4.w*l2w[(ch+3)*128+c];
    }
    size_t row = ((size_t)(b*HGT+h))*WID + w0 + p;
    XTp[row*C_DIM + c] += acc;
  }
}

// ---------------- per-batch BHWC -> BCHW transpose (into staging) ----------------
__global__ __launch_bounds__(256) void transpose_b_kernel(const float* __restrict__ src, float* __restrict__ dst){
  __shared__ float tile[128*65];
  int w0 = blockIdx.x*64, h = blockIdx.y;
  int tid = threadIdx.x;
  for (int r=0; r<32; r++){
    int e = tid + 256*r; int c = e & 127, wl = e >> 7;
    tile[c*65 + wl] = src[((size_t)h*WID + w0 + wl)*C_DIM + c];
  }
  __syncthreads();
  for (int r=0; r<32; r++){
    int e = tid + 256*r; int wl = e & 63, c = e >> 6;
    dst[((size_t)c*HGT + h)*WID + w0 + wl] = tile[c*65 + wl];
  }
}

// ---------------- host ----------------
extern "C" void kernel_launch(void* const* d_in, const int* in_sizes, int n_in,
                              void* d_out, int out_size, void* d_ws, size_t ws_size,
                              hipStream_t stream) {
  const float* x      = (const float*)d_in[0];
  const float* pos_w  = (const float*)d_in[1];
  const float* pos_b  = (const float*)d_in[2];
  const float* ln1_g  = (const float*)d_in[3];
  const float* ln1_b  = (const float*)d_in[4];
  const float* q_w    = (const float*)d_in[5];
  const float* q_b    = (const float*)d_in[6];
  const float* kv_w   = (const float*)d_in[7];
  const float* kv_b   = (const float*)d_in[8];
  const float* rpb    = (const float*)d_in[9];
  const float* proj_w = (const float*)d_in[10];
  const float* proj_b = (const float*)d_in[11];
  const float* fft1_w = (const float*)d_in[12];
  const float* fft1_b = (const float*)d_in[13];
  const float* fft2_w = (const float*)d_in[14];
  const float* fft2_b = (const float*)d_in[15];
  const float* ln2_g  = (const float*)d_in[16];
  const float* ln2_b  = (const float*)d_in[17];
  const float* l1_w   = (const float*)d_in[18];
  const float* l1_b   = (const float*)d_in[19];
  const float* dw_w   = (const float*)d_in[20];
  const float* dw_b   = (const float*)d_in[21];
  const float* l2_w   = (const float*)d_in[22];
  const float* l2_b   = (const float*)d_in[23];

  const size_t S   = (size_t)NB*HGT*WID*C_DIM;   // 18,874,368
  const size_t Sb  = S/NB;                       //  4,718,592
  const size_t SZb = (size_t)HGT*WFD*C_DIM;      //  2,383,872
  const int    P   = (int)(NB*HGT*WID);          // 147,456

  float* XT = (float*)d_out;

  float* ws    = (float*)d_ws;
  float* TAB   = ws;
  float* STATS = ws + 262144;
  float* POOL  = ws + 262144 + 2*(size_t)P;
  size_t pool  = (ws_size/4 > 557056) ? (ws_size/4 - 557056) : 0;

  const float* cosW = TAB + T_COSW; const float* sinW = TAB + T_SINW;
  const float* cosH = TAB + T_COSH; const float* sinH = TAB + T_SINH;
  const float* icos = TAB + T_ICOS; const float* isin = TAB + T_ISIN;
  const float* biasT = TAB + T_BIAS;

  int SH = 32;
  while ((size_t)2*(SH+2)*WID*512 > pool && SH > 8) SH >>= 1;

  build_tables<<<354, 256, 0, stream>>>(TAB, rpb);
  posconv_kernel<<<dim3(3,192,4), 256, 0, stream>>>(x, pos_w, pos_b, XT);

  // ---- attention: LN1 stats -> per-chunk {q gemm, kv gemm, attn, proj gemm} ----
  ln_stats_kernel<<<P/4, 256, 0, stream>>>(XT, STATS);
  {
    int winChunk = (int)((pool/(64*512)/12)*12);   // chunk needs R*512 floats
    if (winChunk < 12) winChunk = 12;
    if (winChunk > 2304) winChunk = 2304;
    for (int w0 = 0; w0 < 2304; w0 += winChunk){
      int nw = (2304 - w0 < winChunk) ? (2304 - w0) : winChunk;
      int R = nw*64, prow0 = w0*64;
      float* Qc   = POOL;
      float* KVc  = POOL + (size_t)R*128;
      float* OUTc = POOL + (size_t)R*384;
      gemm_kernel<0,false,false,true><<<dim3(2, R/64), 256, 0, stream>>>(
          XT, nullptr, q_w, q_b, Qc, 128, 128, 128, STATS, ln1_g, ln1_b, prow0, P-1);
      gemm_kernel<0,false,false,true><<<dim3(4, R/64), 256, 0, stream>>>(
          XT, nullptr, kv_w, kv_b, KVc, 128, 256, 128, STATS, ln1_g, ln1_b, prow0, P-1);
      attn_light<<<dim3(nw, 4), 64, 0, stream>>>(Qc, KVc, biasT, OUTc, w0, prow0);
      gemm_kernel<0,true,false,false><<<dim3(2, R/64), 256, 0, stream>>>(
          OUTc, nullptr, proj_w, proj_b, XT + (size_t)prow0*C_DIM,
          128, 128, 128, nullptr, nullptr, nullptr, 0, 0);
    }
  }

  // ---- FFT residual branch: dumb DFTs + tiled-GEMM mixes, chunked over k ----
  {
    int CK = 1;
    if (pool > 2*SZb + 147456) CK = (int)((pool - 2*SZb)/147456);
    if (CK < 1) CK = 1;
    if (CK > WFD) CK = WFD;
    float* FR  = POOL;
    float* FI  = POOL + SZb;
    float* FF0 = POOL + 2*SZb;                 // CK*192*256
    float* FF1 = FF0 + (size_t)CK*49152;       // CK*192*256
    float* GR  = FF1 + (size_t)CK*49152;       // CK*192*128
    float* GI  = GR  + (size_t)CK*24576;       // CK*192*128
    for (int b = 0; b < NB; ++b){
      float* XTb = XT + (size_t)b*Sb;
      rfftw_dumb<<<9312, 256, 0, stream>>>(XTb, FR, FI, cosW, sinW);
      for (int k0 = 0; k0 < WFD; k0 += CK){
        int ck = (WFD - k0 < CK) ? (WFD - k0) : CK;
        int rows = ck*192;
        ffth_dumb<<<ck*96, 256, 0, stream>>>(FR, FI, FF0, cosH, sinH, k0);
        gemm_kernel<1,false,false,false><<<dim3(4, rows/64), 256, 0, stream>>>(
            FF0, nullptr, fft1_w, fft1_b, FF1, 256, 256, 256,
            nullptr, nullptr, nullptr, 0, 0);
        gemm_kernel<0,false,false,false><<<dim3(4, rows/64), 256, 0, stream>>>(
            FF1, nullptr, fft2_w, fft2_b, FF0, 256, 256, 256,
            nullptr, nullptr, nullptr, 0, 0);
        iffth_dumb<<<ck*96, 256, 0, stream>>>(FF0, GR, GI, cosH, sinH, ck);
        irfftw_dumb<<<18432, 256, 0, stream>>>(GR, GI, XTb, icos, isin, ck, k0);
      }
    }
  }

  // ---- LN2 stats ----
  ln_stats_kernel<<<P/4, 256, 0, stream>>>(XT, STATS);

  // ---- LeFF, strip-mined ----
  {
    const size_t SBSZ = (size_t)(SH+2)*WID*512;
    float* SB[2] = { POOL, POOL + SBSZ };
    int nStrips = HGT/SH;
    for (int b = 0; b < NB; ++b){
      auto launch_g = [&](int s){
        int r0 = s*SH;
        int prow0 = (b*HGT + r0 - 1)*WID;
        gemm_kernel<2,false,false,true><<<dim3(8, (SH+2)*3), 256, 0, stream>>>(
            XT, nullptr, l1_w, l1_b, SB[s&1], 128, 512, 128,
            STATS, ln2_g, ln2_b, prow0, P-1);
      };
      launch_g(0);
      for (int s = 0; s < nStrips; ++s){
        if (s+1 < nStrips) launch_g(s+1);
        leff_tail_kernel<<<24*SH, 256, 0, stream>>>(SB[s&1], dw_w, dw_b, l2_w, l2_b,
                                                    XT, b, s*SH);
      }
    }
  }

  // ---- final transpose per batch: XT(BHWC, in d_out) -> POOL(BCHW) -> copy back ----
  for (int b = 0; b < NB; ++b){
    transpose_b_kernel<<<dim3(3,192), 256, 0, stream>>>(XT + (size_t)b*Sb, POOL);
    hipMemcpyAsync((float*)d_out + (size_t)b*Sb, POOL, Sb*sizeof(float),
                   hipMemcpyDeviceToDevice, stream);
  }
}

// Round 6
// 6625.476 us; speedup vs baseline: 1.5696x; 1.1414x over previous
//
#include <hip/hip_runtime.h>
#include <math.h>

// ---------------- constants ----------------
#define C_DIM 128
#define HGT 192
#define WID 192
#define NB 4
#define WFD 97   // 192/2+1

// table offsets (floats)
#define T_COSW 0
#define T_SINW 18624
#define T_COSH 37248
#define T_SINH 74112
#define T_ICOS 110976
#define T_ISIN 129600
#define T_BIAS 148224
// total 164608 < 262144 reserved

typedef __attribute__((ext_vector_type(8))) short bf16x8;
typedef __attribute__((ext_vector_type(4))) float f32x4;

__device__ __forceinline__ float gelu_f(float v){
  return 0.5f*v*(1.0f + erff(v*0.70710678118654752440f));
}
__device__ __forceinline__ unsigned short f2bf(float f){
  unsigned int u = __float_as_uint(f);
  unsigned int r = (u + 0x7FFFu + ((u>>16)&1u)) >> 16;
  return (unsigned short)r;
}

// ---------------- table build ----------------
__global__ __launch_bounds__(256) void build_tables(float* __restrict__ tab, const float* __restrict__ rpb){
  int idx = blockIdx.x*256 + threadIdx.x;
  const double TP = 6.283185307179586476925286766559;
  if (idx < 18624){ // rfft-W matrices: [wf=97][w=192]
    int i = idx/192, j = idx%192;
    double th = TP*((double)(i*j))/192.0;
    tab[T_COSW+idx] = (float)cos(th);
    tab[T_SINW+idx] = (float)sin(th);
    return;
  }
  idx -= 18624;
  if (idx < 36864){ // fft-H matrices: [hf=192][h=192]
    int i = idx/192, j = idx%192;
    double th = TP*((double)(i*j))/192.0;
    tab[T_COSH+idx] = (float)cos(th);
    tab[T_SINH+idx] = (float)sin(th);
    return;
  }
  idx -= 36864;
  if (idx < 18624){ // irfft-W matrices: [w=192][k=97], alpha/(H*W) folded
    int w = idx/97, k = idx%97;
    double th = TP*((double)(k*w))/192.0;
    double a = (k==0 || k==96) ? 1.0 : 2.0;
    double sc = a/36864.0;
    tab[T_ICOS+idx] = (float)(sc*cos(th));
    tab[T_ISIN+idx] = (float)(sc*sin(th));
    return;
  }
  idx -= 18624;
  if (idx < 16384){ // attn bias: [head][n][m]
    int head = idx>>12, n = (idx>>6)&63, m = idx&63;
    int dh = n/16 - m/16 + 3;
    int dw = (n&15) - (m&15) + 15;
    tab[T_BIAS+idx] = rpb[(dh*31+dw)*4 + head];
  }
}

// ---------------- pos depthwise conv (BCHW in -> BHWC out, + residual) ----------------
__global__ __launch_bounds__(256) void posconv_kernel(const float* __restrict__ x, const float* __restrict__ pw,
                               const float* __restrict__ pb, float* __restrict__ xt){
  __shared__ float tile[64*129];
  int w0 = blockIdx.x*64; int h = blockIdx.y; int b = blockIdx.z;
  int tid = threadIdx.x;
  int wl = tid & 63; int cg = tid >> 6;
  int w = w0 + wl;
  for (int ci = 0; ci < 32; ++ci){
    int c = cg*32 + ci;
    const float* xp = x + (size_t)(b*C_DIM + c)*HGT*WID;
    float acc = xp[(size_t)h*WID + w] + pb[c];
    #pragma unroll
    for (int ky=0; ky<3; ky++){
      int hh = h + ky - 1;
      if (hh < 0 || hh >= HGT) continue;
      #pragma unroll
      for (int kx=0; kx<3; kx++){
        int ww = w + kx - 1;
        if (ww < 0 || ww >= WID) continue;
        acc += pw[c*27 + 9 + ky*3 + kx] * xp[(size_t)hh*WID + ww];
      }
    }
    tile[wl*129 + c] = acc;
  }
  __syncthreads();
  for (int r=0; r<32; r++){
    int e = tid + 256*r; int c = e & 127; int wl2 = e >> 7;
    xt[((size_t)(b*HGT+h)*WID + w0 + wl2)*C_DIM + c] = tile[wl2*129 + c];
  }
}

// ---------------- LN row stats (mean, rstd) ----------------
__global__ __launch_bounds__(256) void ln_stats_kernel(const float* __restrict__ src, float* __restrict__ stats){
  int wave = threadIdx.x >> 6; int lane = threadIdx.x & 63;
  size_t p = (size_t)blockIdx.x*4 + wave;
  const float* s = src + p*C_DIM;
  float v0 = s[lane], v1 = s[lane+64];
  float sum = v0 + v1;
  #pragma unroll
  for (int o=1; o<64; o<<=1) sum += __shfl_xor(sum, o, 64);
  float m = sum * (1.0f/128.0f);
  float d0 = v0-m, d1 = v1-m;
  float vs = d0*d0 + d1*d1;
  #pragma unroll
  for (int o=1; o<64; o<<=1) vs += __shfl_xor(vs, o, 64);
  float rstd = rsqrtf(vs*(1.0f/128.0f) + 1e-5f);
  if (lane==0){ stats[2*p] = m; stats[2*p+1] = rstd; }
}

// ---------------- bf16 MFMA GEMM: dst[p,n] = act(A[p,:]@W + bias) (+dst) ----------------
// BM=BN=64, BK=32, 256 thr = 4 waves, each wave one 32x32 quadrant via 4x mfma 16x16x32.
// Requires K%32==0, N%64==0, rows%64==0.
template<int ACT, bool ADD, bool LNA>
__global__ __launch_bounds__(256) void gemm_mfma(const float* __restrict__ A1,
                            const float* __restrict__ Wm, const float* __restrict__ bias,
                            float* __restrict__ dst, int K, int N, int lda,
                            const float* __restrict__ stats, const float* __restrict__ lng,
                            const float* __restrict__ lnb, int prow0, int pmax){
  __shared__ __align__(16) unsigned short As[64*40];  // [m][k] pad 40
  __shared__ __align__(16) unsigned short Bs[64*40];  // [n][k] pad 40
  int p0 = blockIdx.y*64, n0 = blockIdx.x*64;
  int tid = threadIdx.x;
  int wave = tid >> 6, lane = tid & 63;
  int wr = (wave>>1)*32, wc = (wave&1)*32;
  f32x4 acc00 = {}, acc01 = {}, acc10 = {}, acc11 = {};
  int am = tid >> 2, ak = (tid & 3)*8;    // A stage: row, k-start
  int bk = tid >> 3, bn = (tid & 7)*8;    // B stage: k, n-start
  for (int k0 = 0; k0 < K; k0 += 32){
    { // stage A (optionally layernormed) as bf16
      int gp = p0 + am;
      float s0 = 0.f, s1 = 0.f;
      if (LNA){
        gp += prow0;
        gp = gp < 0 ? 0 : (gp > pmax ? pmax : gp);
        s0 = stats[2*gp]; s1 = stats[2*gp+1];
      }
      const float* src = A1 + (size_t)gp*lda + k0 + ak;
      float4 aa = *(const float4*)src;
      float4 ab = *(const float4*)(src+4);
      float v[8] = {aa.x,aa.y,aa.z,aa.w,ab.x,ab.y,ab.z,ab.w};
      unsigned short* dp = &As[am*40 + ak];
      #pragma unroll
      for (int j=0;j<8;j++){
        float f = v[j];
        if (LNA) f = (f - s0)*s1*lng[k0+ak+j] + lnb[k0+ak+j];
        dp[j] = f2bf(f);
      }
    }
    { // stage B transposed: W[k][n] -> Bs[n][k]
      const float* src = Wm + (size_t)(k0+bk)*N + n0 + bn;
      float4 wa = *(const float4*)src;
      float4 wb = *(const float4*)(src+4);
      float v[8] = {wa.x,wa.y,wa.z,wa.w,wb.x,wb.y,wb.z,wb.w};
      #pragma unroll
      for (int j=0;j<8;j++) Bs[(bn+j)*40 + bk] = f2bf(v[j]);
    }
    __syncthreads();
    int fm = lane & 15, kg = (lane>>4)*8;
    bf16x8 a0 = *(const bf16x8*)&As[(wr+fm)*40 + kg];
    bf16x8 a1 = *(const bf16x8*)&As[(wr+16+fm)*40 + kg];
    bf16x8 b0 = *(const bf16x8*)&Bs[(wc+fm)*40 + kg];
    bf16x8 b1 = *(const bf16x8*)&Bs[(wc+16+fm)*40 + kg];
    acc00 = __builtin_amdgcn_mfma_f32_16x16x32_bf16(a0, b0, acc00, 0,0,0);
    acc01 = __builtin_amdgcn_mfma_f32_16x16x32_bf16(a0, b1, acc01, 0,0,0);
    acc10 = __builtin_amdgcn_mfma_f32_16x16x32_bf16(a1, b0, acc10, 0,0,0);
    acc11 = __builtin_amdgcn_mfma_f32_16x16x32_bf16(a1, b1, acc11, 0,0,0);
    __syncthreads();
  }
  // epilogue: D layout col=lane&15, row=(lane>>4)*4+reg
  int cn = lane & 15, rq = (lane>>4)*4;
  #pragma unroll
  for (int mi=0; mi<2; ++mi){
    #pragma unroll
    for (int ni=0; ni<2; ++ni){
      f32x4 a = (mi==0) ? (ni==0?acc00:acc01) : (ni==0?acc10:acc11);
      int n = n0 + wc + ni*16 + cn;
      float bsv = bias[n];
      #pragma unroll
      for (int r=0; r<4; ++r){
        size_t row = (size_t)p0 + wr + mi*16 + rq + r;
        float v = a[r] + bsv;
        if (ACT==1) v = (v>=0.f) ? v : 0.01f*v;
        if (ACT==2) v = gelu_f(v);
        if (ADD) v += dst[row*(size_t)N + n];
        dst[row*(size_t)N + n] = v;
      }
    }
  }
}

// ---------------- light attention: reads precomputed Qc/KVc ----------------
__global__ __launch_bounds__(64) void attn_light(
    const float* __restrict__ Qc, const float* __restrict__ KVc,
    const float* __restrict__ biasT, float* __restrict__ OUTc,
    int win0, int prow0){
  __shared__ float kb[64*36];
  __shared__ float vb[64*36];
  int win = win0 + blockIdx.x, head = blockIdx.y;
  int b = win/576, rem = win%576, whi = rem/12, wwi = rem%12;
  int lane = threadIdx.x;
  int rowbase = (b*HGT + whi*4)*WID + wwi*16;
  int l = (rowbase - prow0) + (lane>>4)*WID + (lane&15);
  {
    const float* kp = KVc + (size_t)l*256 + head*32;
    #pragma unroll
    for (int d4=0; d4<8; ++d4){
      *(float4*)&kb[lane*36+d4*4] = *(const float4*)(kp+d4*4);
      *(float4*)&vb[lane*36+d4*4] = *(const float4*)(kp+128+d4*4);
    }
  }
  float q_[32];
  {
    const float* qp = Qc + (size_t)l*128 + head*32;
    #pragma unroll
    for (int d=0; d<32; ++d) q_[d] = qp[d]*0.17677669529663688f; // 1/sqrt(32)
  }
  __syncthreads();
  float s[64];
  const float* bp = biasT + head*4096 + lane*64;
  for (int m=0;m<64;m++){
    float a = bp[m];
    const float4* k4 = (const float4*)&kb[m*36];
    #pragma unroll
    for (int d4=0; d4<8; ++d4){
      float4 w4 = k4[d4];
      a += q_[d4*4+0]*w4.x + q_[d4*4+1]*w4.y + q_[d4*4+2]*w4.z + q_[d4*4+3]*w4.w;
    }
    s[m] = a;
  }
  float mx = -1e30f;
  for (int m=0;m<64;m++) mx = fmaxf(mx, s[m]);
  float sum = 0.f;
  for (int m=0;m<64;m++){ float e = expf(s[m]-mx); sum += e; s[m] = e; }
  float inv = 1.f/sum;
  float acc[32];
  #pragma unroll
  for (int d=0; d<32; ++d) acc[d]=0.f;
  for (int m=0;m<64;m++){
    float pm = s[m]*inv;
    const float4* v4p = (const float4*)&vb[m*36];
    #pragma unroll
    for (int d4=0; d4<8; ++d4){
      float4 w4 = v4p[d4];
      acc[d4*4+0]+=pm*w4.x; acc[d4*4+1]+=pm*w4.y; acc[d4*4+2]+=pm*w4.z; acc[d4*4+3]+=pm*w4.w;
    }
  }
  float* op = OUTc + (size_t)l*128 + head*32;
  #pragma unroll
  for (int d4=0; d4<8; ++d4) ((float4*)op)[d4] = *(float4*)&acc[d4*4];
}

// ================= DUMB (bulletproof) FFT branch =================
// A: rfft along W. out FR/FI [h][k][c], id = (h*97+k)*128+c
__global__ __launch_bounds__(256) void rfftw_dumb(const float* __restrict__ XTb, float* __restrict__ FR,
                                                  float* __restrict__ FI,
                                                  const float* __restrict__ cosW, const float* __restrict__ sinW){
  int id = blockIdx.x*256 + threadIdx.x;
  int c = id & 127; int t = id >> 7; int k = t % 97; int h = t / 97;
  const float* xp = XTb + (size_t)h*24576 + c;
  const float* cw = cosW + k*192; const float* sw = sinW + k*192;
  float ar = 0.f, ai = 0.f;
  for (int w = 0; w < 192; ++w){
    float v = xp[(size_t)w*128];
    ar += cw[w]*v; ai -= sw[w]*v;
  }
  FR[id] = ar; FI[id] = ai;
}

// B: fft along H (sign -) for k-chunk: out FF0[(kl*192+hf)*256 + {c | c+128}]
__global__ __launch_bounds__(256) void ffth_dumb(const float* __restrict__ FR, const float* __restrict__ FI,
                                                 float* __restrict__ FF0,
                                                 const float* __restrict__ cosH, const float* __restrict__ sinH,
                                                 int k0){
  int id = blockIdx.x*256 + threadIdx.x;      // (kl*192+hf)*128 + c
  int c = id & 127; int t = id >> 7; int hf = t % 192; int kl = t / 192;
  int k = k0 + kl;
  const float* fr = FR + (size_t)k*128 + c;
  const float* fi = FI + (size_t)k*128 + c;
  const float* ch = cosH + hf*192; const float* sh = sinH + hf*192;
  float re = 0.f, im = 0.f;
  for (int h = 0; h < 192; ++h){
    float a = fr[(size_t)h*12416], b = fi[(size_t)h*12416];   // 97*128=12416
    float cv = ch[h], sv = sh[h];
    re += a*cv + b*sv;
    im += b*cv - a*sv;
  }
  size_t row = (size_t)t*256;
  FF0[row + c] = re; FF0[row + c + 128] = im;
}

// D: ifft along H (sign +): in FF rows (kl*192+hf)*256, out GR/GI [h][kl][c] (stride CK)
// reuse-friendly ordering: consecutive blocks share kl (192-fold reuse of the kl slab)
__global__ __launch_bounds__(256) void iffth_dumb(const float* __restrict__ FF, float* __restrict__ GR,
                                                  float* __restrict__ GI,
                                                  const float* __restrict__ cosH, const float* __restrict__ sinH,
                                                  int CK){
  int id = blockIdx.x*256 + threadIdx.x;
  int c = id & 127; int t = id >> 7; int h = t % 192; int kl = t / 192;
  const float* base = FF + (size_t)kl*192*256;
  const float* ch = cosH + h*192; const float* sh = sinH + h*192;
  float re = 0.f, im = 0.f;
  for (int hf = 0; hf < 192; ++hf){
    float a = base[(size_t)hf*256 + c], b = base[(size_t)hf*256 + c + 128];
    float cv = ch[hf], sv = sh[hf];
    re += a*cv - b*sv;
    im += b*cv + a*sv;
  }
  size_t oid = ((size_t)h*CK + kl)*128 + c;
  GR[oid] = re; GI[oid] = im;
}

// E: irfft along W, chunk-accumulate into XTb
__global__ __launch_bounds__(256) void irfftw_dumb(const float* __restrict__ GR, const float* __restrict__ GI,
                                                   float* __restrict__ XTb,
                                                   const float* __restrict__ icos, const float* __restrict__ isin,
                                                   int CK, int k0){
  int id = blockIdx.x*256 + threadIdx.x;      // (h*192+w)*128 + c
  int c = id & 127; int t = id >> 7; int w = t % 192; int h = t / 192;
  const float* gr = GR + (size_t)h*CK*128 + c;
  const float* gi = GI + (size_t)h*CK*128 + c;
  const float* ic = icos + w*97 + k0;
  const float* is = isin + w*97 + k0;
  float acc = 0.f;
  for (int kl = 0; kl < CK; ++kl)
    acc += ic[kl]*gr[(size_t)kl*128] - is[kl]*gi[(size_t)kl*128];
  XTb[id] += acc;
}

// ---------------- LeFF tail: dwconv3x3 + gelu + linear2 + residual (strip) ----------------
__global__ __launch_bounds__(256) void leff_tail_kernel(const float* __restrict__ h1, const float* __restrict__ dw,
                                 const float* __restrict__ db, const float* __restrict__ l2w,
                                 const float* __restrict__ l2b, float* __restrict__ XTp,
                                 int b, int r0){
  __shared__ float t_s[8*516];
  int blk = blockIdx.x;
  int w0 = (blk % 24)*8;
  int h = r0 + blk/24;
  int tid = threadIdx.x;
  for (int r=0;r<16;r++){
    int e = tid + 256*r;
    int ch = e & 511, p = e >> 9;
    int w = w0 + p;
    float acc = db[ch];
    #pragma unroll
    for (int ky=0; ky<3; ky++){
      int hh = h+ky-1;
      if (hh<0 || hh>=HGT) continue;
      int br = hh - r0 + 1;
      #pragma unroll
      for (int kx=0; kx<3; kx++){
        int ww = w+kx-1;
        if (ww<0 || ww>=WID) continue;
        acc += dw[ch*9+ky*3+kx]*h1[((size_t)br*WID + ww)*512 + ch];
      }
    }
    t_s[p*516+ch] = gelu_f(acc);
  }
  __syncthreads();
  int c = tid & 127, pg = tid >> 7;
  #pragma unroll
  for (int pi=0; pi<4; ++pi){
    int p = pg*4 + pi;
    float acc = l2b[c];
    const float* tp = &t_s[p*516];
    for (int ch=0; ch<512; ch+=4){
      float4 t4 = *(const float4*)(tp+ch);
      acc += t4.x*l2w[(ch+0)*128+c] + t4.y*l2w[(ch+1)*128+c]
           + t4.z*l2w[(ch+2)*128+c] + t4.w*l2w[(ch+3)*128+c];
    }
    size_t row = ((size_t)(b*HGT+h))*WID + w0 + p;
    XTp[row*C_DIM + c] += acc;
  }
}

// ---------------- per-batch BHWC -> BCHW transpose (into staging) ----------------
__global__ __launch_bounds__(256) void transpose_b_kernel(const float* __restrict__ src, float* __restrict__ dst){
  __shared__ float tile[128*65];
  int w0 = blockIdx.x*64, h = blockIdx.y;
  int tid = threadIdx.x;
  for (int r=0; r<32; r++){
    int e = tid + 256*r; int c = e & 127, wl = e >> 7;
    tile[c*65 + wl] = src[((size_t)h*WID + w0 + wl)*C_DIM + c];
  }
  __syncthreads();
  for (int r=0; r<32; r++){
    int e = tid + 256*r; int wl = e & 63, c = e >> 6;
    dst[((size_t)c*HGT + h)*WID + w0 + wl] = tile[c*65 + wl];
  }
}

// ---------------- host ----------------
extern "C" void kernel_launch(void* const* d_in, const int* in_sizes, int n_in,
                              void* d_out, int out_size, void* d_ws, size_t ws_size,
                              hipStream_t stream) {
  const float* x      = (const float*)d_in[0];
  const float* pos_w  = (const float*)d_in[1];
  const float* pos_b  = (const float*)d_in[2];
  const float* ln1_g  = (const float*)d_in[3];
  const float* ln1_b  = (const float*)d_in[4];
  const float* q_w    = (const float*)d_in[5];
  const float* q_b    = (const float*)d_in[6];
  const float* kv_w   = (const float*)d_in[7];
  const float* kv_b   = (const float*)d_in[8];
  const float* rpb    = (const float*)d_in[9];
  const float* proj_w = (const float*)d_in[10];
  const float* proj_b = (const float*)d_in[11];
  const float* fft1_w = (const float*)d_in[12];
  const float* fft1_b = (const float*)d_in[13];
  const float* fft2_w = (const float*)d_in[14];
  const float* fft2_b = (const float*)d_in[15];
  const float* ln2_g  = (const float*)d_in[16];
  const float* ln2_b  = (const float*)d_in[17];
  const float* l1_w   = (const float*)d_in[18];
  const float* l1_b   = (const float*)d_in[19];
  const float* dw_w   = (const float*)d_in[20];
  const float* dw_b   = (const float*)d_in[21];
  const float* l2_w   = (const float*)d_in[22];
  const float* l2_b   = (const float*)d_in[23];

  const size_t S   = (size_t)NB*HGT*WID*C_DIM;   // 18,874,368
  const size_t Sb  = S/NB;                       //  4,718,592
  const size_t SZb = (size_t)HGT*WFD*C_DIM;      //  2,383,872
  const int    P   = (int)(NB*HGT*WID);          // 147,456

  float* XT = (float*)d_out;

  float* ws    = (float*)d_ws;
  float* TAB   = ws;
  float* STATS = ws + 262144;
  float* POOL  = ws + 262144 + 2*(size_t)P;
  size_t pool  = (ws_size/4 > 557056) ? (ws_size/4 - 557056) : 0;

  const float* cosW = TAB + T_COSW; const float* sinW = TAB + T_SINW;
  const float* cosH = TAB + T_COSH; const float* sinH = TAB + T_SINH;
  const float* icos = TAB + T_ICOS; const float* isin = TAB + T_ISIN;
  const float* biasT = TAB + T_BIAS;

  int SH = 32;
  while ((size_t)2*(SH+2)*WID*512 > pool && SH > 8) SH >>= 1;

  build_tables<<<354, 256, 0, stream>>>(TAB, rpb);
  posconv_kernel<<<dim3(3,192,4), 256, 0, stream>>>(x, pos_w, pos_b, XT);

  // ---- attention: LN1 stats -> per-chunk {q gemm, kv gemm, attn, proj gemm} ----
  ln_stats_kernel<<<P/4, 256, 0, stream>>>(XT, STATS);
  {
    int winChunk = (int)((pool/(64*512)/12)*12);   // chunk needs R*512 floats
    if (winChunk < 12) winChunk = 12;
    if (winChunk > 2304) winChunk = 2304;
    for (int w0 = 0; w0 < 2304; w0 += winChunk){
      int nw = (2304 - w0 < winChunk) ? (2304 - w0) : winChunk;
      int R = nw*64, prow0 = w0*64;
      float* Qc   = POOL;
      float* KVc  = POOL + (size_t)R*128;
      float* OUTc = POOL + (size_t)R*384;
      gemm_mfma<0,false,true><<<dim3(2, R/64), 256, 0, stream>>>(
          XT, q_w, q_b, Qc, 128, 128, 128, STATS, ln1_g, ln1_b, prow0, P-1);
      gemm_mfma<0,false,true><<<dim3(4, R/64), 256, 0, stream>>>(
          XT, kv_w, kv_b, KVc, 128, 256, 128, STATS, ln1_g, ln1_b, prow0, P-1);
      attn_light<<<dim3(nw, 4), 64, 0, stream>>>(Qc, KVc, biasT, OUTc, w0, prow0);
      gemm_mfma<0,true,false><<<dim3(2, R/64), 256, 0, stream>>>(
          OUTc, proj_w, proj_b, XT + (size_t)prow0*C_DIM,
          128, 128, 128, nullptr, nullptr, nullptr, 0, 0);
    }
  }

  // ---- FFT residual branch: dumb DFTs + MFMA mixes, chunked over k ----
  {
    int CK = 1;
    if (pool > 2*SZb + 147456) CK = (int)((pool - 2*SZb)/147456);
    if (CK < 1) CK = 1;
    if (CK > WFD) CK = WFD;
    float* FR  = POOL;
    float* FI  = POOL + SZb;
    float* FF0 = POOL + 2*SZb;                 // CK*192*256
    float* FF1 = FF0 + (size_t)CK*49152;       // CK*192*256
    float* GR  = FF1 + (size_t)CK*49152;       // CK*192*128
    float* GI  = GR  + (size_t)CK*24576;       // CK*192*128
    for (int b = 0; b < NB; ++b){
      float* XTb = XT + (size_t)b*Sb;
      rfftw_dumb<<<9312, 256, 0, stream>>>(XTb, FR, FI, cosW, sinW);
      for (int k0 = 0; k0 < WFD; k0 += CK){
        int ck = (WFD - k0 < CK) ? (WFD - k0) : CK;
        int rows = ck*192;
        ffth_dumb<<<ck*96, 256, 0, stream>>>(FR, FI, FF0, cosH, sinH, k0);
        gemm_mfma<1,false,false><<<dim3(4, rows/64), 256, 0, stream>>>(
            FF0, fft1_w, fft1_b, FF1, 256, 256, 256,
            nullptr, nullptr, nullptr, 0, 0);
        gemm_mfma<0,false,false><<<dim3(4, rows/64), 256, 0, stream>>>(
            FF1, fft2_w, fft2_b, FF0, 256, 256, 256,
            nullptr, nullptr, nullptr, 0, 0);
        iffth_dumb<<<ck*96, 256, 0, stream>>>(FF0, GR, GI, cosH, sinH, ck);
        irfftw_dumb<<<18432, 256, 0, stream>>>(GR, GI, XTb, icos, isin, ck, k0);
      }
    }
  }

  // ---- LN2 stats ----
  ln_stats_kernel<<<P/4, 256, 0, stream>>>(XT, STATS);

  // ---- LeFF, strip-mined ----
  {
    const size_t SBSZ = (size_t)(SH+2)*WID*512;
    float* SB[2] = { POOL, POOL + SBSZ };
    int nStrips = HGT/SH;
    for (int b = 0; b < NB; ++b){
      auto launch_g = [&](int s){
        int r0 = s*SH;
        int prow0 = (b*HGT + r0 - 1)*WID;
        gemm_mfma<2,false,true><<<dim3(8, (SH+2)*3), 256, 0, stream>>>(
            XT, l1_w, l1_b, SB[s&1], 128, 512, 128,
            STATS, ln2_g, ln2_b, prow0, P-1);
      };
      launch_g(0);
      for (int s = 0; s < nStrips; ++s){
        if (s+1 < nStrips) launch_g(s+1);
        leff_tail_kernel<<<24*SH, 256, 0, stream>>>(SB[s&1], dw_w, dw_b, l2_w, l2_b,
                                                    XT, b, s*SH);
      }
    }
  }

  // ---- final transpose per batch: XT(BHWC, in d_out) -> POOL(BCHW) -> copy back ----
  for (int b = 0; b < NB; ++b){
    transpose_b_kernel<<<dim3(3,192), 256, 0, stream>>>(XT + (size_t)b*Sb, POOL);
    hipMemcpyAsync((float*)d_out + (size_t)b*Sb, POOL, Sb*sizeof(float),
                   hipMemcpyDeviceToDevice, stream);
  }
}

// Round 7
// 4820.196 us; speedup vs baseline: 2.1575x; 1.3745x over previous
//
#include <hip/hip_runtime.h>
#include <math.h>

// ---------------- constants ----------------
#define C_DIM 128
#define HGT 192
#define WID 192
#define NB 4
#define WFD 97   // 192/2+1

// table offsets (floats)
#define T_COSW 0
#define T_SINW 18624
#define T_COSH 37248
#define T_SINH 74112
#define T_ICOS 110976
#define T_ISIN 129600
#define T_BIAS 148224
// total 164608 < 262144 reserved

typedef __attribute__((ext_vector_type(8))) short bf16x8;
typedef __attribute__((ext_vector_type(4))) float f32x4;

__device__ __forceinline__ float gelu_f(float v){
  return 0.5f*v*(1.0f + erff(v*0.70710678118654752440f));
}
__device__ __forceinline__ unsigned short f2bf(float f){
  unsigned int u = __float_as_uint(f);
  unsigned int r = (u + 0x7FFFu + ((u>>16)&1u)) >> 16;
  return (unsigned short)r;
}

// ---------------- table build ----------------
__global__ __launch_bounds__(256) void build_tables(float* __restrict__ tab, const float* __restrict__ rpb){
  int idx = blockIdx.x*256 + threadIdx.x;
  const double TP = 6.283185307179586476925286766559;
  if (idx < 18624){ // rfft-W matrices: [wf=97][w=192]
    int i = idx/192, j = idx%192;
    double th = TP*((double)(i*j))/192.0;
    tab[T_COSW+idx] = (float)cos(th);
    tab[T_SINW+idx] = (float)sin(th);
    return;
  }
  idx -= 18624;
  if (idx < 36864){ // fft-H matrices: [hf=192][h=192]
    int i = idx/192, j = idx%192;
    double th = TP*((double)(i*j))/192.0;
    tab[T_COSH+idx] = (float)cos(th);
    tab[T_SINH+idx] = (float)sin(th);
    return;
  }
  idx -= 36864;
  if (idx < 18624){ // irfft-W matrices: [w=192][k=97], alpha/(H*W) folded
    int w = idx/97, k = idx%97;
    double th = TP*((double)(k*w))/192.0;
    double a = (k==0 || k==96) ? 1.0 : 2.0;
    double sc = a/36864.0;
    tab[T_ICOS+idx] = (float)(sc*cos(th));
    tab[T_ISIN+idx] = (float)(sc*sin(th));
    return;
  }
  idx -= 18624;
  if (idx < 16384){ // attn bias: [head][n][m]
    int head = idx>>12, n = (idx>>6)&63, m = idx&63;
    int dh = n/16 - m/16 + 3;
    int dw = (n&15) - (m&15) + 15;
    tab[T_BIAS+idx] = rpb[(dh*31+dw)*4 + head];
  }
}

// ---------------- pos depthwise conv v2: LDS row staging, 8h x 64w x 16c batches ----------------
__global__ __launch_bounds__(256) void posconv2_kernel(const float* __restrict__ x, const float* __restrict__ pw,
                               const float* __restrict__ pb, float* __restrict__ xt){
  __shared__ float rows_s[16*660];    // [c][r(10)][wc(66)]
  __shared__ float outt[8*64*17];     // [(h*64+w)*17 + cl]
  int w0 = blockIdx.x*64, h0 = blockIdx.y*8, b = blockIdx.z;
  int tid = threadIdx.x;
  int hl = tid >> 6, wl = tid & 63;
  for (int cb = 0; cb < 128; cb += 16){
    // stage 16 channels x 10 rows x 66 cols (zero-padded)
    for (int e = tid; e < 16*660; e += 256){
      int c = e / 660; int rem = e - c*660;
      int r = rem / 66; int wc = rem - r*66;
      int gh = h0 - 1 + r, gw = w0 - 1 + wc;
      float v = 0.f;
      if (gh >= 0 && gh < HGT && gw >= 0 && gw < WID)
        v = x[((size_t)(b*C_DIM + cb + c))*(HGT*WID) + gh*WID + gw];
      rows_s[e] = v;
    }
    __syncthreads();
    // compute 8x64 outputs per channel
    for (int c = 0; c < 16; ++c){
      const float* rs = &rows_s[c*660];
      float wreg[9];
      #pragma unroll
      for (int t9 = 0; t9 < 9; ++t9) wreg[t9] = pw[(cb+c)*27 + 9 + t9];
      float bias = pb[cb+c];
      #pragma unroll
      for (int j = 0; j < 2; ++j){
        int hh = hl*2 + j;
        float acc = rs[(hh+1)*66 + wl+1] + bias;
        #pragma unroll
        for (int ky = 0; ky < 3; ++ky)
          #pragma unroll
          for (int kx = 0; kx < 3; ++kx)
            acc += wreg[ky*3+kx]*rs[(hh+ky)*66 + wl+kx];
        outt[(hh*64+wl)*17 + c] = acc;
      }
    }
    __syncthreads();
    // flush c-coalesced (64B segments)
    for (int r = 0; r < 32; ++r){
      int e = r*256 + tid;
      int cl = e & 15, hw = e >> 4;
      int h = hw >> 6, w = hw & 63;
      xt[((size_t)(b*HGT + h0+h)*WID + (w0+w))*C_DIM + cb + cl] = outt[(h*64+w)*17 + cl];
    }
    __syncthreads();
  }
}

// ---------------- LN row stats (mean, rstd) ----------------
__global__ __launch_bounds__(256) void ln_stats_kernel(const float* __restrict__ src, float* __restrict__ stats){
  int wave = threadIdx.x >> 6; int lane = threadIdx.x & 63;
  size_t p = (size_t)blockIdx.x*4 + wave;
  const float* s = src + p*C_DIM;
  float v0 = s[lane], v1 = s[lane+64];
  float sum = v0 + v1;
  #pragma unroll
  for (int o=1; o<64; o<<=1) sum += __shfl_xor(sum, o, 64);
  float m = sum * (1.0f/128.0f);
  float d0 = v0-m, d1 = v1-m;
  float vs = d0*d0 + d1*d1;
  #pragma unroll
  for (int o=1; o<64; o<<=1) vs += __shfl_xor(vs, o, 64);
  float rstd = rsqrtf(vs*(1.0f/128.0f) + 1e-5f);
  if (lane==0){ stats[2*p] = m; stats[2*p+1] = rstd; }
}

// ---------------- bf16 MFMA GEMM ----------------
template<int ACT, bool ADD, bool LNA>
__global__ __launch_bounds__(256) void gemm_mfma(const float* __restrict__ A1,
                            const float* __restrict__ Wm, const float* __restrict__ bias,
                            float* __restrict__ dst, int K, int N, int lda,
                            const float* __restrict__ stats, const float* __restrict__ lng,
                            const float* __restrict__ lnb, int prow0, int pmax){
  __shared__ __align__(16) unsigned short As[64*40];  // [m][k] pad 40
  __shared__ __align__(16) unsigned short Bs[64*40];  // [n][k] pad 40
  int p0 = blockIdx.y*64, n0 = blockIdx.x*64;
  int tid = threadIdx.x;
  int wave = tid >> 6, lane = tid & 63;
  int wr = (wave>>1)*32, wc = (wave&1)*32;
  f32x4 acc00 = {}, acc01 = {}, acc10 = {}, acc11 = {};
  int am = tid >> 2, ak = (tid & 3)*8;
  int bk = tid >> 3, bn = (tid & 7)*8;
  for (int k0 = 0; k0 < K; k0 += 32){
    {
      int gp = p0 + am;
      float s0 = 0.f, s1 = 0.f;
      if (LNA){
        gp += prow0;
        gp = gp < 0 ? 0 : (gp > pmax ? pmax : gp);
        s0 = stats[2*gp]; s1 = stats[2*gp+1];
      }
      const float* src = A1 + (size_t)gp*lda + k0 + ak;
      float4 aa = *(const float4*)src;
      float4 ab = *(const float4*)(src+4);
      float v[8] = {aa.x,aa.y,aa.z,aa.w,ab.x,ab.y,ab.z,ab.w};
      unsigned short* dp = &As[am*40 + ak];
      #pragma unroll
      for (int j=0;j<8;j++){
        float f = v[j];
        if (LNA) f = (f - s0)*s1*lng[k0+ak+j] + lnb[k0+ak+j];
        dp[j] = f2bf(f);
      }
    }
    {
      const float* src = Wm + (size_t)(k0+bk)*N + n0 + bn;
      float4 wa = *(const float4*)src;
      float4 wb = *(const float4*)(src+4);
      float v[8] = {wa.x,wa.y,wa.z,wa.w,wb.x,wb.y,wb.z,wb.w};
      #pragma unroll
      for (int j=0;j<8;j++) Bs[(bn+j)*40 + bk] = f2bf(v[j]);
    }
    __syncthreads();
    int fm = lane & 15, kg = (lane>>4)*8;
    bf16x8 a0 = *(const bf16x8*)&As[(wr+fm)*40 + kg];
    bf16x8 a1 = *(const bf16x8*)&As[(wr+16+fm)*40 + kg];
    bf16x8 b0 = *(const bf16x8*)&Bs[(wc+fm)*40 + kg];
    bf16x8 b1 = *(const bf16x8*)&Bs[(wc+16+fm)*40 + kg];
    acc00 = __builtin_amdgcn_mfma_f32_16x16x32_bf16(a0, b0, acc00, 0,0,0);
    acc01 = __builtin_amdgcn_mfma_f32_16x16x32_bf16(a0, b1, acc01, 0,0,0);
    acc10 = __builtin_amdgcn_mfma_f32_16x16x32_bf16(a1, b0, acc10, 0,0,0);
    acc11 = __builtin_amdgcn_mfma_f32_16x16x32_bf16(a1, b1, acc11, 0,0,0);
    __syncthreads();
  }
  int cn = lane & 15, rq = (lane>>4)*4;
  #pragma unroll
  for (int mi=0; mi<2; ++mi){
    #pragma unroll
    for (int ni=0; ni<2; ++ni){
      f32x4 a = (mi==0) ? (ni==0?acc00:acc01) : (ni==0?acc10:acc11);
      int n = n0 + wc + ni*16 + cn;
      float bsv = bias[n];
      #pragma unroll
      for (int r=0; r<4; ++r){
        size_t row = (size_t)p0 + wr + mi*16 + rq + r;
        float v = a[r] + bsv;
        if (ACT==1) v = (v>=0.f) ? v : 0.01f*v;
        if (ACT==2) v = gelu_f(v);
        if (ADD) v += dst[row*(size_t)N + n];
        dst[row*(size_t)N + n] = v;
      }
    }
  }
}

// ---------------- light attention ----------------
__global__ __launch_bounds__(64) void attn_light(
    const float* __restrict__ Qc, const float* __restrict__ KVc,
    const float* __restrict__ biasT, float* __restrict__ OUTc,
    int win0, int prow0){
  __shared__ float kb[64*36];
  __shared__ float vb[64*36];
  int win = win0 + blockIdx.x, head = blockIdx.y;
  int b = win/576, rem = win%576, whi = rem/12, wwi = rem%12;
  int lane = threadIdx.x;
  int rowbase = (b*HGT + whi*4)*WID + wwi*16;
  int l = (rowbase - prow0) + (lane>>4)*WID + (lane&15);
  {
    const float* kp = KVc + (size_t)l*256 + head*32;
    #pragma unroll
    for (int d4=0; d4<8; ++d4){
      *(float4*)&kb[lane*36+d4*4] = *(const float4*)(kp+d4*4);
      *(float4*)&vb[lane*36+d4*4] = *(const float4*)(kp+128+d4*4);
    }
  }
  float q_[32];
  {
    const float* qp = Qc + (size_t)l*128 + head*32;
    #pragma unroll
    for (int d=0; d<32; ++d) q_[d] = qp[d]*0.17677669529663688f;
  }
  __syncthreads();
  float s[64];
  const float* bp = biasT + head*4096 + lane*64;
  for (int m=0;m<64;m++){
    float a = bp[m];
    const float4* k4 = (const float4*)&kb[m*36];
    #pragma unroll
    for (int d4=0; d4<8; ++d4){
      float4 w4 = k4[d4];
      a += q_[d4*4+0]*w4.x + q_[d4*4+1]*w4.y + q_[d4*4+2]*w4.z + q_[d4*4+3]*w4.w;
    }
    s[m] = a;
  }
  float mx = -1e30f;
  for (int m=0;m<64;m++) mx = fmaxf(mx, s[m]);
  float sum = 0.f;
  for (int m=0;m<64;m++){ float e = expf(s[m]-mx); sum += e; s[m] = e; }
  float inv = 1.f/sum;
  float acc[32];
  #pragma unroll
  for (int d=0; d<32; ++d) acc[d]=0.f;
  for (int m=0;m<64;m++){
    float pm = s[m]*inv;
    const float4* v4p = (const float4*)&vb[m*36];
    #pragma unroll
    for (int d4=0; d4<8; ++d4){
      float4 w4 = v4p[d4];
      acc[d4*4+0]+=pm*w4.x; acc[d4*4+1]+=pm*w4.y; acc[d4*4+2]+=pm*w4.z; acc[d4*4+3]+=pm*w4.w;
    }
  }
  float* op = OUTc + (size_t)l*128 + head*32;
  #pragma unroll
  for (int d4=0; d4<8; ++d4) ((float4*)op)[d4] = *(float4*)&acc[d4*4];
}

// ================= fp32 DFT branch (4-way output tiling, exact math) =================
// A: rfft along W. 4 k per thread share the data load. out FR/FI [h][k][c].
__global__ __launch_bounds__(256) void rfftw_dumb(const float* __restrict__ XTb, float* __restrict__ FR,
                                                  float* __restrict__ FI,
                                                  const float* __restrict__ cosW, const float* __restrict__ sinW){
  int id = blockIdx.x*256 + threadIdx.x;      // (h*25+kg)*128 + c
  int c = id & 127; int t = id >> 7; int kg = t % 25; int h = t / 25;
  int ks = kg*4;
  const float* xp = XTb + (size_t)h*24576 + c;
  int kk[4];
  #pragma unroll
  for (int j=0;j<4;j++){ int k = ks+j; kk[j] = k > 96 ? 96 : k; }
  float ar[4] = {}, ai[4] = {};
  for (int w = 0; w < 192; ++w){
    float v = xp[(size_t)w*128];
    #pragma unroll
    for (int j=0;j<4;j++){
      ar[j] += cosW[kk[j]*192+w]*v;
      ai[j] -= sinW[kk[j]*192+w]*v;
    }
  }
  #pragma unroll
  for (int j=0;j<4;j++){
    int k = ks+j;
    if (k < 97){
      size_t o = ((size_t)h*97 + k)*128 + c;
      FR[o] = ar[j]; FI[o] = ai[j];
    }
  }
}

// B: fft along H (sign -): 4 hf per thread share data loads. out FF0 rows (kl*192+hf)*256.
__global__ __launch_bounds__(256) void ffth_dumb(const float* __restrict__ FR, const float* __restrict__ FI,
                                                 float* __restrict__ FF0,
                                                 const float* __restrict__ cosH, const float* __restrict__ sinH,
                                                 int k0){
  int id = blockIdx.x*256 + threadIdx.x;      // (kl*48+hfg)*128 + c
  int c = id & 127; int t = id >> 7; int hfg = t % 48; int kl = t / 48;
  int k = k0 + kl;
  const float* fr = FR + (size_t)k*128 + c;
  const float* fi = FI + (size_t)k*128 + c;
  int hf0 = hfg*4;
  float re[4] = {}, im[4] = {};
  for (int h = 0; h < 192; ++h){
    float a = fr[(size_t)h*12416], b = fi[(size_t)h*12416];
    #pragma unroll
    for (int j=0;j<4;j++){
      float cv = cosH[(hf0+j)*192 + h], sv = sinH[(hf0+j)*192 + h];
      re[j] += a*cv + b*sv;
      im[j] += b*cv - a*sv;
    }
  }
  #pragma unroll
  for (int j=0;j<4;j++){
    size_t row = ((size_t)kl*192 + hf0+j)*256;
    FF0[row + c] = re[j]; FF0[row + c + 128] = im[j];
  }
}

// D: ifft along H (sign +): 4 h per thread. out GR/GI [h][kl][c].
__global__ __launch_bounds__(256) void iffth_dumb(const float* __restrict__ FF, float* __restrict__ GR,
                                                  float* __restrict__ GI,
                                                  const float* __restrict__ cosH, const float* __restrict__ sinH,
                                                  int CK){
  int id = blockIdx.x*256 + threadIdx.x;      // (kl*48+hg)*128 + c
  int c = id & 127; int t = id >> 7; int hg = t % 48; int kl = t / 48;
  const float* base = FF + (size_t)kl*192*256;
  int h0 = hg*4;
  float re[4] = {}, im[4] = {};
  for (int hf = 0; hf < 192; ++hf){
    float a = base[(size_t)hf*256 + c], b = base[(size_t)hf*256 + c + 128];
    #pragma unroll
    for (int j=0;j<4;j++){
      float cv = cosH[(h0+j)*192 + hf], sv = sinH[(h0+j)*192 + hf];
      re[j] += a*cv - b*sv;
      im[j] += b*cv + a*sv;
    }
  }
  #pragma unroll
  for (int j=0;j<4;j++){
    size_t oid = ((size_t)(h0+j)*CK + kl)*128 + c;
    GR[oid] = re[j]; GI[oid] = im[j];
  }
}

// E: irfft along W: 4 w per thread share data loads; accumulate into XTb.
__global__ __launch_bounds__(256) void irfftw_dumb(const float* __restrict__ GR, const float* __restrict__ GI,
                                                   float* __restrict__ XTb,
                                                   const float* __restrict__ icos, const float* __restrict__ isin,
                                                   int CK, int k0){
  int id = blockIdx.x*256 + threadIdx.x;      // (h*48+wg)*128 + c
  int c = id & 127; int t = id >> 7; int wg = t % 48; int h = t / 48;
  const float* gr = GR + (size_t)h*CK*128 + c;
  const float* gi = GI + (size_t)h*CK*128 + c;
  int w0 = wg*4;
  float acc[4] = {};
  for (int kl = 0; kl < CK; ++kl){
    float a = gr[(size_t)kl*128], b = gi[(size_t)kl*128];
    #pragma unroll
    for (int j=0;j<4;j++)
      acc[j] += icos[(w0+j)*97 + k0 + kl]*a - isin[(w0+j)*97 + k0 + kl]*b;
  }
  #pragma unroll
  for (int j=0;j<4;j++)
    XTb[((size_t)h*192 + w0+j)*128 + c] += acc[j];
}

// ---------------- LeFF dwconv strip: SB1[(SH+2)*192*512] -> gelu(dwconv) -> SB2[SH*192*512] ----------------
__global__ __launch_bounds__(256) void dwconv_strip(const float* __restrict__ SB1, const float* __restrict__ dw,
                                                    const float* __restrict__ db, float* __restrict__ SB2,
                                                    int r0){
  int id = blockIdx.x*256 + threadIdx.x;      // (hl*192+w)*512 + ch
  int ch = id & 511; int t = id >> 9; int w = t % 192; int hl = t / 192;
  int h = r0 + hl;
  float acc = db[ch];
  #pragma unroll
  for (int ky=0; ky<3; ky++){
    int hh = h+ky-1;
    if (hh<0 || hh>=HGT) continue;
    int br = hl + ky;
    #pragma unroll
    for (int kx=0; kx<3; kx++){
      int ww = w+kx-1;
      if (ww<0 || ww>=WID) continue;
      acc += dw[ch*9+ky*3+kx]*SB1[((size_t)br*WID + ww)*512 + ch];
    }
  }
  SB2[id] = gelu_f(acc);
}

// ---------------- per-batch BHWC -> BCHW transpose (into staging) ----------------
__global__ __launch_bounds__(256) void transpose_b_kernel(const float* __restrict__ src, float* __restrict__ dst){
  __shared__ float tile[128*65];
  int w0 = blockIdx.x*64, h = blockIdx.y;
  int tid = threadIdx.x;
  for (int r=0; r<32; r++){
    int e = tid + 256*r; int c = e & 127, wl = e >> 7;
    tile[c*65 + wl] = src[((size_t)h*WID + w0 + wl)*C_DIM + c];
  }
  __syncthreads();
  for (int r=0; r<32; r++){
    int e = tid + 256*r; int wl = e & 63, c = e >> 6;
    dst[((size_t)c*HGT + h)*WID + w0 + wl] = tile[c*65 + wl];
  }
}

// ---------------- host ----------------
extern "C" void kernel_launch(void* const* d_in, const int* in_sizes, int n_in,
                              void* d_out, int out_size, void* d_ws, size_t ws_size,
                              hipStream_t stream) {
  const float* x      = (const float*)d_in[0];
  const float* pos_w  = (const float*)d_in[1];
  const float* pos_b  = (const float*)d_in[2];
  const float* ln1_g  = (const float*)d_in[3];
  const float* ln1_b  = (const float*)d_in[4];
  const float* q_w    = (const float*)d_in[5];
  const float* q_b    = (const float*)d_in[6];
  const float* kv_w   = (const float*)d_in[7];
  const float* kv_b   = (const float*)d_in[8];
  const float* rpb    = (const float*)d_in[9];
  const float* proj_w = (const float*)d_in[10];
  const float* proj_b = (const float*)d_in[11];
  const float* fft1_w = (const float*)d_in[12];
  const float* fft1_b = (const float*)d_in[13];
  const float* fft2_w = (const float*)d_in[14];
  const float* fft2_b = (const float*)d_in[15];
  const float* ln2_g  = (const float*)d_in[16];
  const float* ln2_b  = (const float*)d_in[17];
  const float* l1_w   = (const float*)d_in[18];
  const float* l1_b   = (const float*)d_in[19];
  const float* dw_w   = (const float*)d_in[20];
  const float* dw_b   = (const float*)d_in[21];
  const float* l2_w   = (const float*)d_in[22];
  const float* l2_b   = (const float*)d_in[23];

  const size_t S   = (size_t)NB*HGT*WID*C_DIM;   // 18,874,368
  const size_t Sb  = S/NB;                       //  4,718,592
  const size_t SZb = (size_t)HGT*WFD*C_DIM;      //  2,383,872
  const int    P   = (int)(NB*HGT*WID);          // 147,456

  float* XT = (float*)d_out;

  float* ws    = (float*)d_ws;
  float* TAB   = ws;
  float* STATS = ws + 262144;
  float* POOL  = ws + 262144 + 2*(size_t)P;
  size_t pool  = (ws_size/4 > 557056) ? (ws_size/4 - 557056) : 0;

  const float* cosW = TAB + T_COSW; const float* sinW = TAB + T_SINW;
  const float* cosH = TAB + T_COSH; const float* sinH = TAB + T_SINH;
  const float* icos = TAB + T_ICOS; const float* isin = TAB + T_ISIN;
  const float* biasT = TAB + T_BIAS;

  build_tables<<<354, 256, 0, stream>>>(TAB, rpb);
  posconv2_kernel<<<dim3(3,24,4), 256, 0, stream>>>(x, pos_w, pos_b, XT);

  // ---- attention: LN1 stats -> per-chunk {q gemm, kv gemm, attn, proj gemm} ----
  ln_stats_kernel<<<P/4, 256, 0, stream>>>(XT, STATS);
  {
    int winChunk = (int)((pool/(64*512)/12)*12);
    if (winChunk < 12) winChunk = 12;
    if (winChunk > 2304) winChunk = 2304;
    for (int w0 = 0; w0 < 2304; w0 += winChunk){
      int nw = (2304 - w0 < winChunk) ? (2304 - w0) : winChunk;
      int R = nw*64, prow0 = w0*64;
      float* Qc   = POOL;
      float* KVc  = POOL + (size_t)R*128;
      float* OUTc = POOL + (size_t)R*384;
      gemm_mfma<0,false,true><<<dim3(2, R/64), 256, 0, stream>>>(
          XT, q_w, q_b, Qc, 128, 128, 128, STATS, ln1_g, ln1_b, prow0, P-1);
      gemm_mfma<0,false,true><<<dim3(4, R/64), 256, 0, stream>>>(
          XT, kv_w, kv_b, KVc, 128, 256, 128, STATS, ln1_g, ln1_b, prow0, P-1);
      attn_light<<<dim3(nw, 4), 64, 0, stream>>>(Qc, KVc, biasT, OUTc, w0, prow0);
      gemm_mfma<0,true,false><<<dim3(2, R/64), 256, 0, stream>>>(
          OUTc, proj_w, proj_b, XT + (size_t)prow0*C_DIM,
          128, 128, 128, nullptr, nullptr, nullptr, 0, 0);
    }
  }

  // ---- FFT residual branch: fp32 DFTs (4-way tiled) + MFMA mixes, chunked over k ----
  {
    int CK = 1;
    if (pool > 2*SZb + 147456) CK = (int)((pool - 2*SZb)/147456);
    if (CK < 1) CK = 1;
    if (CK > WFD) CK = WFD;
    float* FR  = POOL;
    float* FI  = POOL + SZb;
    float* FF0 = POOL + 2*SZb;                 // CK*192*256
    float* FF1 = FF0 + (size_t)CK*49152;       // CK*192*256
    float* GR  = FF1 + (size_t)CK*49152;       // CK*192*128
    float* GI  = GR  + (size_t)CK*24576;       // CK*192*128
    for (int b = 0; b < NB; ++b){
      float* XTb = XT + (size_t)b*Sb;
      rfftw_dumb<<<2400, 256, 0, stream>>>(XTb, FR, FI, cosW, sinW);
      for (int k0 = 0; k0 < WFD; k0 += CK){
        int ck = (WFD - k0 < CK) ? (WFD - k0) : CK;
        int rows = ck*192;
        ffth_dumb<<<ck*24, 256, 0, stream>>>(FR, FI, FF0, cosH, sinH, k0);
        gemm_mfma<1,false,false><<<dim3(4, rows/64), 256, 0, stream>>>(
            FF0, fft1_w, fft1_b, FF1, 256, 256, 256,
            nullptr, nullptr, nullptr, 0, 0);
        gemm_mfma<0,false,false><<<dim3(4, rows/64), 256, 0, stream>>>(
            FF1, fft2_w, fft2_b, FF0, 256, 256, 256,
            nullptr, nullptr, nullptr, 0, 0);
        iffth_dumb<<<ck*24, 256, 0, stream>>>(FF0, GR, GI, cosH, sinH, ck);
        irfftw_dumb<<<4608, 256, 0, stream>>>(GR, GI, XTb, icos, isin, ck, k0);
      }
    }
  }

  // ---- LN2 stats ----
  ln_stats_kernel<<<P/4, 256, 0, stream>>>(XT, STATS);

  // ---- LeFF: strip-mined l1 gemm -> dwconv+gelu -> l2 MFMA gemm (+residual) ----
  {
    int SH = 32;
    while ((size_t)(3*SH+4)*98304 > pool && SH > 8) SH >>= 1;
    const size_t SB1SZ = (size_t)(SH+2)*98304;
    float* SB1[2] = { POOL, POOL + SB1SZ };
    float* SB2 = POOL + 2*SB1SZ;
    int nStrips = HGT/SH;
    for (int b = 0; b < NB; ++b){
      auto launch_g = [&](int s){
        int r0 = s*SH;
        int prow0 = (b*HGT + r0 - 1)*WID;
        gemm_mfma<2,false,true><<<dim3(8, (SH+2)*3), 256, 0, stream>>>(
            XT, l1_w, l1_b, SB1[s&1], 128, 512, 128,
            STATS, ln2_g, ln2_b, prow0, P-1);
      };
      launch_g(0);
      for (int s = 0; s < nStrips; ++s){
        if (s+1 < nStrips) launch_g(s+1);
        int r0 = s*SH;
        dwconv_strip<<<SH*384, 256, 0, stream>>>(SB1[s&1], dw_w, dw_b, SB2, r0);
        gemm_mfma<0,true,false><<<dim3(2, SH*3), 256, 0, stream>>>(
            SB2, l2_w, l2_b, XT + ((size_t)(b*HGT + r0)*WID)*C_DIM,
            512, 128, 512, nullptr, nullptr, nullptr, 0, 0);
      }
    }
  }

  // ---- final transpose per batch: XT(BHWC, in d_out) -> POOL(BCHW) -> copy back ----
  for (int b = 0; b < NB; ++b){
    transpose_b_kernel<<<dim3(3,192), 256, 0, stream>>>(XT + (size_t)b*Sb, POOL);
    hipMemcpyAsync((float*)d_out + (size_t)b*Sb, POOL, Sb*sizeof(float),
                   hipMemcpyDeviceToDevice, stream);
  }
}

// Round 8
// 2641.069 us; speedup vs baseline: 3.9377x; 1.8251x over previous
//
#include <hip/hip_runtime.h>
#include <math.h>

// ---------------- constants ----------------
#define C_DIM 128
#define HGT 192
#define WID 192
#define NB 4
#define WFD 97   // 192/2+1

// table offsets (floats)
#define T_COSW 0
#define T_SINW 18624
#define T_COSH 37248
#define T_SINH 74112
#define T_ICOS 110976
#define T_ISIN 129600
#define T_BIAS 148224
#define T_MW   164608            // 256x192 combined rfft-W matrix
#define T_MHF  213760            // 384x384 combined fft-H matrix
#define T_MHI  361216            // 384x384 combined ifft-H matrix
#define T_MWI  508672            // 192x224 combined irfft-W matrix
#define TAB_SZ 557056            // table reserve (floats)

typedef __attribute__((ext_vector_type(8))) short bf16x8;
typedef __attribute__((ext_vector_type(4))) float f32x4;

__device__ __forceinline__ float gelu_f(float v){
  return 0.5f*v*(1.0f + erff(v*0.70710678118654752440f));
}
__device__ __forceinline__ unsigned short f2bf(float f){
  unsigned int u = __float_as_uint(f);
  unsigned int r = (u + 0x7FFFu + ((u>>16)&1u)) >> 16;
  return (unsigned short)r;
}

// ---------------- table build ----------------
__global__ __launch_bounds__(256) void build_tables(float* __restrict__ tab, const float* __restrict__ rpb){
  int idx = blockIdx.x*256 + threadIdx.x;
  const double TP = 6.283185307179586476925286766559;
  if (idx < 18624){ // rfft-W: [97][192]
    int i = idx/192, j = idx%192;
    double th = TP*((double)(i*j))/192.0;
    tab[T_COSW+idx] = (float)cos(th);
    tab[T_SINW+idx] = (float)sin(th);
    return;
  }
  idx -= 18624;
  if (idx < 36864){ // fft-H: [192][192]
    int i = idx/192, j = idx%192;
    double th = TP*((double)(i*j))/192.0;
    tab[T_COSH+idx] = (float)cos(th);
    tab[T_SINH+idx] = (float)sin(th);
    return;
  }
  idx -= 36864;
  if (idx < 18624){ // irfft-W: [192][97], alpha/(H*W) folded
    int w = idx/97, k = idx%97;
    double th = TP*((double)(k*w))/192.0;
    double a = (k==0 || k==96) ? 1.0 : 2.0;
    double sc = a/36864.0;
    tab[T_ICOS+idx] = (float)(sc*cos(th));
    tab[T_ISIN+idx] = (float)(sc*sin(th));
    return;
  }
  idx -= 18624;
  if (idx < 16384){ // attn bias: [head][n][m]
    int head = idx>>12, n = (idx>>6)&63, m = idx&63;
    int dh = n/16 - m/16 + 3;
    int dw = (n&15) - (m&15) + 15;
    tab[T_BIAS+idx] = rpb[(dh*31+dw)*4 + head];
    return;
  }
  idx -= 16384;
  if (idx < 49152){ // MW [256][192]: rows 0..96 cos, 97..193 -sin, rest 0
    int r = idx/192, w = idx%192;
    float v = 0.f;
    if (r < 97) v = (float)cos(TP*((double)(r*w))/192.0);
    else if (r < 194) v = (float)(-sin(TP*((double)((r-97)*w))/192.0));
    tab[T_MW+idx] = v;
    return;
  }
  idx -= 49152;
  if (idx < 147456){ // MHF [384][384]: re rows [cos|sin], im rows [-sin|cos]
    int r = idx/384, j = idx%384;
    int hf = (r < 192) ? r : r-192;
    int h  = (j < 192) ? j : j-192;
    double c = cos(TP*((double)(hf*h))/192.0);
    double s = sin(TP*((double)(hf*h))/192.0);
    float v;
    if (r < 192) v = (j < 192) ? (float)c : (float)s;
    else         v = (j < 192) ? (float)(-s) : (float)c;
    tab[T_MHF+idx] = v;
    return;
  }
  idx -= 147456;
  if (idx < 147456){ // MHI [384][384]: re rows [cos|-sin], im rows [sin|cos]
    int r = idx/384, j = idx%384;
    int h  = (r < 192) ? r : r-192;
    int hf = (j < 192) ? j : j-192;
    double c = cos(TP*((double)(h*hf))/192.0);
    double s = sin(TP*((double)(h*hf))/192.0);
    float v;
    if (r < 192) v = (j < 192) ? (float)c : (float)(-s);
    else         v = (j < 192) ? (float)s : (float)c;
    tab[T_MHI+idx] = v;
    return;
  }
  idx -= 147456;
  if (idx < 43008){ // MWI [192][224]: cols 0..96 icos, 112..208 -isin, rest 0
    int w = idx/224, j = idx%224;
    float v = 0.f;
    if (j < 97){
      double a = (j==0 || j==96) ? 1.0 : 2.0;
      v = (float)((a/36864.0)*cos(TP*((double)(j*w))/192.0));
    } else if (j >= 112 && j < 209){
      int k = j-112;
      double a = (k==0 || k==96) ? 1.0 : 2.0;
      v = (float)(-(a/36864.0)*sin(TP*((double)(k*w))/192.0));
    }
    tab[T_MWI+idx] = v;
  }
}

// ---------------- pos depthwise conv v3: cb in grid ----------------
__global__ __launch_bounds__(256) void posconv2_kernel(const float* __restrict__ x, const float* __restrict__ pw,
                               const float* __restrict__ pb, float* __restrict__ xt){
  __shared__ float rows_s[16*660];    // [c][r(10)][wc(66)]
  __shared__ float outt[8*64*17];
  int w0 = blockIdx.x*64, h0 = blockIdx.y*8;
  int b = blockIdx.z >> 3, cb = (blockIdx.z & 7)*16;
  int tid = threadIdx.x;
  int hl = tid >> 6, wl = tid & 63;
  for (int e = tid; e < 16*660; e += 256){
    int c = e / 660; int rem = e - c*660;
    int r = rem / 66; int wc = rem - r*66;
    int gh = h0 - 1 + r, gw = w0 - 1 + wc;
    float v = 0.f;
    if (gh >= 0 && gh < HGT && gw >= 0 && gw < WID)
      v = x[((size_t)(b*C_DIM + cb + c))*(HGT*WID) + gh*WID + gw];
    rows_s[e] = v;
  }
  __syncthreads();
  for (int c = 0; c < 16; ++c){
    const float* rs = &rows_s[c*660];
    float wreg[9];
    #pragma unroll
    for (int t9 = 0; t9 < 9; ++t9) wreg[t9] = pw[(cb+c)*27 + 9 + t9];
    float bias = pb[cb+c];
    #pragma unroll
    for (int j = 0; j < 2; ++j){
      int hh = hl*2 + j;
      float acc = rs[(hh+1)*66 + wl+1] + bias;
      #pragma unroll
      for (int ky = 0; ky < 3; ++ky)
        #pragma unroll
        for (int kx = 0; kx < 3; ++kx)
          acc += wreg[ky*3+kx]*rs[(hh+ky)*66 + wl+kx];
      outt[(hh*64+wl)*17 + c] = acc;
    }
  }
  __syncthreads();
  for (int r = 0; r < 32; ++r){
    int e = r*256 + tid;
    int cl = e & 15, hw = e >> 4;
    int h = hw >> 6, w = hw & 63;
    xt[((size_t)(b*HGT + h0+h)*WID + (w0+w))*C_DIM + cb + cl] = outt[(h*64+w)*17 + cl];
  }
}

// ---------------- LN row stats (mean, rstd) ----------------
__global__ __launch_bounds__(256) void ln_stats_kernel(const float* __restrict__ src, float* __restrict__ stats){
  int wave = threadIdx.x >> 6; int lane = threadIdx.x & 63;
  size_t p = (size_t)blockIdx.x*4 + wave;
  const float* s = src + p*C_DIM;
  float v0 = s[lane], v1 = s[lane+64];
  float sum = v0 + v1;
  #pragma unroll
  for (int o=1; o<64; o<<=1) sum += __shfl_xor(sum, o, 64);
  float m = sum * (1.0f/128.0f);
  float d0 = v0-m, d1 = v1-m;
  float vs = d0*d0 + d1*d1;
  #pragma unroll
  for (int o=1; o<64; o<<=1) vs += __shfl_xor(vs, o, 64);
  float rstd = rsqrtf(vs*(1.0f/128.0f) + 1e-5f);
  if (lane==0){ stats[2*p] = m; stats[2*p+1] = rstd; }
}

// ---------------- bf16 MFMA GEMM ----------------
template<int ACT, bool ADD, bool LNA>
__global__ __launch_bounds__(256) void gemm_mfma(const float* __restrict__ A1,
                            const float* __restrict__ Wm, const float* __restrict__ bias,
                            float* __restrict__ dst, int K, int N, int lda,
                            const float* __restrict__ stats, const float* __restrict__ lng,
                            const float* __restrict__ lnb, int prow0, int pmax){
  __shared__ __align__(16) unsigned short As[64*40];
  __shared__ __align__(16) unsigned short Bs[64*40];
  int p0 = blockIdx.y*64, n0 = blockIdx.x*64;
  int tid = threadIdx.x;
  int wave = tid >> 6, lane = tid & 63;
  int wr = (wave>>1)*32, wc = (wave&1)*32;
  f32x4 acc00 = {}, acc01 = {}, acc10 = {}, acc11 = {};
  int am = tid >> 2, ak = (tid & 3)*8;
  int bk = tid >> 3, bn = (tid & 7)*8;
  for (int k0 = 0; k0 < K; k0 += 32){
    {
      int gp = p0 + am;
      float s0 = 0.f, s1 = 0.f;
      if (LNA){
        gp += prow0;
        gp = gp < 0 ? 0 : (gp > pmax ? pmax : gp);
        s0 = stats[2*gp]; s1 = stats[2*gp+1];
      }
      const float* src = A1 + (size_t)gp*lda + k0 + ak;
      float4 aa = *(const float4*)src;
      float4 ab = *(const float4*)(src+4);
      float v[8] = {aa.x,aa.y,aa.z,aa.w,ab.x,ab.y,ab.z,ab.w};
      unsigned short* dp = &As[am*40 + ak];
      #pragma unroll
      for (int j=0;j<8;j++){
        float f = v[j];
        if (LNA) f = (f - s0)*s1*lng[k0+ak+j] + lnb[k0+ak+j];
        dp[j] = f2bf(f);
      }
    }
    {
      const float* src = Wm + (size_t)(k0+bk)*N + n0 + bn;
      float4 wa = *(const float4*)src;
      float4 wb = *(const float4*)(src+4);
      float v[8] = {wa.x,wa.y,wa.z,wa.w,wb.x,wb.y,wb.z,wb.w};
      #pragma unroll
      for (int j=0;j<8;j++) Bs[(bn+j)*40 + bk] = f2bf(v[j]);
    }
    __syncthreads();
    int fm = lane & 15, kg = (lane>>4)*8;
    bf16x8 a0 = *(const bf16x8*)&As[(wr+fm)*40 + kg];
    bf16x8 a1 = *(const bf16x8*)&As[(wr+16+fm)*40 + kg];
    bf16x8 b0 = *(const bf16x8*)&Bs[(wc+fm)*40 + kg];
    bf16x8 b1 = *(const bf16x8*)&Bs[(wc+16+fm)*40 + kg];
    acc00 = __builtin_amdgcn_mfma_f32_16x16x32_bf16(a0, b0, acc00, 0,0,0);
    acc01 = __builtin_amdgcn_mfma_f32_16x16x32_bf16(a0, b1, acc01, 0,0,0);
    acc10 = __builtin_amdgcn_mfma_f32_16x16x32_bf16(a1, b0, acc10, 0,0,0);
    acc11 = __builtin_amdgcn_mfma_f32_16x16x32_bf16(a1, b1, acc11, 0,0,0);
    __syncthreads();
  }
  int cn = lane & 15, rq = (lane>>4)*4;
  #pragma unroll
  for (int mi=0; mi<2; ++mi){
    #pragma unroll
    for (int ni=0; ni<2; ++ni){
      f32x4 a = (mi==0) ? (ni==0?acc00:acc01) : (ni==0?acc10:acc11);
      int n = n0 + wc + ni*16 + cn;
      float bsv = bias[n];
      #pragma unroll
      for (int r=0; r<4; ++r){
        size_t row = (size_t)p0 + wr + mi*16 + rq + r;
        float v = a[r] + bsv;
        if (ACT==1) v = (v>=0.f) ? v : 0.01f*v;
        if (ACT==2) v = gelu_f(v);
        if (ADD) v += dst[row*(size_t)N + n];
        dst[row*(size_t)N + n] = v;
      }
    }
  }
}

// ---------------- DFT-as-GEMM: dst = Atab(fp32->bf16) @ W(fp32->bf16) ----------------
// MODE 0: rfft-W  per (b,h):  A=MW[256][192], W=XTb rows w (ld 128) -> FR/FI
// MODE 1: fft-H   per (b,kl): A=MHF[384][384], W=FR/FI rows h (ld 12416) -> FF0[kl]
// MODE 2: ifft-H  per (b,kl): A=MHI[384][384], W=FF0[kl] rows hf (ld 256) -> G[h][k][256]
// MODE 3: irfft-W per (b,h):  A=MWI[192][224], W=G[h] rows k (ld 256) -> += XTb
template<int MODE>
__global__ __launch_bounds__(256) void dft_gemm(const float* __restrict__ Atab,
                            const float* __restrict__ W1, const float* __restrict__ W2,
                            float* __restrict__ D1, float* __restrict__ D2, int k0){
  constexpr int K      = (MODE==0)?192 : (MODE==3)?224 : 384;
  constexpr int MT     = (MODE==0)?4 : (MODE==3)?3 : 6;
  constexpr int MVALID = (MODE==0)?194 : (MODE==3)?192 : 384;
  __shared__ __align__(16) unsigned short As[64*40];
  __shared__ __align__(16) unsigned short Bs[64*40];
  int slab = blockIdx.y / MT;
  int p0 = (blockIdx.y % MT)*64, n0 = blockIdx.x*64;
  int tid = threadIdx.x;
  int wave = tid >> 6, lane = tid & 63;
  int wr = (wave>>1)*32, wc = (wave&1)*32;
  f32x4 acc00 = {}, acc01 = {}, acc10 = {}, acc11 = {};
  int am = tid >> 2, ak = (tid & 3)*8;
  int bk = tid >> 3, bn = (tid & 7)*8;
  for (int kk0 = 0; kk0 < K; kk0 += 32){
    {
      const float* src = Atab + (size_t)(p0+am)*K + kk0 + ak;
      float4 aa = *(const float4*)src;
      float4 ab = *(const float4*)(src+4);
      float v[8] = {aa.x,aa.y,aa.z,aa.w,ab.x,ab.y,ab.z,ab.w};
      unsigned short* dp = &As[am*40 + ak];
      #pragma unroll
      for (int j=0;j<8;j++) dp[j] = f2bf(v[j]);
    }
    {
      int r = kk0 + bk;
      const float* src;
      if (MODE==0)      src = W1 + (size_t)slab*24576 + (size_t)r*128;
      else if (MODE==1) src = (r<192) ? W1 + (size_t)(k0+slab)*128 + (size_t)r*12416
                                      : W2 + (size_t)(k0+slab)*128 + (size_t)(r-192)*12416;
      else if (MODE==2) src = (r<192) ? W1 + (size_t)slab*49152 + (size_t)r*256
                                      : W2 + (size_t)slab*49152 + (size_t)(r-192)*256;
      else              src = (r<112) ? W1 + (size_t)slab*24832 + (size_t)r*256
                                      : W2 + (size_t)slab*24832 + (size_t)(r-112)*256;
      src += n0 + bn;
      float4 wa = *(const float4*)src;
      float4 wb = *(const float4*)(src+4);
      float v[8] = {wa.x,wa.y,wa.z,wa.w,wb.x,wb.y,wb.z,wb.w};
      #pragma unroll
      for (int j=0;j<8;j++) Bs[(bn+j)*40 + bk] = f2bf(v[j]);
    }
    __syncthreads();
    int fm = lane & 15, kg = (lane>>4)*8;
    bf16x8 a0 = *(const bf16x8*)&As[(wr+fm)*40 + kg];
    bf16x8 a1 = *(const bf16x8*)&As[(wr+16+fm)*40 + kg];
    bf16x8 b0 = *(const bf16x8*)&Bs[(wc+fm)*40 + kg];
    bf16x8 b1 = *(const bf16x8*)&Bs[(wc+16+fm)*40 + kg];
    acc00 = __builtin_amdgcn_mfma_f32_16x16x32_bf16(a0, b0, acc00, 0,0,0);
    acc01 = __builtin_amdgcn_mfma_f32_16x16x32_bf16(a0, b1, acc01, 0,0,0);
    acc10 = __builtin_amdgcn_mfma_f32_16x16x32_bf16(a1, b0, acc10, 0,0,0);
    acc11 = __builtin_amdgcn_mfma_f32_16x16x32_bf16(a1, b1, acc11, 0,0,0);
    __syncthreads();
  }
  int cn = lane & 15, rq = (lane>>4)*4;
  #pragma unroll
  for (int mi=0; mi<2; ++mi){
    #pragma unroll
    for (int ni=0; ni<2; ++ni){
      f32x4 a = (mi==0) ? (ni==0?acc00:acc01) : (ni==0?acc10:acc11);
      int n = n0 + wc + ni*16 + cn;
      #pragma unroll
      for (int r=0; r<4; ++r){
        int p = p0 + wr + mi*16 + rq + r;
        if (p >= MVALID) continue;
        float v = a[r];
        if (MODE==0){
          if (p < 97) D1[(size_t)slab*12416 + (size_t)p*128 + n] = v;
          else        D2[(size_t)slab*12416 + (size_t)(p-97)*128 + n] = v;
        } else if (MODE==1){
          float* base = D1 + (size_t)slab*49152;
          if (p < 192) base[(size_t)p*256 + n] = v;
          else         base[(size_t)(p-192)*256 + 128 + n] = v;
        } else if (MODE==2){
          int kg2 = k0 + slab;
          if (p < 192) D1[((size_t)p*97 + kg2)*256 + n] = v;
          else         D1[((size_t)(p-192)*97 + kg2)*256 + 128 + n] = v;
        } else {
          D1[(size_t)slab*24576 + (size_t)p*128 + n] += v;
        }
      }
    }
  }
}

// ---------------- light attention (scores in LDS; no spill) ----------------
__global__ __launch_bounds__(64) void attn_light(
    const float* __restrict__ Qc, const float* __restrict__ KVc,
    const float* __restrict__ biasT, float* __restrict__ OUTc,
    int win0, int prow0){
  __shared__ float kb[64*36];
  __shared__ float vb[64*36];
  __shared__ float sb[64*65];
  int win = win0 + blockIdx.x, head = blockIdx.y;
  int b = win/576, rem = win%576, whi = rem/12, wwi = rem%12;
  int lane = threadIdx.x;
  int rowbase = (b*HGT + whi*4)*WID + wwi*16;
  int l = (rowbase - prow0) + (lane>>4)*WID + (lane&15);
  {
    const float* kp = KVc + (size_t)l*256 + head*32;
    #pragma unroll
    for (int d4=0; d4<8; ++d4){
      *(float4*)&kb[lane*36+d4*4] = *(const float4*)(kp+d4*4);
      *(float4*)&vb[lane*36+d4*4] = *(const float4*)(kp+128+d4*4);
    }
  }
  float q_[32];
  {
    const float* qp = Qc + (size_t)l*128 + head*32;
    #pragma unroll
    for (int d=0; d<32; ++d) q_[d] = qp[d]*0.17677669529663688f;
  }
  __syncthreads();
  float* srow = &sb[lane*65];
  const float* bp = biasT + head*4096 + lane*64;
  for (int m=0;m<64;m++){
    float a = bp[m];
    const float4* k4 = (const float4*)&kb[m*36];
    #pragma unroll
    for (int d4=0; d4<8; ++d4){
      float4 w4 = k4[d4];
      a += q_[d4*4+0]*w4.x + q_[d4*4+1]*w4.y + q_[d4*4+2]*w4.z + q_[d4*4+3]*w4.w;
    }
    srow[m] = a;
  }
  float mx = -1e30f;
  for (int m=0;m<64;m++) mx = fmaxf(mx, srow[m]);
  float sum = 0.f;
  for (int m=0;m<64;m++){ float e = expf(srow[m]-mx); sum += e; srow[m] = e; }
  float inv = 1.f/sum;
  float acc[32];
  #pragma unroll
  for (int d=0; d<32; ++d) acc[d]=0.f;
  for (int m=0;m<64;m++){
    float pm = srow[m]*inv;
    const float4* v4p = (const float4*)&vb[m*36];
    #pragma unroll
    for (int d4=0; d4<8; ++d4){
      float4 w4 = v4p[d4];
      acc[d4*4+0]+=pm*w4.x; acc[d4*4+1]+=pm*w4.y; acc[d4*4+2]+=pm*w4.z; acc[d4*4+3]+=pm*w4.w;
    }
  }
  float* op = OUTc + (size_t)l*128 + head*32;
  #pragma unroll
  for (int d4=0; d4<8; ++d4) ((float4*)op)[d4] = *(float4*)&acc[d4*4];
}

// ---------------- LeFF dwconv strip ----------------
__global__ __launch_bounds__(256) void dwconv_strip(const float* __restrict__ SB1, const float* __restrict__ dw,
                                                    const float* __restrict__ db, float* __restrict__ SB2,
                                                    int r0){
  int id = blockIdx.x*256 + threadIdx.x;
  int ch = id & 511; int t = id >> 9; int w = t % 192; int hl = t / 192;
  int h = r0 + hl;
  float acc = db[ch];
  #pragma unroll
  for (int ky=0; ky<3; ky++){
    int hh = h+ky-1;
    if (hh<0 || hh>=HGT) continue;
    int br = hl + ky;
    #pragma unroll
    for (int kx=0; kx<3; kx++){
      int ww = w+kx-1;
      if (ww<0 || ww>=WID) continue;
      acc += dw[ch*9+ky*3+kx]*SB1[((size_t)br*WID + ww)*512 + ch];
    }
  }
  SB2[id] = gelu_f(acc);
}

// ---------------- per-batch BHWC -> BCHW transpose ----------------
__global__ __launch_bounds__(256) void transpose_b_kernel(const float* __restrict__ src, float* __restrict__ dst){
  __shared__ float tile[128*65];
  int w0 = blockIdx.x*64, h = blockIdx.y;
  int tid = threadIdx.x;
  for (int r=0; r<32; r++){
    int e = tid + 256*r; int c = e & 127, wl = e >> 7;
    tile[c*65 + wl] = src[((size_t)h*WID + w0 + wl)*C_DIM + c];
  }
  __syncthreads();
  for (int r=0; r<32; r++){
    int e = tid + 256*r; int wl = e & 63, c = e >> 6;
    dst[((size_t)c*HGT + h)*WID + w0 + wl] = tile[c*65 + wl];
  }
}

// ---------------- host ----------------
extern "C" void kernel_launch(void* const* d_in, const int* in_sizes, int n_in,
                              void* d_out, int out_size, void* d_ws, size_t ws_size,
                              hipStream_t stream) {
  const float* x      = (const float*)d_in[0];
  const float* pos_w  = (const float*)d_in[1];
  const float* pos_b  = (const float*)d_in[2];
  const float* ln1_g  = (const float*)d_in[3];
  const float* ln1_b  = (const float*)d_in[4];
  const float* q_w    = (const float*)d_in[5];
  const float* q_b    = (const float*)d_in[6];
  const float* kv_w   = (const float*)d_in[7];
  const float* kv_b   = (const float*)d_in[8];
  const float* rpb    = (const float*)d_in[9];
  const float* proj_w = (const float*)d_in[10];
  const float* proj_b = (const float*)d_in[11];
  const float* fft1_w = (const float*)d_in[12];
  const float* fft1_b = (const float*)d_in[13];
  const float* fft2_w = (const float*)d_in[14];
  const float* fft2_b = (const float*)d_in[15];
  const float* ln2_g  = (const float*)d_in[16];
  const float* ln2_b  = (const float*)d_in[17];
  const float* l1_w   = (const float*)d_in[18];
  const float* l1_b   = (const float*)d_in[19];
  const float* dw_w   = (const float*)d_in[20];
  const float* dw_b   = (const float*)d_in[21];
  const float* l2_w   = (const float*)d_in[22];
  const float* l2_b   = (const float*)d_in[23];

  const size_t S   = (size_t)NB*HGT*WID*C_DIM;   // 18,874,368
  const size_t Sb  = S/NB;                       //  4,718,592
  const size_t SZb = (size_t)HGT*WFD*C_DIM;      //  2,383,872
  const size_t GSZ = (size_t)HGT*WFD*256;        //  4,767,744
  const int    P   = (int)(NB*HGT*WID);          // 147,456

  float* XT = (float*)d_out;

  float* ws    = (float*)d_ws;
  float* TAB   = ws;
  float* STATS = ws + TAB_SZ;
  float* POOL  = ws + TAB_SZ + 2*(size_t)P;
  size_t head  = TAB_SZ + 2*(size_t)P;
  size_t pool  = (ws_size/4 > head) ? (ws_size/4 - head) : 0;

  const float* biasT = TAB + T_BIAS;
  const float* MW  = TAB + T_MW;
  const float* MHF = TAB + T_MHF;
  const float* MHI = TAB + T_MHI;
  const float* MWI = TAB + T_MWI;

  build_tables<<<2155, 256, 0, stream>>>(TAB, rpb);
  posconv2_kernel<<<dim3(3,24,32), 256, 0, stream>>>(x, pos_w, pos_b, XT);

  // ---- attention: LN1 stats -> per-chunk {q gemm, kv gemm, attn, proj gemm} ----
  ln_stats_kernel<<<P/4, 256, 0, stream>>>(XT, STATS);
  {
    int winChunk = (int)((pool/(64*512)/12)*12);
    if (winChunk < 12) winChunk = 12;
    if (winChunk > 2304) winChunk = 2304;
    for (int w0 = 0; w0 < 2304; w0 += winChunk){
      int nw = (2304 - w0 < winChunk) ? (2304 - w0) : winChunk;
      int R = nw*64, prow0 = w0*64;
      float* Qc   = POOL;
      float* KVc  = POOL + (size_t)R*128;
      float* OUTc = POOL + (size_t)R*384;
      gemm_mfma<0,false,true><<<dim3(2, R/64), 256, 0, stream>>>(
          XT, q_w, q_b, Qc, 128, 128, 128, STATS, ln1_g, ln1_b, prow0, P-1);
      gemm_mfma<0,false,true><<<dim3(4, R/64), 256, 0, stream>>>(
          XT, kv_w, kv_b, KVc, 128, 256, 128, STATS, ln1_g, ln1_b, prow0, P-1);
      attn_light<<<dim3(nw, 4), 64, 0, stream>>>(Qc, KVc, biasT, OUTc, w0, prow0);
      gemm_mfma<0,true,false><<<dim3(2, R/64), 256, 0, stream>>>(
          OUTc, proj_w, proj_b, XT + (size_t)prow0*C_DIM,
          128, 128, 128, nullptr, nullptr, nullptr, 0, 0);
    }
  }

  // ---- FFT residual branch: all-MFMA (DFT-as-GEMM + mixes), chunked over k ----
  {
    // layout: FR | FI | G | FF0 | FF1
    float* FR  = POOL;
    float* FI  = POOL + SZb;
    float* G   = POOL + 2*SZb;
    size_t fixed = 2*SZb + GSZ;
    int CK = 1;
    if (pool > fixed + 98304) CK = (int)((pool - fixed)/98304);
    if (CK < 1) CK = 1;
    if (CK > WFD) CK = WFD;
    float* FF0 = POOL + fixed;
    float* FF1 = FF0 + (size_t)CK*49152;
    for (int b = 0; b < NB; ++b){
      float* XTb = XT + (size_t)b*Sb;
      dft_gemm<0><<<dim3(2, 192*4), 256, 0, stream>>>(MW, XTb, nullptr, FR, FI, 0);
      for (int k0 = 0; k0 < WFD; k0 += CK){
        int ck = (WFD - k0 < CK) ? (WFD - k0) : CK;
        int rows = ck*192;
        dft_gemm<1><<<dim3(2, ck*6), 256, 0, stream>>>(MHF, FR, FI, FF0, nullptr, k0);
        gemm_mfma<1,false,false><<<dim3(4, rows/64), 256, 0, stream>>>(
            FF0, fft1_w, fft1_b, FF1, 256, 256, 256,
            nullptr, nullptr, nullptr, 0, 0);
        gemm_mfma<0,false,false><<<dim3(4, rows/64), 256, 0, stream>>>(
            FF1, fft2_w, fft2_b, FF0, 256, 256, 256,
            nullptr, nullptr, nullptr, 0, 0);
        dft_gemm<2><<<dim3(2, ck*6), 256, 0, stream>>>(MHI, FF0, FF0+128, G, nullptr, k0);
      }
      dft_gemm<3><<<dim3(2, 192*3), 256, 0, stream>>>(MWI, G, G+128, XTb, nullptr, 0);
    }
  }

  // ---- LN2 stats ----
  ln_stats_kernel<<<P/4, 256, 0, stream>>>(XT, STATS);

  // ---- LeFF: strip-mined l1 gemm -> dwconv+gelu -> l2 MFMA gemm (+residual) ----
  {
    int SH = 32;
    while ((size_t)(3*SH+4)*98304 > pool && SH > 8) SH >>= 1;
    const size_t SB1SZ = (size_t)(SH+2)*98304;
    float* SB1[2] = { POOL, POOL + SB1SZ };
    float* SB2 = POOL + 2*SB1SZ;
    int nStrips = HGT/SH;
    for (int b = 0; b < NB; ++b){
      auto launch_g = [&](int s){
        int r0 = s*SH;
        int prow0 = (b*HGT + r0 - 1)*WID;
        gemm_mfma<2,false,true><<<dim3(8, (SH+2)*3), 256, 0, stream>>>(
            XT, l1_w, l1_b, SB1[s&1], 128, 512, 128,
            STATS, ln2_g, ln2_b, prow0, P-1);
      };
      launch_g(0);
      for (int s = 0; s < nStrips; ++s){
        if (s+1 < nStrips) launch_g(s+1);
        int r0 = s*SH;
        dwconv_strip<<<SH*384, 256, 0, stream>>>(SB1[s&1], dw_w, dw_b, SB2, r0);
        gemm_mfma<0,true,false><<<dim3(2, SH*3), 256, 0, stream>>>(
            SB2, l2_w, l2_b, XT + ((size_t)(b*HGT + r0)*WID)*C_DIM,
            512, 128, 512, nullptr, nullptr, nullptr, 0, 0);
      }
    }
  }

  // ---- final transpose per batch: XT(BHWC, in d_out) -> POOL(BCHW) -> copy back ----
  for (int b = 0; b < NB; ++b){
    transpose_b_kernel<<<dim3(3,192), 256, 0, stream>>>(XT + (size_t)b*Sb, POOL);
    hipMemcpyAsync((float*)d_out + (size_t)b*Sb, POOL, Sb*sizeof(float),
                   hipMemcpyDeviceToDevice, stream);
  }
}

// Round 9
// 2523.741 us; speedup vs baseline: 4.1207x; 1.0465x over previous
//
#include <hip/hip_runtime.h>
#include <math.h>

// ---------------- constants ----------------
#define C_DIM 128
#define HGT 192
#define WID 192
#define NB 4
#define WFD 97   // 192/2+1

// table offsets (floats)
#define T_BIAS 0                 // 4*64*64
#define T_MW   16384             // 256x192 combined rfft-W matrix
#define T_MHF  65536             // 384x384 combined fft-H matrix
#define T_MHI  212992            // 384x384 combined ifft-H matrix
#define T_MWI  360448            // 192x224 combined irfft-W matrix
#define TAB_SZ 403456            // table reserve (floats)

typedef __attribute__((ext_vector_type(8))) short bf16x8;
typedef __attribute__((ext_vector_type(4))) float f32x4;

__device__ __forceinline__ float gelu_f(float v){
  return 0.5f*v*(1.0f + erff(v*0.70710678118654752440f));
}
__device__ __forceinline__ unsigned short f2bf(float f){
  unsigned int u = __float_as_uint(f);
  unsigned int r = (u + 0x7FFFu + ((u>>16)&1u)) >> 16;
  return (unsigned short)r;
}

// ---------------- table build (exact int mod-192 + float trig) ----------------
__global__ __launch_bounds__(256) void build_tables(float* __restrict__ tab, const float* __restrict__ rpb){
  int idx = blockIdx.x*256 + threadIdx.x;
  const float STEP = (float)(6.283185307179586476925286766559/192.0);
  if (idx < 16384){ // attn bias: [head][n][m]
    int head = idx>>12, n = (idx>>6)&63, m = idx&63;
    int dh = n/16 - m/16 + 3;
    int dw = (n&15) - (m&15) + 15;
    tab[T_BIAS+idx] = rpb[(dh*31+dw)*4 + head];
    return;
  }
  idx -= 16384;
  if (idx < 49152){ // MW [256][192]: rows 0..96 cos, 97..193 -sin, rest 0
    int r = idx/192, w = idx%192;
    float v = 0.f;
    if (r < 97){ int a = (r*w)%192; v = cosf(a*STEP); }
    else if (r < 194){ int a = ((r-97)*w)%192; v = -sinf(a*STEP); }
    tab[T_MW+idx] = v;
    return;
  }
  idx -= 49152;
  if (idx < 147456){ // MHF [384][384]: re rows [cos|sin], im rows [-sin|cos]
    int r = idx/384, j = idx%384;
    int hf = (r < 192) ? r : r-192;
    int h  = (j < 192) ? j : j-192;
    int a = (hf*h)%192;
    float c = cosf(a*STEP), s = sinf(a*STEP);
    float v;
    if (r < 192) v = (j < 192) ? c : s;
    else         v = (j < 192) ? -s : c;
    tab[T_MHF+idx] = v;
    return;
  }
  idx -= 147456;
  if (idx < 147456){ // MHI [384][384]: re rows [cos|-sin], im rows [sin|cos]
    int r = idx/384, j = idx%384;
    int h  = (r < 192) ? r : r-192;
    int hf = (j < 192) ? j : j-192;
    int a = (h*hf)%192;
    float c = cosf(a*STEP), s = sinf(a*STEP);
    float v;
    if (r < 192) v = (j < 192) ? c : -s;
    else         v = (j < 192) ? s : c;
    tab[T_MHI+idx] = v;
    return;
  }
  idx -= 147456;
  if (idx < 43008){ // MWI [192][224]: cols 0..96 icos, 112..208 -isin, rest 0
    int w = idx/224, j = idx%224;
    float v = 0.f;
    if (j < 97){
      int a = (j*w)%192;
      float sc = ((j==0 || j==96) ? 1.f : 2.f) / 36864.f;
      v = sc*cosf(a*STEP);
    } else if (j >= 112 && j < 209){
      int k = j-112;
      int a = (k*w)%192;
      float sc = ((k==0 || k==96) ? 1.f : 2.f) / 36864.f;
      v = -sc*sinf(a*STEP);
    }
    tab[T_MWI+idx] = v;
  }
}

// ---------------- pos depthwise conv v3: cb in grid ----------------
__global__ __launch_bounds__(256) void posconv2_kernel(const float* __restrict__ x, const float* __restrict__ pw,
                               const float* __restrict__ pb, float* __restrict__ xt){
  __shared__ float rows_s[16*660];    // [c][r(10)][wc(66)]
  __shared__ float outt[8*64*17];
  int w0 = blockIdx.x*64, h0 = blockIdx.y*8;
  int b = blockIdx.z >> 3, cb = (blockIdx.z & 7)*16;
  int tid = threadIdx.x;
  int hl = tid >> 6, wl = tid & 63;
  for (int e = tid; e < 16*660; e += 256){
    int c = e / 660; int rem = e - c*660;
    int r = rem / 66; int wc = rem - r*66;
    int gh = h0 - 1 + r, gw = w0 - 1 + wc;
    float v = 0.f;
    if (gh >= 0 && gh < HGT && gw >= 0 && gw < WID)
      v = x[((size_t)(b*C_DIM + cb + c))*(HGT*WID) + gh*WID + gw];
    rows_s[e] = v;
  }
  __syncthreads();
  for (int c = 0; c < 16; ++c){
    const float* rs = &rows_s[c*660];
    float wreg[9];
    #pragma unroll
    for (int t9 = 0; t9 < 9; ++t9) wreg[t9] = pw[(cb+c)*27 + 9 + t9];
    float bias = pb[cb+c];
    #pragma unroll
    for (int j = 0; j < 2; ++j){
      int hh = hl*2 + j;
      float acc = rs[(hh+1)*66 + wl+1] + bias;
      #pragma unroll
      for (int ky = 0; ky < 3; ++ky)
        #pragma unroll
        for (int kx = 0; kx < 3; ++kx)
          acc += wreg[ky*3+kx]*rs[(hh+ky)*66 + wl+kx];
      outt[(hh*64+wl)*17 + c] = acc;
    }
  }
  __syncthreads();
  for (int r = 0; r < 32; ++r){
    int e = r*256 + tid;
    int cl = e & 15, hw = e >> 4;
    int h = hw >> 6, w = hw & 63;
    xt[((size_t)(b*HGT + h0+h)*WID + (w0+w))*C_DIM + cb + cl] = outt[(h*64+w)*17 + cl];
  }
}

// ---------------- LN row stats (mean, rstd) ----------------
__global__ __launch_bounds__(256) void ln_stats_kernel(const float* __restrict__ src, float* __restrict__ stats){
  int wave = threadIdx.x >> 6; int lane = threadIdx.x & 63;
  size_t p = (size_t)blockIdx.x*4 + wave;
  const float* s = src + p*C_DIM;
  float v0 = s[lane], v1 = s[lane+64];
  float sum = v0 + v1;
  #pragma unroll
  for (int o=1; o<64; o<<=1) sum += __shfl_xor(sum, o, 64);
  float m = sum * (1.0f/128.0f);
  float d0 = v0-m, d1 = v1-m;
  float vs = d0*d0 + d1*d1;
  #pragma unroll
  for (int o=1; o<64; o<<=1) vs += __shfl_xor(vs, o, 64);
  float rstd = rsqrtf(vs*(1.0f/128.0f) + 1e-5f);
  if (lane==0){ stats[2*p] = m; stats[2*p+1] = rstd; }
}

// ---------------- bf16 MFMA GEMM ----------------
template<int ACT, bool ADD, bool LNA>
__global__ __launch_bounds__(256) void gemm_mfma(const float* __restrict__ A1,
                            const float* __restrict__ Wm, const float* __restrict__ bias,
                            float* __restrict__ dst, int K, int N, int lda,
                            const float* __restrict__ stats, const float* __restrict__ lng,
                            const float* __restrict__ lnb, int prow0, int pmax){
  __shared__ __align__(16) unsigned short As[64*40];
  __shared__ __align__(16) unsigned short Bs[64*40];
  int p0 = blockIdx.y*64, n0 = blockIdx.x*64;
  int tid = threadIdx.x;
  int wave = tid >> 6, lane = tid & 63;
  int wr = (wave>>1)*32, wc = (wave&1)*32;
  f32x4 acc00 = {}, acc01 = {}, acc10 = {}, acc11 = {};
  int am = tid >> 2, ak = (tid & 3)*8;
  int bk = tid >> 3, bn = (tid & 7)*8;
  for (int k0 = 0; k0 < K; k0 += 32){
    {
      int gp = p0 + am;
      float s0 = 0.f, s1 = 0.f;
      if (LNA){
        gp += prow0;
        gp = gp < 0 ? 0 : (gp > pmax ? pmax : gp);
        s0 = stats[2*gp]; s1 = stats[2*gp+1];
      }
      const float* src = A1 + (size_t)gp*lda + k0 + ak;
      float4 aa = *(const float4*)src;
      float4 ab = *(const float4*)(src+4);
      float v[8] = {aa.x,aa.y,aa.z,aa.w,ab.x,ab.y,ab.z,ab.w};
      unsigned short* dp = &As[am*40 + ak];
      #pragma unroll
      for (int j=0;j<8;j++){
        float f = v[j];
        if (LNA) f = (f - s0)*s1*lng[k0+ak+j] + lnb[k0+ak+j];
        dp[j] = f2bf(f);
      }
    }
    {
      const float* src = Wm + (size_t)(k0+bk)*N + n0 + bn;
      float4 wa = *(const float4*)src;
      float4 wb = *(const float4*)(src+4);
      float v[8] = {wa.x,wa.y,wa.z,wa.w,wb.x,wb.y,wb.z,wb.w};
      #pragma unroll
      for (int j=0;j<8;j++) Bs[(bn+j)*40 + bk] = f2bf(v[j]);
    }
    __syncthreads();
    int fm = lane & 15, kg = (lane>>4)*8;
    bf16x8 a0 = *(const bf16x8*)&As[(wr+fm)*40 + kg];
    bf16x8 a1 = *(const bf16x8*)&As[(wr+16+fm)*40 + kg];
    bf16x8 b0 = *(const bf16x8*)&Bs[(wc+fm)*40 + kg];
    bf16x8 b1 = *(const bf16x8*)&Bs[(wc+16+fm)*40 + kg];
    acc00 = __builtin_amdgcn_mfma_f32_16x16x32_bf16(a0, b0, acc00, 0,0,0);
    acc01 = __builtin_amdgcn_mfma_f32_16x16x32_bf16(a0, b1, acc01, 0,0,0);
    acc10 = __builtin_amdgcn_mfma_f32_16x16x32_bf16(a1, b0, acc10, 0,0,0);
    acc11 = __builtin_amdgcn_mfma_f32_16x16x32_bf16(a1, b1, acc11, 0,0,0);
    __syncthreads();
  }
  int cn = lane & 15, rq = (lane>>4)*4;
  #pragma unroll
  for (int mi=0; mi<2; ++mi){
    #pragma unroll
    for (int ni=0; ni<2; ++ni){
      f32x4 a = (mi==0) ? (ni==0?acc00:acc01) : (ni==0?acc10:acc11);
      int n = n0 + wc + ni*16 + cn;
      float bsv = bias[n];
      #pragma unroll
      for (int r=0; r<4; ++r){
        size_t row = (size_t)p0 + wr + mi*16 + rq + r;
        float v = a[r] + bsv;
        if (ACT==1) v = (v>=0.f) ? v : 0.01f*v;
        if (ACT==2) v = gelu_f(v);
        if (ADD) v += dst[row*(size_t)N + n];
        dst[row*(size_t)N + n] = v;
      }
    }
  }
}

// ---------------- DFT-as-GEMM ----------------
template<int MODE>
__global__ __launch_bounds__(256) void dft_gemm(const float* __restrict__ Atab,
                            const float* __restrict__ W1, const float* __restrict__ W2,
                            float* __restrict__ D1, float* __restrict__ D2, int k0){
  constexpr int K      = (MODE==0)?192 : (MODE==3)?224 : 384;
  constexpr int MT     = (MODE==0)?4 : (MODE==3)?3 : 6;
  constexpr int MVALID = (MODE==0)?194 : (MODE==3)?192 : 384;
  __shared__ __align__(16) unsigned short As[64*40];
  __shared__ __align__(16) unsigned short Bs[64*40];
  int slab = blockIdx.y / MT;
  int p0 = (blockIdx.y % MT)*64, n0 = blockIdx.x*64;
  int tid = threadIdx.x;
  int wave = tid >> 6, lane = tid & 63;
  int wr = (wave>>1)*32, wc = (wave&1)*32;
  f32x4 acc00 = {}, acc01 = {}, acc10 = {}, acc11 = {};
  int am = tid >> 2, ak = (tid & 3)*8;
  int bk = tid >> 3, bn = (tid & 7)*8;
  for (int kk0 = 0; kk0 < K; kk0 += 32){
    {
      const float* src = Atab + (size_t)(p0+am)*K + kk0 + ak;
      float4 aa = *(const float4*)src;
      float4 ab = *(const float4*)(src+4);
      float v[8] = {aa.x,aa.y,aa.z,aa.w,ab.x,ab.y,ab.z,ab.w};
      unsigned short* dp = &As[am*40 + ak];
      #pragma unroll
      for (int j=0;j<8;j++) dp[j] = f2bf(v[j]);
    }
    {
      int r = kk0 + bk;
      const float* src;
      if (MODE==0)      src = W1 + (size_t)slab*24576 + (size_t)r*128;
      else if (MODE==1) src = (r<192) ? W1 + (size_t)(k0+slab)*128 + (size_t)r*12416
                                      : W2 + (size_t)(k0+slab)*128 + (size_t)(r-192)*12416;
      else if (MODE==2) src = (r<192) ? W1 + (size_t)slab*49152 + (size_t)r*256
                                      : W2 + (size_t)slab*49152 + (size_t)(r-192)*256;
      else              src = (r<112) ? W1 + (size_t)slab*24832 + (size_t)r*256
                                      : W2 + (size_t)slab*24832 + (size_t)(r-112)*256;
      src += n0 + bn;
      float4 wa = *(const float4*)src;
      float4 wb = *(const float4*)(src+4);
      float v[8] = {wa.x,wa.y,wa.z,wa.w,wb.x,wb.y,wb.z,wb.w};
      #pragma unroll
      for (int j=0;j<8;j++) Bs[(bn+j)*40 + bk] = f2bf(v[j]);
    }
    __syncthreads();
    int fm = lane & 15, kg = (lane>>4)*8;
    bf16x8 a0 = *(const bf16x8*)&As[(wr+fm)*40 + kg];
    bf16x8 a1 = *(const bf16x8*)&As[(wr+16+fm)*40 + kg];
    bf16x8 b0 = *(const bf16x8*)&Bs[(wc+fm)*40 + kg];
    bf16x8 b1 = *(const bf16x8*)&Bs[(wc+16+fm)*40 + kg];
    acc00 = __builtin_amdgcn_mfma_f32_16x16x32_bf16(a0, b0, acc00, 0,0,0);
    acc01 = __builtin_amdgcn_mfma_f32_16x16x32_bf16(a0, b1, acc01, 0,0,0);
    acc10 = __builtin_amdgcn_mfma_f32_16x16x32_bf16(a1, b0, acc10, 0,0,0);
    acc11 = __builtin_amdgcn_mfma_f32_16x16x32_bf16(a1, b1, acc11, 0,0,0);
    __syncthreads();
  }
  int cn = lane & 15, rq = (lane>>4)*4;
  #pragma unroll
  for (int mi=0; mi<2; ++mi){
    #pragma unroll
    for (int ni=0; ni<2; ++ni){
      f32x4 a = (mi==0) ? (ni==0?acc00:acc01) : (ni==0?acc10:acc11);
      int n = n0 + wc + ni*16 + cn;
      #pragma unroll
      for (int r=0; r<4; ++r){
        int p = p0 + wr + mi*16 + rq + r;
        if (p >= MVALID) continue;
        float v = a[r];
        if (MODE==0){
          if (p < 97) D1[(size_t)slab*12416 + (size_t)p*128 + n] = v;
          else        D2[(size_t)slab*12416 + (size_t)(p-97)*128 + n] = v;
        } else if (MODE==1){
          float* base = D1 + (size_t)slab*49152;
          if (p < 192) base[(size_t)p*256 + n] = v;
          else         base[(size_t)(p-192)*256 + 128 + n] = v;
        } else if (MODE==2){
          int kg2 = k0 + slab;
          if (p < 192) D1[((size_t)p*97 + kg2)*256 + n] = v;
          else         D1[((size_t)(p-192)*97 + kg2)*256 + 128 + n] = v;
        } else {
          D1[(size_t)slab*24576 + (size_t)p*128 + n] += v;
        }
      }
    }
  }
}

// ---------------- MFMA window attention: block = window, wave = head ----------------
__global__ __launch_bounds__(256) void attn_mfma(
    const float* __restrict__ Qc, const float* __restrict__ KVc,
    const float* __restrict__ biasT, float* __restrict__ OUTc,
    int win0, int prow0){
  __shared__ __align__(16) unsigned short P_s[4][64][72];
  __shared__ __align__(16) unsigned short Vt_s[4][32][72];
  int win = win0 + blockIdx.x;
  int b = win/576, rem = win%576, whi = rem/12, wwi = rem%12;
  int tid = threadIdx.x;
  int wave = tid>>6, lane = tid&63, head = wave;
  int rowbase0 = (b*HGT + whi*4)*WID + wwi*16 - prow0;
  int fm = lane & 15, kg = (lane>>4)*8;
  // Q,K fragments (A: row=lane&15, k=(lane>>4)*8 — same mapping as validated gemm_mfma)
  bf16x8 qf[4], kf[4];
  #pragma unroll
  for (int t4=0; t4<4; ++t4){
    {
      const float* qp = Qc + (size_t)(rowbase0 + t4*WID + fm)*128 + head*32 + kg;
      float4 a = *(const float4*)qp, b4 = *(const float4*)(qp+4);
      float v[8] = {a.x,a.y,a.z,a.w,b4.x,b4.y,b4.z,b4.w};
      bf16x8 f;
      #pragma unroll
      for (int j=0;j<8;j++) f[j] = (short)f2bf(v[j]*0.17677669529663688f);
      qf[t4] = f;
    }
    {
      const float* kp = KVc + (size_t)(rowbase0 + t4*WID + fm)*256 + head*32 + kg;
      float4 a = *(const float4*)kp, b4 = *(const float4*)(kp+4);
      float v[8] = {a.x,a.y,a.z,a.w,b4.x,b4.y,b4.z,b4.w};
      bf16x8 f;
      #pragma unroll
      for (int j=0;j<8;j++) f[j] = (short)f2bf(v[j]);
      kf[t4] = f;
    }
  }
  // stage V^T (lane = token)
  {
    int lv = rowbase0 + (lane>>4)*WID + (lane&15);
    const float* vp = KVc + (size_t)lv*256 + 128 + head*32;
    #pragma unroll
    for (int d4=0; d4<8; ++d4){
      float4 v4 = *(const float4*)(vp + d4*4);
      Vt_s[wave][d4*4+0][lane] = f2bf(v4.x);
      Vt_s[wave][d4*4+1][lane] = f2bf(v4.y);
      Vt_s[wave][d4*4+2][lane] = f2bf(v4.z);
      Vt_s[wave][d4*4+3][lane] = f2bf(v4.w);
    }
  }
  // S = QK^T (16 MFMA)
  f32x4 s[4][4];
  #pragma unroll
  for (int ni=0; ni<4; ++ni)
    #pragma unroll
    for (int mj=0; mj<4; ++mj){
      f32x4 z = {};
      s[ni][mj] = __builtin_amdgcn_mfma_f32_16x16x32_bf16(qf[ni], kf[mj], z, 0,0,0);
    }
  // + rel-pos bias (D layout: col=lane&15, row=(lane>>4)*4+r)
  const float* bp = biasT + head*4096;
  #pragma unroll
  for (int ni=0; ni<4; ++ni){
    int nbase = ni*16 + (lane>>4)*4;
    #pragma unroll
    for (int mj=0; mj<4; ++mj){
      int m = mj*16 + fm;
      #pragma unroll
      for (int r=0;r<4;r++)
        s[ni][mj][r] += bp[(nbase+r)*64 + m];
    }
  }
  // row softmax (reduce across the 16-lane column groups)
  float rs[4][4];
  #pragma unroll
  for (int ni=0; ni<4; ++ni){
    #pragma unroll
    for (int r=0;r<4;r++){
      float t = fmaxf(fmaxf(s[ni][0][r], s[ni][1][r]), fmaxf(s[ni][2][r], s[ni][3][r]));
      #pragma unroll
      for (int o=1;o<16;o<<=1) t = fmaxf(t, __shfl_xor(t, o, 64));
      float sum = 0.f;
      #pragma unroll
      for (int mj=0; mj<4; ++mj){
        float e = expf(s[ni][mj][r] - t);
        s[ni][mj][r] = e;
        sum += e;
      }
      #pragma unroll
      for (int o=1;o<16;o<<=1) sum += __shfl_xor(sum, o, 64);
      rs[ni][r] = sum;
    }
  }
  // store P (bf16, unnormalized)
  #pragma unroll
  for (int ni=0; ni<4; ++ni){
    int nbase = ni*16 + (lane>>4)*4;
    #pragma unroll
    for (int mj=0; mj<4; ++mj){
      int m = mj*16 + fm;
      #pragma unroll
      for (int r=0;r<4;r++)
        P_s[wave][nbase+r][m] = f2bf(s[ni][mj][r]);
    }
  }
  // O = P·V (16 MFMA, k=m over 64)
  f32x4 o2[4][2] = {};
  #pragma unroll
  for (int ks=0; ks<2; ++ks){
    bf16x8 vb0 = *(const bf16x8*)&Vt_s[wave][fm][ks*32+kg];
    bf16x8 vb1 = *(const bf16x8*)&Vt_s[wave][16+fm][ks*32+kg];
    #pragma unroll
    for (int ni=0; ni<4; ++ni){
      bf16x8 pa = *(const bf16x8*)&P_s[wave][ni*16+fm][ks*32+kg];
      o2[ni][0] = __builtin_amdgcn_mfma_f32_16x16x32_bf16(pa, vb0, o2[ni][0], 0,0,0);
      o2[ni][1] = __builtin_amdgcn_mfma_f32_16x16x32_bf16(pa, vb1, o2[ni][1], 0,0,0);
    }
  }
  // normalize + write
  #pragma unroll
  for (int ni=0; ni<4; ++ni){
    #pragma unroll
    for (int r=0;r<4;r++){
      int l = rowbase0 + ni*WID + (lane>>4)*4 + r;
      float inv = 1.0f / rs[ni][r];
      float* op = OUTc + (size_t)l*128 + head*32;
      op[fm]    = o2[ni][0][r]*inv;
      op[16+fm] = o2[ni][1][r]*inv;
    }
  }
}

// ---------------- LeFF dwconv strip ----------------
__global__ __launch_bounds__(256) void dwconv_strip(const float* __restrict__ SB1, const float* __restrict__ dw,
                                                    const float* __restrict__ db, float* __restrict__ SB2,
                                                    int r0){
  int id = blockIdx.x*256 + threadIdx.x;
  int ch = id & 511; int t = id >> 9; int w = t % 192; int hl = t / 192;
  int h = r0 + hl;
  float acc = db[ch];
  #pragma unroll
  for (int ky=0; ky<3; ky++){
    int hh = h+ky-1;
    if (hh<0 || hh>=HGT) continue;
    int br = hl + ky;
    #pragma unroll
    for (int kx=0; kx<3; kx++){
      int ww = w+kx-1;
      if (ww<0 || ww>=WID) continue;
      acc += dw[ch*9+ky*3+kx]*SB1[((size_t)br*WID + ww)*512 + ch];
    }
  }
  SB2[id] = gelu_f(acc);
}

// ---------------- per-batch BHWC -> BCHW transpose ----------------
__global__ __launch_bounds__(256) void transpose_b_kernel(const float* __restrict__ src, float* __restrict__ dst){
  __shared__ float tile[128*65];
  int w0 = blockIdx.x*64, h = blockIdx.y;
  int tid = threadIdx.x;
  for (int r=0; r<32; r++){
    int e = tid + 256*r; int c = e & 127, wl = e >> 7;
    tile[c*65 + wl] = src[((size_t)h*WID + w0 + wl)*C_DIM + c];
  }
  __syncthreads();
  for (int r=0; r<32; r++){
    int e = tid + 256*r; int wl = e & 63, c = e >> 6;
    dst[((size_t)c*HGT + h)*WID + w0 + wl] = tile[c*65 + wl];
  }
}

// ---------------- host ----------------
extern "C" void kernel_launch(void* const* d_in, const int* in_sizes, int n_in,
                              void* d_out, int out_size, void* d_ws, size_t ws_size,
                              hipStream_t stream) {
  const float* x      = (const float*)d_in[0];
  const float* pos_w  = (const float*)d_in[1];
  const float* pos_b  = (const float*)d_in[2];
  const float* ln1_g  = (const float*)d_in[3];
  const float* ln1_b  = (const float*)d_in[4];
  const float* q_w    = (const float*)d_in[5];
  const float* q_b    = (const float*)d_in[6];
  const float* kv_w   = (const float*)d_in[7];
  const float* kv_b   = (const float*)d_in[8];
  const float* rpb    = (const float*)d_in[9];
  const float* proj_w = (const float*)d_in[10];
  const float* proj_b = (const float*)d_in[11];
  const float* fft1_w = (const float*)d_in[12];
  const float* fft1_b = (const float*)d_in[13];
  const float* fft2_w = (const float*)d_in[14];
  const float* fft2_b = (const float*)d_in[15];
  const float* ln2_g  = (const float*)d_in[16];
  const float* ln2_b  = (const float*)d_in[17];
  const float* l1_w   = (const float*)d_in[18];
  const float* l1_b   = (const float*)d_in[19];
  const float* dw_w   = (const float*)d_in[20];
  const float* dw_b   = (const float*)d_in[21];
  const float* l2_w   = (const float*)d_in[22];
  const float* l2_b   = (const float*)d_in[23];

  const size_t S   = (size_t)NB*HGT*WID*C_DIM;   // 18,874,368
  const size_t Sb  = S/NB;                       //  4,718,592
  const size_t SZb = (size_t)HGT*WFD*C_DIM;      //  2,383,872
  const size_t GSZ = (size_t)HGT*WFD*256;        //  4,767,744
  const int    P   = (int)(NB*HGT*WID);          // 147,456

  float* XT = (float*)d_out;

  float* ws    = (float*)d_ws;
  float* TAB   = ws;
  float* STATS = ws + TAB_SZ;
  float* POOL  = ws + TAB_SZ + 2*(size_t)P;
  size_t head  = TAB_SZ + 2*(size_t)P;
  size_t pool  = (ws_size/4 > head) ? (ws_size/4 - head) : 0;

  const float* biasT = TAB + T_BIAS;
  const float* MW  = TAB + T_MW;
  const float* MHF = TAB + T_MHF;
  const float* MHI = TAB + T_MHI;
  const float* MWI = TAB + T_MWI;

  build_tables<<<1576, 256, 0, stream>>>(TAB, rpb);
  posconv2_kernel<<<dim3(3,24,32), 256, 0, stream>>>(x, pos_w, pos_b, XT);

  // ---- attention: LN1 stats -> per-chunk {q gemm, kv gemm, attn(MFMA), proj gemm} ----
  ln_stats_kernel<<<P/4, 256, 0, stream>>>(XT, STATS);
  {
    int winChunk = (int)((pool/(64*512)/12)*12);
    if (winChunk < 12) winChunk = 12;
    if (winChunk > 2304) winChunk = 2304;
    for (int w0 = 0; w0 < 2304; w0 += winChunk){
      int nw = (2304 - w0 < winChunk) ? (2304 - w0) : winChunk;
      int R = nw*64, prow0 = w0*64;
      float* Qc   = POOL;
      float* KVc  = POOL + (size_t)R*128;
      float* OUTc = POOL + (size_t)R*384;
      gemm_mfma<0,false,true><<<dim3(2, R/64), 256, 0, stream>>>(
          XT, q_w, q_b, Qc, 128, 128, 128, STATS, ln1_g, ln1_b, prow0, P-1);
      gemm_mfma<0,false,true><<<dim3(4, R/64), 256, 0, stream>>>(
          XT, kv_w, kv_b, KVc, 128, 256, 128, STATS, ln1_g, ln1_b, prow0, P-1);
      attn_mfma<<<nw, 256, 0, stream>>>(Qc, KVc, biasT, OUTc, w0, prow0);
      gemm_mfma<0,true,false><<<dim3(2, R/64), 256, 0, stream>>>(
          OUTc, proj_w, proj_b, XT + (size_t)prow0*C_DIM,
          128, 128, 128, nullptr, nullptr, nullptr, 0, 0);
    }
  }

  // ---- FFT residual branch: all-MFMA (DFT-as-GEMM + mixes), chunked over k ----
  {
    float* FR  = POOL;
    float* FI  = POOL + SZb;
    float* G   = POOL + 2*SZb;
    size_t fixed = 2*SZb + GSZ;
    int CK = 1;
    if (pool > fixed + 98304) CK = (int)((pool - fixed)/98304);
    if (CK < 1) CK = 1;
    if (CK > WFD) CK = WFD;
    float* FF0 = POOL + fixed;
    float* FF1 = FF0 + (size_t)CK*49152;
    for (int b = 0; b < NB; ++b){
      float* XTb = XT + (size_t)b*Sb;
      dft_gemm<0><<<dim3(2, 192*4), 256, 0, stream>>>(MW, XTb, nullptr, FR, FI, 0);
      for (int k0 = 0; k0 < WFD; k0 += CK){
        int ck = (WFD - k0 < CK) ? (WFD - k0) : CK;
        int rows = ck*192;
        dft_gemm<1><<<dim3(2, ck*6), 256, 0, stream>>>(MHF, FR, FI, FF0, nullptr, k0);
        gemm_mfma<1,false,false><<<dim3(4, rows/64), 256, 0, stream>>>(
            FF0, fft1_w, fft1_b, FF1, 256, 256, 256,
            nullptr, nullptr, nullptr, 0, 0);
        gemm_mfma<0,false,false><<<dim3(4, rows/64), 256, 0, stream>>>(
            FF1, fft2_w, fft2_b, FF0, 256, 256, 256,
            nullptr, nullptr, nullptr, 0, 0);
        dft_gemm<2><<<dim3(2, ck*6), 256, 0, stream>>>(MHI, FF0, FF0+128, G, nullptr, k0);
      }
      dft_gemm<3><<<dim3(2, 192*3), 256, 0, stream>>>(MWI, G, G+128, XTb, nullptr, 0);
    }
  }

  // ---- LN2 stats ----
  ln_stats_kernel<<<P/4, 256, 0, stream>>>(XT, STATS);

  // ---- LeFF: strip-mined l1 gemm -> dwconv+gelu -> l2 MFMA gemm (+residual) ----
  {
    int SH = 32;
    while ((size_t)(3*SH+4)*98304 > pool && SH > 8) SH >>= 1;
    const size_t SB1SZ = (size_t)(SH+2)*98304;
    float* SB1[2] = { POOL, POOL + SB1SZ };
    float* SB2 = POOL + 2*SB1SZ;
    int nStrips = HGT/SH;
    for (int b = 0; b < NB; ++b){
      auto launch_g = [&](int s){
        int r0 = s*SH;
        int prow0 = (b*HGT + r0 - 1)*WID;
        gemm_mfma<2,false,true><<<dim3(8, (SH+2)*3), 256, 0, stream>>>(
            XT, l1_w, l1_b, SB1[s&1], 128, 512, 128,
            STATS, ln2_g, ln2_b, prow0, P-1);
      };
      launch_g(0);
      for (int s = 0; s < nStrips; ++s){
        if (s+1 < nStrips) launch_g(s+1);
        int r0 = s*SH;
        dwconv_strip<<<SH*384, 256, 0, stream>>>(SB1[s&1], dw_w, dw_b, SB2, r0);
        gemm_mfma<0,true,false><<<dim3(2, SH*3), 256, 0, stream>>>(
            SB2, l2_w, l2_b, XT + ((size_t)(b*HGT + r0)*WID)*C_DIM,
            512, 128, 512, nullptr, nullptr, nullptr, 0, 0);
      }
    }
  }

  // ---- final transpose per batch: XT(BHWC, in d_out) -> POOL(BCHW) -> copy back ----
  for (int b = 0; b < NB; ++b){
    transpose_b_kernel<<<dim3(3,192), 256, 0, stream>>>(XT + (size_t)b*Sb, POOL);
    hipMemcpyAsync((float*)d_out + (size_t)b*Sb, POOL, Sb*sizeof(float),
                   hipMemcpyDeviceToDevice, stream);
  }
}

// Round 10
// 2003.120 us; speedup vs baseline: 5.1917x; 1.2599x over previous
//
#include <hip/hip_runtime.h>
#include <math.h>

// ---------------- constants ----------------
#define C_DIM 128
#define HGT 192
#define WID 192
#define NB 4
#define WFD 97   // 192/2+1

// table offsets (floats)
#define T_BIAS 0                 // 4*64*64
#define T_MW   16384             // 256x192 combined rfft-W matrix
#define T_MHF  65536             // 384x384 combined fft-H matrix
#define T_MHI  212992            // 384x384 combined ifft-H matrix
#define T_MWI  360448            // 192x224 combined irfft-W matrix
#define TAB_SZ 403456            // table reserve (floats)

typedef __attribute__((ext_vector_type(8))) short bf16x8;
typedef __attribute__((ext_vector_type(4))) float f32x4;

__device__ __forceinline__ float gelu_f(float v){
  return 0.5f*v*(1.0f + erff(v*0.70710678118654752440f));
}
__device__ __forceinline__ unsigned short f2bf(float f){
  unsigned int u = __float_as_uint(f);
  unsigned int r = (u + 0x7FFFu + ((u>>16)&1u)) >> 16;
  return (unsigned short)r;
}

// ---------------- table build (exact int mod-192 + float trig) ----------------
__global__ __launch_bounds__(256) void build_tables(float* __restrict__ tab, const float* __restrict__ rpb){
  int idx = blockIdx.x*256 + threadIdx.x;
  const float STEP = (float)(6.283185307179586476925286766559/192.0);
  if (idx < 16384){ // attn bias: [head][n][m]
    int head = idx>>12, n = (idx>>6)&63, m = idx&63;
    int dh = n/16 - m/16 + 3;
    int dw = (n&15) - (m&15) + 15;
    tab[T_BIAS+idx] = rpb[(dh*31+dw)*4 + head];
    return;
  }
  idx -= 16384;
  if (idx < 49152){ // MW [256][192]: rows 0..96 cos, 97..193 -sin, rest 0
    int r = idx/192, w = idx%192;
    float v = 0.f;
    if (r < 97){ int a = (r*w)%192; v = cosf(a*STEP); }
    else if (r < 194){ int a = ((r-97)*w)%192; v = -sinf(a*STEP); }
    tab[T_MW+idx] = v;
    return;
  }
  idx -= 49152;
  if (idx < 147456){ // MHF [384][384]: re rows [cos|sin], im rows [-sin|cos]
    int r = idx/384, j = idx%384;
    int hf = (r < 192) ? r : r-192;
    int h  = (j < 192) ? j : j-192;
    int a = (hf*h)%192;
    float c = cosf(a*STEP), s = sinf(a*STEP);
    float v;
    if (r < 192) v = (j < 192) ? c : s;
    else         v = (j < 192) ? -s : c;
    tab[T_MHF+idx] = v;
    return;
  }
  idx -= 147456;
  if (idx < 147456){ // MHI [384][384]: re rows [cos|-sin], im rows [sin|cos]
    int r = idx/384, j = idx%384;
    int h  = (r < 192) ? r : r-192;
    int hf = (j < 192) ? j : j-192;
    int a = (h*hf)%192;
    float c = cosf(a*STEP), s = sinf(a*STEP);
    float v;
    if (r < 192) v = (j < 192) ? c : -s;
    else         v = (j < 192) ? s : c;
    tab[T_MHI+idx] = v;
    return;
  }
  idx -= 147456;
  if (idx < 43008){ // MWI [192][224]: cols 0..96 icos, 112..208 -isin, rest 0
    int w = idx/224, j = idx%224;
    float v = 0.f;
    if (j < 97){
      int a = (j*w)%192;
      float sc = ((j==0 || j==96) ? 1.f : 2.f) / 36864.f;
      v = sc*cosf(a*STEP);
    } else if (j >= 112 && j < 209){
      int k = j-112;
      int a = (k*w)%192;
      float sc = ((k==0 || k==96) ? 1.f : 2.f) / 36864.f;
      v = -sc*sinf(a*STEP);
    }
    tab[T_MWI+idx] = v;
  }
}

// ---------------- pos depthwise conv v4: 8h x 32w x 16c, 21.8 KB LDS ----------------
__global__ __launch_bounds__(256) void posconv3_kernel(const float* __restrict__ x, const float* __restrict__ pw,
                               const float* __restrict__ pb, float* __restrict__ xt){
  __shared__ float rows_s[16*340];    // [c][r(10)][wc(34)]; reused as out[256px][17]
  int w0 = blockIdx.x*32, h0 = blockIdx.y*8;
  int b = blockIdx.z >> 3, cb = (blockIdx.z & 7)*16;
  int tid = threadIdx.x;
  int hl = tid >> 5, wl = tid & 31;   // one pixel per thread
  for (int e = tid; e < 16*340; e += 256){
    int c = e / 340; int rem = e - c*340;
    int r = rem / 34; int wc = rem - r*34;
    int gh = h0 - 1 + r, gw = w0 - 1 + wc;
    float v = 0.f;
    if (gh >= 0 && gh < HGT && gw >= 0 && gw < WID)
      v = x[((size_t)(b*C_DIM + cb + c))*(HGT*WID) + gh*WID + gw];
    rows_s[e] = v;
  }
  __syncthreads();
  float outr[16];
  #pragma unroll
  for (int c = 0; c < 16; ++c){
    const float* rs = &rows_s[c*340];
    float wreg[9];
    #pragma unroll
    for (int t9 = 0; t9 < 9; ++t9) wreg[t9] = pw[(cb+c)*27 + 9 + t9];
    float bias = pb[cb+c];
    float acc = rs[(hl+1)*34 + wl+1] + bias;
    #pragma unroll
    for (int ky = 0; ky < 3; ++ky)
      #pragma unroll
      for (int kx = 0; kx < 3; ++kx)
        acc += wreg[ky*3+kx]*rs[(hl+ky)*34 + wl+kx];
    outr[c] = acc;
  }
  __syncthreads();
  // repack into rows_s as out[pixel][17]
  {
    int px = hl*32 + wl;
    #pragma unroll
    for (int c = 0; c < 16; ++c) rows_s[px*17 + c] = outr[c];
  }
  __syncthreads();
  // flush c-coalesced: 4096 elems, 16 c per pixel (64B segments)
  for (int r = 0; r < 16; ++r){
    int e = r*256 + tid;
    int cl = e & 15, hw = e >> 4;
    int h = hw >> 5, w = hw & 31;
    xt[((size_t)(b*HGT + h0+h)*WID + (w0+w))*C_DIM + cb + cl] = rows_s[hw*17 + cl];
  }
}

// ---------------- LN row stats (mean, rstd) ----------------
__global__ __launch_bounds__(256) void ln_stats_kernel(const float* __restrict__ src, float* __restrict__ stats){
  int wave = threadIdx.x >> 6; int lane = threadIdx.x & 63;
  size_t p = (size_t)blockIdx.x*4 + wave;
  const float* s = src + p*C_DIM;
  float v0 = s[lane], v1 = s[lane+64];
  float sum = v0 + v1;
  #pragma unroll
  for (int o=1; o<64; o<<=1) sum += __shfl_xor(sum, o, 64);
  float m = sum * (1.0f/128.0f);
  float d0 = v0-m, d1 = v1-m;
  float vs = d0*d0 + d1*d1;
  #pragma unroll
  for (int o=1; o<64; o<<=1) vs += __shfl_xor(vs, o, 64);
  float rstd = rsqrtf(vs*(1.0f/128.0f) + 1e-5f);
  if (lane==0){ stats[2*p] = m; stats[2*p+1] = rstd; }
}

// ---------------- bf16 MFMA GEMM ----------------
template<int ACT, bool ADD, bool LNA>
__global__ __launch_bounds__(256) void gemm_mfma(const float* __restrict__ A1,
                            const float* __restrict__ Wm, const float* __restrict__ bias,
                            float* __restrict__ dst, int K, int N, int lda,
                            const float* __restrict__ stats, const float* __restrict__ lng,
                            const float* __restrict__ lnb, int prow0, int pmax){
  __shared__ __align__(16) unsigned short As[64*40];
  __shared__ __align__(16) unsigned short Bs[64*40];
  int p0 = blockIdx.y*64, n0 = blockIdx.x*64;
  int tid = threadIdx.x;
  int wave = tid >> 6, lane = tid & 63;
  int wr = (wave>>1)*32, wc = (wave&1)*32;
  f32x4 acc00 = {}, acc01 = {}, acc10 = {}, acc11 = {};
  int am = tid >> 2, ak = (tid & 3)*8;
  int bk = tid >> 3, bn = (tid & 7)*8;
  for (int k0 = 0; k0 < K; k0 += 32){
    {
      int gp = p0 + am;
      float s0 = 0.f, s1 = 0.f;
      if (LNA){
        gp += prow0;
        gp = gp < 0 ? 0 : (gp > pmax ? pmax : gp);
        s0 = stats[2*gp]; s1 = stats[2*gp+1];
      }
      const float* src = A1 + (size_t)gp*lda + k0 + ak;
      float4 aa = *(const float4*)src;
      float4 ab = *(const float4*)(src+4);
      float v[8] = {aa.x,aa.y,aa.z,aa.w,ab.x,ab.y,ab.z,ab.w};
      unsigned short* dp = &As[am*40 + ak];
      #pragma unroll
      for (int j=0;j<8;j++){
        float f = v[j];
        if (LNA) f = (f - s0)*s1*lng[k0+ak+j] + lnb[k0+ak+j];
        dp[j] = f2bf(f);
      }
    }
    {
      const float* src = Wm + (size_t)(k0+bk)*N + n0 + bn;
      float4 wa = *(const float4*)src;
      float4 wb = *(const float4*)(src+4);
      float v[8] = {wa.x,wa.y,wa.z,wa.w,wb.x,wb.y,wb.z,wb.w};
      #pragma unroll
      for (int j=0;j<8;j++) Bs[(bn+j)*40 + bk] = f2bf(v[j]);
    }
    __syncthreads();
    int fm = lane & 15, kg = (lane>>4)*8;
    bf16x8 a0 = *(const bf16x8*)&As[(wr+fm)*40 + kg];
    bf16x8 a1 = *(const bf16x8*)&As[(wr+16+fm)*40 + kg];
    bf16x8 b0 = *(const bf16x8*)&Bs[(wc+fm)*40 + kg];
    bf16x8 b1 = *(const bf16x8*)&Bs[(wc+16+fm)*40 + kg];
    acc00 = __builtin_amdgcn_mfma_f32_16x16x32_bf16(a0, b0, acc00, 0,0,0);
    acc01 = __builtin_amdgcn_mfma_f32_16x16x32_bf16(a0, b1, acc01, 0,0,0);
    acc10 = __builtin_amdgcn_mfma_f32_16x16x32_bf16(a1, b0, acc10, 0,0,0);
    acc11 = __builtin_amdgcn_mfma_f32_16x16x32_bf16(a1, b1, acc11, 0,0,0);
    __syncthreads();
  }
  int cn = lane & 15, rq = (lane>>4)*4;
  #pragma unroll
  for (int mi=0; mi<2; ++mi){
    #pragma unroll
    for (int ni=0; ni<2; ++ni){
      f32x4 a = (mi==0) ? (ni==0?acc00:acc01) : (ni==0?acc10:acc11);
      int n = n0 + wc + ni*16 + cn;
      float bsv = bias[n];
      #pragma unroll
      for (int r=0; r<4; ++r){
        size_t row = (size_t)p0 + wr + mi*16 + rq + r;
        float v = a[r] + bsv;
        if (ACT==1) v = (v>=0.f) ? v : 0.01f*v;
        if (ACT==2) v = gelu_f(v);
        if (ADD) v += dst[row*(size_t)N + n];
        dst[row*(size_t)N + n] = v;
      }
    }
  }
}

// ---------------- fused Q+KV GEMM (LNA from XT; weight select per block) ----------------
__global__ __launch_bounds__(256) void gemm_qkv(const float* __restrict__ A1,
                            const float* __restrict__ qw, const float* __restrict__ qb,
                            const float* __restrict__ kvw, const float* __restrict__ kvb,
                            float* __restrict__ Qc, float* __restrict__ KVc,
                            const float* __restrict__ stats, const float* __restrict__ lng,
                            const float* __restrict__ lnb, int prow0, int pmax){
  __shared__ __align__(16) unsigned short As[64*40];
  __shared__ __align__(16) unsigned short Bs[64*40];
  int p0 = blockIdx.y*64, gn0 = blockIdx.x*64;   // gn0 in [0,384)
  bool isQ = (gn0 < 128);
  const float* Wm  = isQ ? qw : kvw;
  const float* bias= isQ ? qb : kvb;
  float* dst       = isQ ? Qc : KVc;
  int N            = isQ ? 128 : 256;
  int n0           = isQ ? gn0 : gn0 - 128;
  int tid = threadIdx.x;
  int wave = tid >> 6, lane = tid & 63;
  int wr = (wave>>1)*32, wc = (wave&1)*32;
  f32x4 acc00 = {}, acc01 = {}, acc10 = {}, acc11 = {};
  int am = tid >> 2, ak = (tid & 3)*8;
  int bk = tid >> 3, bn = (tid & 7)*8;
  for (int k0 = 0; k0 < 128; k0 += 32){
    {
      int gp = p0 + am + prow0;
      gp = gp < 0 ? 0 : (gp > pmax ? pmax : gp);
      float s0 = stats[2*gp], s1 = stats[2*gp+1];
      const float* src = A1 + (size_t)gp*128 + k0 + ak;
      float4 aa = *(const float4*)src;
      float4 ab = *(const float4*)(src+4);
      float v[8] = {aa.x,aa.y,aa.z,aa.w,ab.x,ab.y,ab.z,ab.w};
      unsigned short* dp = &As[am*40 + ak];
      #pragma unroll
      for (int j=0;j<8;j++){
        float f = (v[j] - s0)*s1*lng[k0+ak+j] + lnb[k0+ak+j];
        dp[j] = f2bf(f);
      }
    }
    {
      const float* src = Wm + (size_t)(k0+bk)*N + n0 + bn;
      float4 wa = *(const float4*)src;
      float4 wb = *(const float4*)(src+4);
      float v[8] = {wa.x,wa.y,wa.z,wa.w,wb.x,wb.y,wb.z,wb.w};
      #pragma unroll
      for (int j=0;j<8;j++) Bs[(bn+j)*40 + bk] = f2bf(v[j]);
    }
    __syncthreads();
    int fm = lane & 15, kg = (lane>>4)*8;
    bf16x8 a0 = *(const bf16x8*)&As[(wr+fm)*40 + kg];
    bf16x8 a1 = *(const bf16x8*)&As[(wr+16+fm)*40 + kg];
    bf16x8 b0 = *(const bf16x8*)&Bs[(wc+fm)*40 + kg];
    bf16x8 b1 = *(const bf16x8*)&Bs[(wc+16+fm)*40 + kg];
    acc00 = __builtin_amdgcn_mfma_f32_16x16x32_bf16(a0, b0, acc00, 0,0,0);
    acc01 = __builtin_amdgcn_mfma_f32_16x16x32_bf16(a0, b1, acc01, 0,0,0);
    acc10 = __builtin_amdgcn_mfma_f32_16x16x32_bf16(a1, b0, acc10, 0,0,0);
    acc11 = __builtin_amdgcn_mfma_f32_16x16x32_bf16(a1, b1, acc11, 0,0,0);
    __syncthreads();
  }
  int cn = lane & 15, rq = (lane>>4)*4;
  #pragma unroll
  for (int mi=0; mi<2; ++mi){
    #pragma unroll
    for (int ni=0; ni<2; ++ni){
      f32x4 a = (mi==0) ? (ni==0?acc00:acc01) : (ni==0?acc10:acc11);
      int n = n0 + wc + ni*16 + cn;
      float bsv = bias[n];
      #pragma unroll
      for (int r=0; r<4; ++r){
        size_t row = (size_t)p0 + wr + mi*16 + rq + r;
        dst[row*(size_t)N + n] = a[r] + bsv;
      }
    }
  }
}

// ---------------- DFT-as-GEMM ----------------
template<int MODE>
__global__ __launch_bounds__(256) void dft_gemm(const float* __restrict__ Atab,
                            const float* __restrict__ W1, const float* __restrict__ W2,
                            float* __restrict__ D1, float* __restrict__ D2, int k0){
  constexpr int K      = (MODE==0)?192 : (MODE==3)?224 : 384;
  constexpr int MT     = (MODE==0)?4 : (MODE==3)?3 : 6;
  constexpr int MVALID = (MODE==0)?194 : (MODE==3)?192 : 384;
  __shared__ __align__(16) unsigned short As[64*40];
  __shared__ __align__(16) unsigned short Bs[64*40];
  int slab = blockIdx.y / MT;
  int p0 = (blockIdx.y % MT)*64, n0 = blockIdx.x*64;
  int tid = threadIdx.x;
  int wave = tid >> 6, lane = tid & 63;
  int wr = (wave>>1)*32, wc = (wave&1)*32;
  f32x4 acc00 = {}, acc01 = {}, acc10 = {}, acc11 = {};
  int am = tid >> 2, ak = (tid & 3)*8;
  int bk = tid >> 3, bn = (tid & 7)*8;
  for (int kk0 = 0; kk0 < K; kk0 += 32){
    {
      const float* src = Atab + (size_t)(p0+am)*K + kk0 + ak;
      float4 aa = *(const float4*)src;
      float4 ab = *(const float4*)(src+4);
      float v[8] = {aa.x,aa.y,aa.z,aa.w,ab.x,ab.y,ab.z,ab.w};
      unsigned short* dp = &As[am*40 + ak];
      #pragma unroll
      for (int j=0;j<8;j++) dp[j] = f2bf(v[j]);
    }
    {
      int r = kk0 + bk;
      const float* src;
      if (MODE==0)      src = W1 + (size_t)slab*24576 + (size_t)r*128;
      else if (MODE==1) src = (r<192) ? W1 + (size_t)(k0+slab)*128 + (size_t)r*12416
                                      : W2 + (size_t)(k0+slab)*128 + (size_t)(r-192)*12416;
      else if (MODE==2) src = (r<192) ? W1 + (size_t)slab*49152 + (size_t)r*256
                                      : W2 + (size_t)slab*49152 + (size_t)(r-192)*256;
      else              src = (r<112) ? W1 + (size_t)slab*24832 + (size_t)r*256
                                      : W2 + (size_t)slab*24832 + (size_t)(r-112)*256;
      src += n0 + bn;
      float4 wa = *(const float4*)src;
      float4 wb = *(const float4*)(src+4);
      float v[8] = {wa.x,wa.y,wa.z,wa.w,wb.x,wb.y,wb.z,wb.w};
      #pragma unroll
      for (int j=0;j<8;j++) Bs[(bn+j)*40 + bk] = f2bf(v[j]);
    }
    __syncthreads();
    int fm = lane & 15, kg = (lane>>4)*8;
    bf16x8 a0 = *(const bf16x8*)&As[(wr+fm)*40 + kg];
    bf16x8 a1 = *(const bf16x8*)&As[(wr+16+fm)*40 + kg];
    bf16x8 b0 = *(const bf16x8*)&Bs[(wc+fm)*40 + kg];
    bf16x8 b1 = *(const bf16x8*)&Bs[(wc+16+fm)*40 + kg];
    acc00 = __builtin_amdgcn_mfma_f32_16x16x32_bf16(a0, b0, acc00, 0,0,0);
    acc01 = __builtin_amdgcn_mfma_f32_16x16x32_bf16(a0, b1, acc01, 0,0,0);
    acc10 = __builtin_amdgcn_mfma_f32_16x16x32_bf16(a1, b0, acc10, 0,0,0);
    acc11 = __builtin_amdgcn_mfma_f32_16x16x32_bf16(a1, b1, acc11, 0,0,0);
    __syncthreads();
  }
  int cn = lane & 15, rq = (lane>>4)*4;
  #pragma unroll
  for (int mi=0; mi<2; ++mi){
    #pragma unroll
    for (int ni=0; ni<2; ++ni){
      f32x4 a = (mi==0) ? (ni==0?acc00:acc01) : (ni==0?acc10:acc11);
      int n = n0 + wc + ni*16 + cn;
      #pragma unroll
      for (int r=0; r<4; ++r){
        int p = p0 + wr + mi*16 + rq + r;
        if (p >= MVALID) continue;
        float v = a[r];
        if (MODE==0){
          if (p < 97) D1[(size_t)slab*12416 + (size_t)p*128 + n] = v;
          else        D2[(size_t)slab*12416 + (size_t)(p-97)*128 + n] = v;
        } else if (MODE==1){
          float* base = D1 + (size_t)slab*49152;
          if (p < 192) base[(size_t)p*256 + n] = v;
          else         base[(size_t)(p-192)*256 + 128 + n] = v;
        } else if (MODE==2){
          int kg2 = k0 + slab;
          if (p < 192) D1[((size_t)p*97 + kg2)*256 + n] = v;
          else         D1[((size_t)(p-192)*97 + kg2)*256 + 128 + n] = v;
        } else {
          D1[(size_t)slab*24576 + (size_t)p*128 + n] += v;
        }
      }
    }
  }
}

// ---------------- MFMA window attention: block = window, wave = head ----------------
__global__ __launch_bounds__(256) void attn_mfma(
    const float* __restrict__ Qc, const float* __restrict__ KVc,
    const float* __restrict__ biasT, float* __restrict__ OUTc,
    int win0, int prow0){
  __shared__ __align__(16) unsigned short P_s[4][64][72];
  __shared__ __align__(16) unsigned short Vt_s[4][32][72];
  int win = win0 + blockIdx.x;
  int b = win/576, rem = win%576, whi = rem/12, wwi = rem%12;
  int tid = threadIdx.x;
  int wave = tid>>6, lane = tid&63, head = wave;
  int rowbase0 = (b*HGT + whi*4)*WID + wwi*16 - prow0;
  int fm = lane & 15, kg = (lane>>4)*8;
  bf16x8 qf[4], kf[4];
  #pragma unroll
  for (int t4=0; t4<4; ++t4){
    {
      const float* qp = Qc + (size_t)(rowbase0 + t4*WID + fm)*128 + head*32 + kg;
      float4 a = *(const float4*)qp, b4 = *(const float4*)(qp+4);
      float v[8] = {a.x,a.y,a.z,a.w,b4.x,b4.y,b4.z,b4.w};
      bf16x8 f;
      #pragma unroll
      for (int j=0;j<8;j++) f[j] = (short)f2bf(v[j]*0.17677669529663688f);
      qf[t4] = f;
    }
    {
      const float* kp = KVc + (size_t)(rowbase0 + t4*WID + fm)*256 + head*32 + kg;
      float4 a = *(const float4*)kp, b4 = *(const float4*)(kp+4);
      float v[8] = {a.x,a.y,a.z,a.w,b4.x,b4.y,b4.z,b4.w};
      bf16x8 f;
      #pragma unroll
      for (int j=0;j<8;j++) f[j] = (short)f2bf(v[j]);
      kf[t4] = f;
    }
  }
  {
    int lv = rowbase0 + (lane>>4)*WID + (lane&15);
    const float* vp = KVc + (size_t)lv*256 + 128 + head*32;
    #pragma unroll
    for (int d4=0; d4<8; ++d4){
      float4 v4 = *(const float4*)(vp + d4*4);
      Vt_s[wave][d4*4+0][lane] = f2bf(v4.x);
      Vt_s[wave][d4*4+1][lane] = f2bf(v4.y);
      Vt_s[wave][d4*4+2][lane] = f2bf(v4.z);
      Vt_s[wave][d4*4+3][lane] = f2bf(v4.w);
    }
  }
  f32x4 s[4][4];
  #pragma unroll
  for (int ni=0; ni<4; ++ni)
    #pragma unroll
    for (int mj=0; mj<4; ++mj){
      f32x4 z = {};
      s[ni][mj] = __builtin_amdgcn_mfma_f32_16x16x32_bf16(qf[ni], kf[mj], z, 0,0,0);
    }
  const float* bp = biasT + head*4096;
  #pragma unroll
  for (int ni=0; ni<4; ++ni){
    int nbase = ni*16 + (lane>>4)*4;
    #pragma unroll
    for (int mj=0; mj<4; ++mj){
      int m = mj*16 + fm;
      #pragma unroll
      for (int r=0;r<4;r++)
        s[ni][mj][r] += bp[(nbase+r)*64 + m];
    }
  }
  float rs[4][4];
  #pragma unroll
  for (int ni=0; ni<4; ++ni){
    #pragma unroll
    for (int r=0;r<4;r++){
      float t = fmaxf(fmaxf(s[ni][0][r], s[ni][1][r]), fmaxf(s[ni][2][r], s[ni][3][r]));
      #pragma unroll
      for (int o=1;o<16;o<<=1) t = fmaxf(t, __shfl_xor(t, o, 64));
      float sum = 0.f;
      #pragma unroll
      for (int mj=0; mj<4; ++mj){
        float e = expf(s[ni][mj][r] - t);
        s[ni][mj][r] = e;
        sum += e;
      }
      #pragma unroll
      for (int o=1;o<16;o<<=1) sum += __shfl_xor(sum, o, 64);
      rs[ni][r] = sum;
    }
  }
  #pragma unroll
  for (int ni=0; ni<4; ++ni){
    int nbase = ni*16 + (lane>>4)*4;
    #pragma unroll
    for (int mj=0; mj<4; ++mj){
      int m = mj*16 + fm;
      #pragma unroll
      for (int r=0;r<4;r++)
        P_s[wave][nbase+r][m] = f2bf(s[ni][mj][r]);
    }
  }
  f32x4 o2[4][2] = {};
  #pragma unroll
  for (int ks=0; ks<2; ++ks){
    bf16x8 vb0 = *(const bf16x8*)&Vt_s[wave][fm][ks*32+kg];
    bf16x8 vb1 = *(const bf16x8*)&Vt_s[wave][16+fm][ks*32+kg];
    #pragma unroll
    for (int ni=0; ni<4; ++ni){
      bf16x8 pa = *(const bf16x8*)&P_s[wave][ni*16+fm][ks*32+kg];
      o2[ni][0] = __builtin_amdgcn_mfma_f32_16x16x32_bf16(pa, vb0, o2[ni][0], 0,0,0);
      o2[ni][1] = __builtin_amdgcn_mfma_f32_16x16x32_bf16(pa, vb1, o2[ni][1], 0,0,0);
    }
  }
  #pragma unroll
  for (int ni=0; ni<4; ++ni){
    #pragma unroll
    for (int r=0;r<4;r++){
      int l = rowbase0 + ni*WID + (lane>>4)*4 + r;
      float inv = 1.0f / rs[ni][r];
      float* op = OUTc + (size_t)l*128 + head*32;
      op[fm]    = o2[ni][0][r]*inv;
      op[16+fm] = o2[ni][1][r]*inv;
    }
  }
}

// ---------------- LeFF dwconv strip ----------------
__global__ __launch_bounds__(256) void dwconv_strip(const float* __restrict__ SB1, const float* __restrict__ dw,
                                                    const float* __restrict__ db, float* __restrict__ SB2,
                                                    int r0){
  int id = blockIdx.x*256 + threadIdx.x;
  int ch = id & 511; int t = id >> 9; int w = t % 192; int hl = t / 192;
  int h = r0 + hl;
  float acc = db[ch];
  #pragma unroll
  for (int ky=0; ky<3; ky++){
    int hh = h+ky-1;
    if (hh<0 || hh>=HGT) continue;
    int br = hl + ky;
    #pragma unroll
    for (int kx=0; kx<3; kx++){
      int ww = w+kx-1;
      if (ww<0 || ww>=WID) continue;
      acc += dw[ch*9+ky*3+kx]*SB1[((size_t)br*WID + ww)*512 + ch];
    }
  }
  SB2[id] = gelu_f(acc);
}

// ---------------- per-batch BHWC -> BCHW transpose ----------------
__global__ __launch_bounds__(256) void transpose_b_kernel(const float* __restrict__ src, float* __restrict__ dst){
  __shared__ float tile[128*65];
  int w0 = blockIdx.x*64, h = blockIdx.y;
  int tid = threadIdx.x;
  for (int r=0; r<32; r++){
    int e = tid + 256*r; int c = e & 127, wl = e >> 7;
    tile[c*65 + wl] = src[((size_t)h*WID + w0 + wl)*C_DIM + c];
  }
  __syncthreads();
  for (int r=0; r<32; r++){
    int e = tid + 256*r; int wl = e & 63, c = e >> 6;
    dst[((size_t)c*HGT + h)*WID + w0 + wl] = tile[c*65 + wl];
  }
}

// ---------------- host ----------------
extern "C" void kernel_launch(void* const* d_in, const int* in_sizes, int n_in,
                              void* d_out, int out_size, void* d_ws, size_t ws_size,
                              hipStream_t stream) {
  const float* x      = (const float*)d_in[0];
  const float* pos_w  = (const float*)d_in[1];
  const float* pos_b  = (const float*)d_in[2];
  const float* ln1_g  = (const float*)d_in[3];
  const float* ln1_b  = (const float*)d_in[4];
  const float* q_w    = (const float*)d_in[5];
  const float* q_b    = (const float*)d_in[6];
  const float* kv_w   = (const float*)d_in[7];
  const float* kv_b   = (const float*)d_in[8];
  const float* rpb    = (const float*)d_in[9];
  const float* proj_w = (const float*)d_in[10];
  const float* proj_b = (const float*)d_in[11];
  const float* fft1_w = (const float*)d_in[12];
  const float* fft1_b = (const float*)d_in[13];
  const float* fft2_w = (const float*)d_in[14];
  const float* fft2_b = (const float*)d_in[15];
  const float* ln2_g  = (const float*)d_in[16];
  const float* ln2_b  = (const float*)d_in[17];
  const float* l1_w   = (const float*)d_in[18];
  const float* l1_b   = (const float*)d_in[19];
  const float* dw_w   = (const float*)d_in[20];
  const float* dw_b   = (const float*)d_in[21];
  const float* l2_w   = (const float*)d_in[22];
  const float* l2_b   = (const float*)d_in[23];

  const size_t S   = (size_t)NB*HGT*WID*C_DIM;   // 18,874,368
  const size_t Sb  = S/NB;                       //  4,718,592
  const size_t SZb = (size_t)HGT*WFD*C_DIM;      //  2,383,872
  const size_t GSZ = (size_t)HGT*WFD*256;        //  4,767,744
  const int    P   = (int)(NB*HGT*WID);          // 147,456

  float* XT = (float*)d_out;

  float* ws    = (float*)d_ws;
  float* TAB   = ws;
  float* STATS = ws + TAB_SZ;
  float* POOL  = ws + TAB_SZ + 2*(size_t)P;
  size_t head  = TAB_SZ + 2*(size_t)P;
  size_t pool  = (ws_size/4 > head) ? (ws_size/4 - head) : 0;

  const float* biasT = TAB + T_BIAS;
  const float* MW  = TAB + T_MW;
  const float* MHF = TAB + T_MHF;
  const float* MHI = TAB + T_MHI;
  const float* MWI = TAB + T_MWI;

  build_tables<<<1576, 256, 0, stream>>>(TAB, rpb);
  posconv3_kernel<<<dim3(6,24,32), 256, 0, stream>>>(x, pos_w, pos_b, XT);

  // ---- attention: LN1 stats -> per-chunk {qkv gemm, attn(MFMA), proj gemm} ----
  ln_stats_kernel<<<P/4, 256, 0, stream>>>(XT, STATS);
  {
    int winChunk = (int)((pool/(64*512)/12)*12);
    if (winChunk < 12) winChunk = 12;
    if (winChunk > 2304) winChunk = 2304;
    for (int w0 = 0; w0 < 2304; w0 += winChunk){
      int nw = (2304 - w0 < winChunk) ? (2304 - w0) : winChunk;
      int R = nw*64, prow0 = w0*64;
      float* Qc   = POOL;
      float* KVc  = POOL + (size_t)R*128;
      float* OUTc = POOL + (size_t)R*384;
      gemm_qkv<<<dim3(6, R/64), 256, 0, stream>>>(
          XT, q_w, q_b, kv_w, kv_b, Qc, KVc, STATS, ln1_g, ln1_b, prow0, P-1);
      attn_mfma<<<nw, 256, 0, stream>>>(Qc, KVc, biasT, OUTc, w0, prow0);
      gemm_mfma<0,true,false><<<dim3(2, R/64), 256, 0, stream>>>(
          OUTc, proj_w, proj_b, XT + (size_t)prow0*C_DIM,
          128, 128, 128, nullptr, nullptr, nullptr, 0, 0);
    }
  }

  // ---- FFT residual branch: all-MFMA (DFT-as-GEMM + mixes), chunked over k ----
  {
    float* FR  = POOL;
    float* FI  = POOL + SZb;
    float* G   = POOL + 2*SZb;
    size_t fixed = 2*SZb + GSZ;
    int CK = 1;
    if (pool > fixed + 98304) CK = (int)((pool - fixed)/98304);
    if (CK < 1) CK = 1;
    if (CK > WFD) CK = WFD;
    float* FF0 = POOL + fixed;
    float* FF1 = FF0 + (size_t)CK*49152;
    for (int b = 0; b < NB; ++b){
      float* XTb = XT + (size_t)b*Sb;
      dft_gemm<0><<<dim3(2, 192*4), 256, 0, stream>>>(MW, XTb, nullptr, FR, FI, 0);
      for (int k0 = 0; k0 < WFD; k0 += CK){
        int ck = (WFD - k0 < CK) ? (WFD - k0) : CK;
        int rows = ck*192;
        dft_gemm<1><<<dim3(2, ck*6), 256, 0, stream>>>(MHF, FR, FI, FF0, nullptr, k0);
        gemm_mfma<1,false,false><<<dim3(4, rows/64), 256, 0, stream>>>(
            FF0, fft1_w, fft1_b, FF1, 256, 256, 256,
            nullptr, nullptr, nullptr, 0, 0);
        gemm_mfma<0,false,false><<<dim3(4, rows/64), 256, 0, stream>>>(
            FF1, fft2_w, fft2_b, FF0, 256, 256, 256,
            nullptr, nullptr, nullptr, 0, 0);
        dft_gemm<2><<<dim3(2, ck*6), 256, 0, stream>>>(MHI, FF0, FF0+128, G, nullptr, k0);
      }
      dft_gemm<3><<<dim3(2, 192*3), 256, 0, stream>>>(MWI, G, G+128, XTb, nullptr, 0);
    }
  }

  // ---- LN2 stats ----
  ln_stats_kernel<<<P/4, 256, 0, stream>>>(XT, STATS);

  // ---- LeFF: strip-mined l1 gemm -> dwconv+gelu -> l2 MFMA gemm (+residual) ----
  {
    int SH = 96;
    while ((size_t)(3*SH+4)*98304 > pool && SH > 24) SH >>= 1;
    const size_t SB1SZ = (size_t)(SH+2)*98304;
    float* SB1[2] = { POOL, POOL + SB1SZ };
    float* SB2 = POOL + 2*SB1SZ;
    int nStrips = HGT/SH;
    for (int b = 0; b < NB; ++b){
      auto launch_g = [&](int s){
        int r0 = s*SH;
        int prow0 = (b*HGT + r0 - 1)*WID;
        gemm_mfma<2,false,true><<<dim3(8, (SH+2)*3), 256, 0, stream>>>(
            XT, l1_w, l1_b, SB1[s&1], 128, 512, 128,
            STATS, ln2_g, ln2_b, prow0, P-1);
      };
      launch_g(0);
      for (int s = 0; s < nStrips; ++s){
        if (s+1 < nStrips) launch_g(s+1);
        int r0 = s*SH;
        dwconv_strip<<<SH*384, 256, 0, stream>>>(SB1[s&1], dw_w, dw_b, SB2, r0);
        gemm_mfma<0,true,false><<<dim3(2, SH*3), 256, 0, stream>>>(
            SB2, l2_w, l2_b, XT + ((size_t)(b*HGT + r0)*WID)*C_DIM,
            512, 128, 512, nullptr, nullptr, nullptr, 0, 0);
      }
    }
  }

  // ---- final transpose per batch: XT(BHWC, in d_out) -> POOL(BCHW) -> copy back ----
  for (int b = 0; b < NB; ++b){
    transpose_b_kernel<<<dim3(3,192), 256, 0, stream>>>(XT + (size_t)b*Sb, POOL);
    hipMemcpyAsync((float*)d_out + (size_t)b*Sb, POOL, Sb*sizeof(float),
                   hipMemcpyDeviceToDevice, stream);
  }
}

// Round 11
// 1686.658 us; speedup vs baseline: 6.1658x; 1.1876x over previous
//
#include <hip/hip_runtime.h>
#include <math.h>

// ---------------- constants ----------------
#define C_DIM 128
#define HGT 192
#define WID 192
#define NB 4
#define WFD 97   // 192/2+1

// TAB float region
#define T_BIAS  0                // 4*64*64 fp32
#define T_QKVB  16384            // 384 fp32 (q_b | kv_b)
#define TF_SZ   16896
// TAB bf16 region (ushort offsets, base = TAB + TF_SZ floats)
#define UT_MW    0               // [256][192]
#define UT_MHF   49152           // [384][384]
#define UT_MHI   196608          // [384][384]
#define UT_MWI   344064          // [192][224]
#define UT_QKVW  387072          // [384][128]
#define UT_PROJW 436224          // [128][128]
#define UT_FFT1W 452608          // [256][256]
#define UT_FFT2W 518144          // [256][256]
#define UT_L1W   583680          // [512][128]
#define UT_L2W   649216          // [128][512]
#define UT_TOT   714752
#define TAB_SZ   374272          // floats: TF_SZ + UT_TOT/2

typedef __attribute__((ext_vector_type(8))) short bf16x8;
typedef __attribute__((ext_vector_type(4))) float f32x4;

__device__ __forceinline__ float gelu_f(float v){
  return 0.5f*v*(1.0f + erff(v*0.70710678118654752440f));
}
__device__ __forceinline__ unsigned short f2bf(float f){
  unsigned int u = __float_as_uint(f);
  unsigned int r = (u + 0x7FFFu + ((u>>16)&1u)) >> 16;
  return (unsigned short)r;
}
__device__ __forceinline__ float bf2f(unsigned short u){
  unsigned int x = ((unsigned int)u)<<16;
  return __uint_as_float(x);
}
__device__ __forceinline__ void st8u(unsigned short* d, bf16x8 v){
  unsigned int* wp = (unsigned int*)&v;
  unsigned int* dp = (unsigned int*)d;
  dp[0]=wp[0]; dp[1]=wp[1]; dp[2]=wp[2]; dp[3]=wp[3];
}

// ---------------- table build ----------------
__global__ __launch_bounds__(256) void build_tables(float* __restrict__ tab,
        const float* __restrict__ rpb, const float* __restrict__ q_b, const float* __restrict__ kv_b,
        const float* __restrict__ q_w, const float* __restrict__ kv_w, const float* __restrict__ proj_w,
        const float* __restrict__ fft1_w, const float* __restrict__ fft2_w,
        const float* __restrict__ l1_w, const float* __restrict__ l2_w){
  int idx = blockIdx.x*256 + threadIdx.x;
  const float STEP = (float)(6.283185307179586476925286766559/192.0);
  if (idx < 16384){ // attn bias fp32: [head][n][m]
    int head = idx>>12, n = (idx>>6)&63, m = idx&63;
    int dh = n/16 - m/16 + 3;
    int dw = (n&15) - (m&15) + 15;
    tab[T_BIAS+idx] = rpb[(dh*31+dw)*4 + head];
    return;
  }
  idx -= 16384;
  if (idx < 384){ // QKV bias concat fp32
    tab[T_QKVB+idx] = (idx < 128) ? q_b[idx] : kv_b[idx-128];
    return;
  }
  idx -= 384;
  unsigned short* ut = (unsigned short*)(tab + TF_SZ);
  if (idx < 49152){ // MW [256][192]
    int r = idx/192, w = idx%192;
    float v = 0.f;
    if (r < 97){ int a = (r*w)%192; v = cosf(a*STEP); }
    else if (r < 194){ int a = ((r-97)*w)%192; v = -sinf(a*STEP); }
    ut[UT_MW+idx] = f2bf(v);
    return;
  }
  idx -= 49152;
  if (idx < 147456){ // MHF [384][384]
    int r = idx/384, j = idx%384;
    int hf = (r < 192) ? r : r-192;
    int h  = (j < 192) ? j : j-192;
    int a = (hf*h)%192;
    float c = cosf(a*STEP), s = sinf(a*STEP);
    float v;
    if (r < 192) v = (j < 192) ? c : s;
    else         v = (j < 192) ? -s : c;
    ut[UT_MHF+idx] = f2bf(v);
    return;
  }
  idx -= 147456;
  if (idx < 147456){ // MHI [384][384]
    int r = idx/384, j = idx%384;
    int h  = (r < 192) ? r : r-192;
    int hf = (j < 192) ? j : j-192;
    int a = (h*hf)%192;
    float c = cosf(a*STEP), s = sinf(a*STEP);
    float v;
    if (r < 192) v = (j < 192) ? c : -s;
    else         v = (j < 192) ? s : c;
    ut[UT_MHI+idx] = f2bf(v);
    return;
  }
  idx -= 147456;
  if (idx < 43008){ // MWI [192][224]
    int w = idx/224, j = idx%224;
    float v = 0.f;
    if (j < 97){
      int a = (j*w)%192;
      float sc = ((j==0 || j==96) ? 1.f : 2.f) / 36864.f;
      v = sc*cosf(a*STEP);
    } else if (j >= 112 && j < 209){
      int k = j-112;
      int a = (k*w)%192;
      float sc = ((k==0 || k==96) ? 1.f : 2.f) / 36864.f;
      v = -sc*sinf(a*STEP);
    }
    ut[UT_MWI+idx] = f2bf(v);
    return;
  }
  idx -= 43008;
  if (idx < 49152){ // QKVW [384][128]
    int n = idx/128, k = idx%128;
    float v = (n < 128) ? q_w[(size_t)k*128 + n] : kv_w[(size_t)k*256 + (n-128)];
    ut[UT_QKVW+idx] = f2bf(v);
    return;
  }
  idx -= 49152;
  if (idx < 16384){ // PROJW [128][128]
    int n = idx/128, k = idx%128;
    ut[UT_PROJW+idx] = f2bf(proj_w[(size_t)k*128 + n]);
    return;
  }
  idx -= 16384;
  if (idx < 65536){ // FFT1W [256][256]
    int n = idx/256, k = idx%256;
    ut[UT_FFT1W+idx] = f2bf(fft1_w[(size_t)k*256 + n]);
    return;
  }
  idx -= 65536;
  if (idx < 65536){ // FFT2W [256][256]
    int n = idx/256, k = idx%256;
    ut[UT_FFT2W+idx] = f2bf(fft2_w[(size_t)k*256 + n]);
    return;
  }
  idx -= 65536;
  if (idx < 65536){ // L1W [512][128]
    int n = idx/128, k = idx%128;
    ut[UT_L1W+idx] = f2bf(l1_w[(size_t)k*512 + n]);
    return;
  }
  idx -= 65536;
  if (idx < 65536){ // L2W [128][512]
    int n = idx/512, k = idx%512;
    ut[UT_L2W+idx] = f2bf(l2_w[(size_t)k*128 + n]);
  }
}

// ---------------- pos depthwise conv: 8h x 32w x 16c ----------------
__global__ __launch_bounds__(256) void posconv3_kernel(const float* __restrict__ x, const float* __restrict__ pw,
                               const float* __restrict__ pb, float* __restrict__ xt){
  __shared__ float rows_s[16*340];
  int w0 = blockIdx.x*32, h0 = blockIdx.y*8;
  int b = blockIdx.z >> 3, cb = (blockIdx.z & 7)*16;
  int tid = threadIdx.x;
  int hl = tid >> 5, wl = tid & 31;
  for (int e = tid; e < 16*340; e += 256){
    int c = e / 340; int rem = e - c*340;
    int r = rem / 34; int wc = rem - r*34;
    int gh = h0 - 1 + r, gw = w0 - 1 + wc;
    float v = 0.f;
    if (gh >= 0 && gh < HGT && gw >= 0 && gw < WID)
      v = x[((size_t)(b*C_DIM + cb + c))*(HGT*WID) + gh*WID + gw];
    rows_s[e] = v;
  }
  __syncthreads();
  float outr[16];
  #pragma unroll
  for (int c = 0; c < 16; ++c){
    const float* rs = &rows_s[c*340];
    float wreg[9];
    #pragma unroll
    for (int t9 = 0; t9 < 9; ++t9) wreg[t9] = pw[(cb+c)*27 + 9 + t9];
    float bias = pb[cb+c];
    float acc = rs[(hl+1)*34 + wl+1] + bias;
    #pragma unroll
    for (int ky = 0; ky < 3; ++ky)
      #pragma unroll
      for (int kx = 0; kx < 3; ++kx)
        acc += wreg[ky*3+kx]*rs[(hl+ky)*34 + wl+kx];
    outr[c] = acc;
  }
  __syncthreads();
  {
    int px = hl*32 + wl;
    #pragma unroll
    for (int c = 0; c < 16; ++c) rows_s[px*17 + c] = outr[c];
  }
  __syncthreads();
  for (int r = 0; r < 16; ++r){
    int e = r*256 + tid;
    int cl = e & 15, hw = e >> 4;
    int h = hw >> 5, w = hw & 31;
    xt[((size_t)(b*HGT + h0+h)*WID + (w0+w))*C_DIM + cb + cl] = rows_s[hw*17 + cl];
  }
}

// ---------------- LN row stats ----------------
__global__ __launch_bounds__(256) void ln_stats_kernel(const float* __restrict__ src, float* __restrict__ stats){
  int wave = threadIdx.x >> 6; int lane = threadIdx.x & 63;
  size_t p = (size_t)blockIdx.x*4 + wave;
  const float* s = src + p*C_DIM;
  float v0 = s[lane], v1 = s[lane+64];
  float sum = v0 + v1;
  #pragma unroll
  for (int o=1; o<64; o<<=1) sum += __shfl_xor(sum, o, 64);
  float m = sum * (1.0f/128.0f);
  float d0 = v0-m, d1 = v1-m;
  float vs = d0*d0 + d1*d1;
  #pragma unroll
  for (int o=1; o<64; o<<=1) vs += __shfl_xor(vs, o, 64);
  float rstd = rsqrtf(vs*(1.0f/128.0f) + 1e-5f);
  if (lane==0){ stats[2*p] = m; stats[2*p+1] = rstd; }
}

// ---------------- unified MFMA GEMM ----------------
// dst[p, n] = act(A[p,:] @ W^T[n,:] + bias[n]) (+dst)
// WT: bf16 [N][K]. A: fp32 (opt LNA) or bf16. dst: fp32 or bf16. NT 64-col tiles per block.
template<int ACT, bool ADD, bool LNA, bool ABF, bool OBF, bool SCQ, int NT>
__global__ __launch_bounds__(256) void gemm2(const void* __restrict__ A1v,
                            const unsigned short* __restrict__ WT, const float* __restrict__ bias,
                            void* __restrict__ dstv, int K, int N, int lda,
                            const float* __restrict__ stats, const float* __restrict__ lng,
                            const float* __restrict__ lnb, int prow0, int pmax){
  __shared__ __align__(16) unsigned short As[64*40];
  __shared__ __align__(16) unsigned short Bs[NT][64*40];
  int p0 = blockIdx.y*64, n00 = blockIdx.x*(64*NT);
  int tid = threadIdx.x;
  int wave = tid >> 6, lane = tid & 63;
  int wr = (wave>>1)*32, wc = (wave&1)*32;
  f32x4 acc[NT][4];
  #pragma unroll
  for (int nt=0; nt<NT; ++nt)
    #pragma unroll
    for (int q=0; q<4; ++q) acc[nt][q] = (f32x4){};
  int am = tid >> 2, ak = (tid & 3)*8;
  int brow = tid >> 2, bkk = (tid & 3)*8;
  for (int k0 = 0; k0 < K; k0 += 32){
    if constexpr (ABF){
      const unsigned short* A1u = (const unsigned short*)A1v;
      bf16x8 av = *(const bf16x8*)(A1u + (size_t)(p0+am)*lda + k0 + ak);
      st8u(&As[am*40 + ak], av);
    } else {
      int gp = p0 + am;
      float s0 = 0.f, s1 = 0.f;
      if (LNA){
        gp += prow0;
        gp = gp < 0 ? 0 : (gp > pmax ? pmax : gp);
        s0 = stats[2*gp]; s1 = stats[2*gp+1];
      }
      const float* src = (const float*)A1v + (size_t)gp*lda + k0 + ak;
      float4 aa = *(const float4*)src;
      float4 ab = *(const float4*)(src+4);
      float v[8] = {aa.x,aa.y,aa.z,aa.w,ab.x,ab.y,ab.z,ab.w};
      unsigned short* dp = &As[am*40 + ak];
      #pragma unroll
      for (int j=0;j<8;j++){
        float f = v[j];
        if (LNA) f = (f - s0)*s1*lng[k0+ak+j] + lnb[k0+ak+j];
        dp[j] = f2bf(f);
      }
    }
    #pragma unroll
    for (int nt=0; nt<NT; ++nt){
      bf16x8 wv = *(const bf16x8*)(WT + (size_t)(n00 + nt*64 + brow)*K + k0 + bkk);
      st8u(&Bs[nt][brow*40 + bkk], wv);
    }
    __syncthreads();
    int fm = lane & 15, kg = (lane>>4)*8;
    bf16x8 a0 = *(const bf16x8*)&As[(wr+fm)*40 + kg];
    bf16x8 a1 = *(const bf16x8*)&As[(wr+16+fm)*40 + kg];
    #pragma unroll
    for (int nt=0; nt<NT; ++nt){
      bf16x8 b0 = *(const bf16x8*)&Bs[nt][(wc+fm)*40 + kg];
      bf16x8 b1 = *(const bf16x8*)&Bs[nt][(wc+16+fm)*40 + kg];
      acc[nt][0] = __builtin_amdgcn_mfma_f32_16x16x32_bf16(a0, b0, acc[nt][0], 0,0,0);
      acc[nt][1] = __builtin_amdgcn_mfma_f32_16x16x32_bf16(a0, b1, acc[nt][1], 0,0,0);
      acc[nt][2] = __builtin_amdgcn_mfma_f32_16x16x32_bf16(a1, b0, acc[nt][2], 0,0,0);
      acc[nt][3] = __builtin_amdgcn_mfma_f32_16x16x32_bf16(a1, b1, acc[nt][3], 0,0,0);
    }
    __syncthreads();
  }
  int cn = lane & 15, rq = (lane>>4)*4;
  #pragma unroll
  for (int nt=0; nt<NT; ++nt){
    #pragma unroll
    for (int mi=0; mi<2; ++mi){
      #pragma unroll
      for (int ni=0; ni<2; ++ni){
        f32x4 a = acc[nt][mi*2+ni];
        int n = n00 + nt*64 + wc + ni*16 + cn;
        float bsv = bias[n];
        #pragma unroll
        for (int r=0; r<4; ++r){
          size_t row = (size_t)p0 + wr + mi*16 + rq + r;
          float v = a[r] + bsv;
          if (ACT==1) v = (v>=0.f) ? v : 0.01f*v;
          if (ACT==2) v = gelu_f(v);
          if (SCQ && n < 128) v *= 0.17677669529663688f;
          if constexpr (OBF){
            ((unsigned short*)dstv)[row*(size_t)N + n] = f2bf(v);
          } else {
            float* dst = (float*)dstv;
            if (ADD) v += dst[row*(size_t)N + n];
            dst[row*(size_t)N + n] = v;
          }
        }
      }
    }
  }
}

// ---------------- DFT-as-GEMM (bf16 tables / bf16 spectra) ----------------
// MODE 0: rfft-W  per (b,h):  A=MW[256][192] bf16, W=XTb fp32 rows w -> FR/FI bf16
// MODE 1: fft-H   per (b,kl): A=MHF[384][384], W=FR/FI bf16 rows h -> FF0[kl] bf16
// MODE 2: ifft-H  per (b,kl): A=MHI[384][384], W=FF0[kl] bf16 rows hf -> G[h][k][256] bf16
// MODE 3: irfft-W per (b,h):  A=MWI[192][224], W=G[h] bf16 rows k -> += XTb fp32
template<int MODE>
__global__ __launch_bounds__(256) void dft_gemm(const unsigned short* __restrict__ Atab,
                            const void* __restrict__ W1v, const void* __restrict__ W2v,
                            void* __restrict__ D1v, void* __restrict__ D2v, int k0){
  constexpr int K      = (MODE==0)?192 : (MODE==3)?224 : 384;
  constexpr int MT     = (MODE==0)?4 : (MODE==3)?3 : 6;
  constexpr int MVALID = (MODE==0)?194 : (MODE==3)?192 : 384;
  __shared__ __align__(16) unsigned short As[64*40];
  __shared__ __align__(16) unsigned short Bs[64*40];
  int slab = blockIdx.y / MT;
  int p0 = (blockIdx.y % MT)*64, n0 = blockIdx.x*64;
  int tid = threadIdx.x;
  int wave = tid >> 6, lane = tid & 63;
  int wr = (wave>>1)*32, wc = (wave&1)*32;
  f32x4 acc00 = {}, acc01 = {}, acc10 = {}, acc11 = {};
  int am = tid >> 2, ak = (tid & 3)*8;
  int bk = tid >> 3, bn = (tid & 7)*8;
  for (int kk0 = 0; kk0 < K; kk0 += 32){
    {
      bf16x8 av = *(const bf16x8*)(Atab + (size_t)(p0+am)*K + kk0 + ak);
      st8u(&As[am*40 + ak], av);
    }
    {
      int r = kk0 + bk;
      if (MODE==0){
        const float* src = (const float*)W1v + (size_t)slab*24576 + (size_t)r*128 + n0 + bn;
        float4 wa = *(const float4*)src;
        float4 wb = *(const float4*)(src+4);
        float v[8] = {wa.x,wa.y,wa.z,wa.w,wb.x,wb.y,wb.z,wb.w};
        #pragma unroll
        for (int j=0;j<8;j++) Bs[(bn+j)*40 + bk] = f2bf(v[j]);
      } else {
        const unsigned short* src;
        if (MODE==1) src = (r<192) ? (const unsigned short*)W1v + (size_t)(k0+slab)*128 + (size_t)r*12416
                                   : (const unsigned short*)W2v + (size_t)(k0+slab)*128 + (size_t)(r-192)*12416;
        else if (MODE==2) src = (r<192) ? (const unsigned short*)W1v + (size_t)slab*49152 + (size_t)r*256
                                        : (const unsigned short*)W2v + (size_t)slab*49152 + (size_t)(r-192)*256;
        else src = (r<112) ? (const unsigned short*)W1v + (size_t)slab*24832 + (size_t)r*256
                           : (const unsigned short*)W2v + (size_t)slab*24832 + (size_t)(r-112)*256;
        src += n0 + bn;
        bf16x8 wv = *(const bf16x8*)src;
        #pragma unroll
        for (int j=0;j<8;j++) Bs[(bn+j)*40 + bk] = (unsigned short)wv[j];
      }
    }
    __syncthreads();
    int fm = lane & 15, kg = (lane>>4)*8;
    bf16x8 a0 = *(const bf16x8*)&As[(wr+fm)*40 + kg];
    bf16x8 a1 = *(const bf16x8*)&As[(wr+16+fm)*40 + kg];
    bf16x8 b0 = *(const bf16x8*)&Bs[(wc+fm)*40 + kg];
    bf16x8 b1 = *(const bf16x8*)&Bs[(wc+16+fm)*40 + kg];
    acc00 = __builtin_amdgcn_mfma_f32_16x16x32_bf16(a0, b0, acc00, 0,0,0);
    acc01 = __builtin_amdgcn_mfma_f32_16x16x32_bf16(a0, b1, acc01, 0,0,0);
    acc10 = __builtin_amdgcn_mfma_f32_16x16x32_bf16(a1, b0, acc10, 0,0,0);
    acc11 = __builtin_amdgcn_mfma_f32_16x16x32_bf16(a1, b1, acc11, 0,0,0);
    __syncthreads();
  }
  int cn = lane & 15, rq = (lane>>4)*4;
  #pragma unroll
  for (int mi=0; mi<2; ++mi){
    #pragma unroll
    for (int ni=0; ni<2; ++ni){
      f32x4 a = (mi==0) ? (ni==0?acc00:acc01) : (ni==0?acc10:acc11);
      int n = n0 + wc + ni*16 + cn;
      #pragma unroll
      for (int r=0; r<4; ++r){
        int p = p0 + wr + mi*16 + rq + r;
        if (p >= MVALID) continue;
        float v = a[r];
        if (MODE==0){
          unsigned short* D1 = (unsigned short*)D1v;
          unsigned short* D2 = (unsigned short*)D2v;
          if (p < 97) D1[(size_t)slab*12416 + (size_t)p*128 + n] = f2bf(v);
          else        D2[(size_t)slab*12416 + (size_t)(p-97)*128 + n] = f2bf(v);
        } else if (MODE==1){
          unsigned short* base = (unsigned short*)D1v + (size_t)slab*49152;
          if (p < 192) base[(size_t)p*256 + n] = f2bf(v);
          else         base[(size_t)(p-192)*256 + 128 + n] = f2bf(v);
        } else if (MODE==2){
          unsigned short* D1 = (unsigned short*)D1v;
          int kg2 = k0 + slab;
          if (p < 192) D1[((size_t)p*97 + kg2)*256 + n] = f2bf(v);
          else         D1[((size_t)(p-192)*97 + kg2)*256 + 128 + n] = f2bf(v);
        } else {
          ((float*)D1v)[(size_t)slab*24576 + (size_t)p*128 + n] += v;
        }
      }
    }
  }
}

// ---------------- MFMA window attention (bf16 QKV in, bf16 OUT) ----------------
__global__ __launch_bounds__(256) void attn_mfma(
    const unsigned short* __restrict__ QKV, const float* __restrict__ biasT,
    unsigned short* __restrict__ OUTc, int win0, int prow0){
  __shared__ __align__(16) unsigned short P_s[4][64][72];
  __shared__ __align__(16) unsigned short Vt_s[4][32][72];
  int win = win0 + blockIdx.x;
  int b = win/576, rem = win%576, whi = rem/12, wwi = rem%12;
  int tid = threadIdx.x;
  int wave = tid>>6, lane = tid&63, head = wave;
  int rowbase0 = (b*HGT + whi*4)*WID + wwi*16 - prow0;
  int fm = lane & 15, kg = (lane>>4)*8;
  bf16x8 qf[4], kf[4];
  #pragma unroll
  for (int t4=0; t4<4; ++t4){
    const unsigned short* rp = QKV + (size_t)(rowbase0 + t4*WID + fm)*384 + head*32 + kg;
    qf[t4] = *(const bf16x8*)rp;
    kf[t4] = *(const bf16x8*)(rp + 128);
  }
  {
    int lv = rowbase0 + (lane>>4)*WID + (lane&15);
    const unsigned short* vp = QKV + (size_t)lv*384 + 256 + head*32;
    #pragma unroll
    for (int d4=0; d4<8; ++d4){
      bf16x8 dummy;
      unsigned int w0 = *(const unsigned int*)(vp + d4*4);
      unsigned int w1 = *(const unsigned int*)(vp + d4*4 + 2);
      Vt_s[wave][d4*4+0][lane] = (unsigned short)(w0 & 0xFFFF);
      Vt_s[wave][d4*4+1][lane] = (unsigned short)(w0 >> 16);
      Vt_s[wave][d4*4+2][lane] = (unsigned short)(w1 & 0xFFFF);
      Vt_s[wave][d4*4+3][lane] = (unsigned short)(w1 >> 16);
      (void)dummy;
    }
  }
  f32x4 s[4][4];
  #pragma unroll
  for (int ni=0; ni<4; ++ni)
    #pragma unroll
    for (int mj=0; mj<4; ++mj){
      f32x4 z = {};
      s[ni][mj] = __builtin_amdgcn_mfma_f32_16x16x32_bf16(qf[ni], kf[mj], z, 0,0,0);
    }
  const float* bp = biasT + head*4096;
  #pragma unroll
  for (int ni=0; ni<4; ++ni){
    int nbase = ni*16 + (lane>>4)*4;
    #pragma unroll
    for (int mj=0; mj<4; ++mj){
      int m = mj*16 + fm;
      #pragma unroll
      for (int r=0;r<4;r++)
        s[ni][mj][r] += bp[(nbase+r)*64 + m];
    }
  }
  float rs[4][4];
  #pragma unroll
  for (int ni=0; ni<4; ++ni){
    #pragma unroll
    for (int r=0;r<4;r++){
      float t = fmaxf(fmaxf(s[ni][0][r], s[ni][1][r]), fmaxf(s[ni][2][r], s[ni][3][r]));
      #pragma unroll
      for (int o=1;o<16;o<<=1) t = fmaxf(t, __shfl_xor(t, o, 64));
      float sum = 0.f;
      #pragma unroll
      for (int mj=0; mj<4; ++mj){
        float e = expf(s[ni][mj][r] - t);
        s[ni][mj][r] = e;
        sum += e;
      }
      #pragma unroll
      for (int o=1;o<16;o<<=1) sum += __shfl_xor(sum, o, 64);
      rs[ni][r] = sum;
    }
  }
  #pragma unroll
  for (int ni=0; ni<4; ++ni){
    int nbase = ni*16 + (lane>>4)*4;
    #pragma unroll
    for (int mj=0; mj<4; ++mj){
      int m = mj*16 + fm;
      #pragma unroll
      for (int r=0;r<4;r++)
        P_s[wave][nbase+r][m] = f2bf(s[ni][mj][r]);
    }
  }
  f32x4 o2[4][2] = {};
  #pragma unroll
  for (int ks=0; ks<2; ++ks){
    bf16x8 vb0 = *(const bf16x8*)&Vt_s[wave][fm][ks*32+kg];
    bf16x8 vb1 = *(const bf16x8*)&Vt_s[wave][16+fm][ks*32+kg];
    #pragma unroll
    for (int ni=0; ni<4; ++ni){
      bf16x8 pa = *(const bf16x8*)&P_s[wave][ni*16+fm][ks*32+kg];
      o2[ni][0] = __builtin_amdgcn_mfma_f32_16x16x32_bf16(pa, vb0, o2[ni][0], 0,0,0);
      o2[ni][1] = __builtin_amdgcn_mfma_f32_16x16x32_bf16(pa, vb1, o2[ni][1], 0,0,0);
    }
  }
  #pragma unroll
  for (int ni=0; ni<4; ++ni){
    #pragma unroll
    for (int r=0;r<4;r++){
      int l = rowbase0 + ni*WID + (lane>>4)*4 + r;
      float inv = 1.0f / rs[ni][r];
      unsigned short* op = OUTc + (size_t)l*128 + head*32;
      op[fm]    = f2bf(o2[ni][0][r]*inv);
      op[16+fm] = f2bf(o2[ni][1][r]*inv);
    }
  }
}

// ---------------- LeFF dwconv strip (bf16 in/out) ----------------
__global__ __launch_bounds__(256) void dwconv_strip(const unsigned short* __restrict__ SB1,
                                                    const float* __restrict__ dw,
                                                    const float* __restrict__ db,
                                                    unsigned short* __restrict__ SB2,
                                                    int r0){
  int id = blockIdx.x*256 + threadIdx.x;
  int ch = id & 511; int t = id >> 9; int w = t % 192; int hl = t / 192;
  int h = r0 + hl;
  float acc = db[ch];
  #pragma unroll
  for (int ky=0; ky<3; ky++){
    int hh = h+ky-1;
    if (hh<0 || hh>=HGT) continue;
    int br = hl + ky;
    #pragma unroll
    for (int kx=0; kx<3; kx++){
      int ww = w+kx-1;
      if (ww<0 || ww>=WID) continue;
      acc += dw[ch*9+ky*3+kx]*bf2f(SB1[((size_t)br*WID + ww)*512 + ch]);
    }
  }
  SB2[id] = f2bf(gelu_f(acc));
}

// ---------------- per-batch BHWC -> BCHW transpose ----------------
__global__ __launch_bounds__(256) void transpose_b_kernel(const float* __restrict__ src, float* __restrict__ dst){
  __shared__ float tile[128*65];
  int w0 = blockIdx.x*64, h = blockIdx.y;
  int tid = threadIdx.x;
  for (int r=0; r<32; r++){
    int e = tid + 256*r; int c = e & 127, wl = e >> 7;
    tile[c*65 + wl] = src[((size_t)h*WID + w0 + wl)*C_DIM + c];
  }
  __syncthreads();
  for (int r=0; r<32; r++){
    int e = tid + 256*r; int wl = e & 63, c = e >> 6;
    dst[((size_t)c*HGT + h)*WID + w0 + wl] = tile[c*65 + wl];
  }
}

// ---------------- host ----------------
extern "C" void kernel_launch(void* const* d_in, const int* in_sizes, int n_in,
                              void* d_out, int out_size, void* d_ws, size_t ws_size,
                              hipStream_t stream) {
  const float* x      = (const float*)d_in[0];
  const float* pos_w  = (const float*)d_in[1];
  const float* pos_b  = (const float*)d_in[2];
  const float* ln1_g  = (const float*)d_in[3];
  const float* ln1_b  = (const float*)d_in[4];
  const float* q_w    = (const float*)d_in[5];
  const float* q_b    = (const float*)d_in[6];
  const float* kv_w   = (const float*)d_in[7];
  const float* kv_b   = (const float*)d_in[8];
  const float* rpb    = (const float*)d_in[9];
  const float* proj_w = (const float*)d_in[10];
  const float* proj_b = (const float*)d_in[11];
  const float* fft1_w = (const float*)d_in[12];
  const float* fft1_b = (const float*)d_in[13];
  const float* fft2_w = (const float*)d_in[14];
  const float* fft2_b = (const float*)d_in[15];
  const float* ln2_g  = (const float*)d_in[16];
  const float* ln2_b  = (const float*)d_in[17];
  const float* l1_w   = (const float*)d_in[18];
  const float* l1_b   = (const float*)d_in[19];
  const float* dw_w   = (const float*)d_in[20];
  const float* dw_b   = (const float*)d_in[21];
  const float* l2_w   = (const float*)d_in[22];
  const float* l2_b   = (const float*)d_in[23];

  const size_t S   = (size_t)NB*HGT*WID*C_DIM;   // 18,874,368
  const size_t Sb  = S/NB;                       //  4,718,592
  const size_t SZb = (size_t)HGT*WFD*C_DIM;      //  2,383,872 (ushorts per spectrum half)
  const size_t GSZ = (size_t)HGT*WFD*256;        //  4,767,744 (ushorts)
  const int    P   = (int)(NB*HGT*WID);          // 147,456

  float* XT = (float*)d_out;

  float* ws    = (float*)d_ws;
  float* TAB   = ws;
  float* STATS = ws + TAB_SZ;
  float* POOL  = ws + TAB_SZ + 2*(size_t)P;
  size_t head  = TAB_SZ + 2*(size_t)P;
  size_t pool  = (ws_size/4 > head) ? (ws_size/4 - head) : 0;

  const float* biasT = TAB + T_BIAS;
  const float* QKVB  = TAB + T_QKVB;
  const unsigned short* UT = (const unsigned short*)(TAB + TF_SZ);
  const unsigned short* MW  = UT + UT_MW;
  const unsigned short* MHF = UT + UT_MHF;
  const unsigned short* MHI = UT + UT_MHI;
  const unsigned short* MWI = UT + UT_MWI;
  const unsigned short* QKVW  = UT + UT_QKVW;
  const unsigned short* PROJW = UT + UT_PROJW;
  const unsigned short* FFT1W = UT + UT_FFT1W;
  const unsigned short* FFT2W = UT + UT_FFT2W;
  const unsigned short* L1W   = UT + UT_L1W;
  const unsigned short* L2W   = UT + UT_L2W;

  build_tables<<<2858, 256, 0, stream>>>(TAB, rpb, q_b, kv_b, q_w, kv_w, proj_w,
                                         fft1_w, fft2_w, l1_w, l2_w);
  posconv3_kernel<<<dim3(6,24,32), 256, 0, stream>>>(x, pos_w, pos_b, XT);

  // ---- attention: LN1 stats -> per-chunk {qkv gemm(NT=6), attn, proj gemm} ----
  ln_stats_kernel<<<P/4, 256, 0, stream>>>(XT, STATS);
  {
    // chunk needs R*256 floats (QKV R*384 u16 + OUT R*128 u16)
    int winChunk = (int)((pool/(64*256)/12)*12);
    if (winChunk < 12) winChunk = 12;
    if (winChunk > 2304) winChunk = 2304;
    for (int w0 = 0; w0 < 2304; w0 += winChunk){
      int nw = (2304 - w0 < winChunk) ? (2304 - w0) : winChunk;
      int R = nw*64, prow0 = w0*64;
      unsigned short* QKVc = (unsigned short*)POOL;
      unsigned short* OUTc = QKVc + (size_t)R*384;
      gemm2<0,false,true,false,true,true,6><<<dim3(1, R/64), 256, 0, stream>>>(
          XT, QKVW, QKVB, QKVc, 128, 384, 128, STATS, ln1_g, ln1_b, prow0, P-1);
      attn_mfma<<<nw, 256, 0, stream>>>(QKVc, biasT, OUTc, w0, prow0);
      gemm2<0,true,false,true,false,false,2><<<dim3(1, R/64), 256, 0, stream>>>(
          OUTc, PROJW, proj_b, XT + (size_t)prow0*C_DIM,
          128, 128, 128, nullptr, nullptr, nullptr, 0, 0);
    }
  }

  // ---- FFT residual branch: all-MFMA, bf16 spectra, chunked over k ----
  {
    unsigned short* FRu = (unsigned short*)POOL;
    unsigned short* FIu = FRu + SZb;
    unsigned short* Gu  = FIu + SZb;
    size_t fixed = SZb + GSZ/2;                  // floats used by FR+FI+G
    int CK = 1;
    if (pool > fixed + 49152) CK = (int)((pool - fixed)/49152);
    if (CK < 1) CK = 1;
    if (CK > WFD) CK = WFD;
    unsigned short* FF0u = (unsigned short*)(POOL + fixed);
    unsigned short* FF1u = FF0u + (size_t)CK*49152;
    for (int b = 0; b < NB; ++b){
      float* XTb = XT + (size_t)b*Sb;
      dft_gemm<0><<<dim3(2, 192*4), 256, 0, stream>>>(MW, XTb, nullptr, FRu, FIu, 0);
      for (int k0 = 0; k0 < WFD; k0 += CK){
        int ck = (WFD - k0 < CK) ? (WFD - k0) : CK;
        int rows = ck*192;
        dft_gemm<1><<<dim3(2, ck*6), 256, 0, stream>>>(MHF, FRu, FIu, FF0u, nullptr, k0);
        gemm2<1,false,false,true,true,false,4><<<dim3(1, rows/64), 256, 0, stream>>>(
            FF0u, FFT1W, fft1_b, FF1u, 256, 256, 256, nullptr, nullptr, nullptr, 0, 0);
        gemm2<0,false,false,true,true,false,4><<<dim3(1, rows/64), 256, 0, stream>>>(
            FF1u, FFT2W, fft2_b, FF0u, 256, 256, 256, nullptr, nullptr, nullptr, 0, 0);
        dft_gemm<2><<<dim3(2, ck*6), 256, 0, stream>>>(MHI, FF0u, FF0u+128, Gu, nullptr, k0);
      }
      dft_gemm<3><<<dim3(2, 192*3), 256, 0, stream>>>(MWI, Gu, Gu+128, XTb, nullptr, 0);
    }
  }

  // ---- LN2 stats ----
  ln_stats_kernel<<<P/4, 256, 0, stream>>>(XT, STATS);

  // ---- LeFF: strip-mined l1 gemm(NT=4) -> dwconv+gelu -> l2 gemm(NT=2, +residual) ----
  {
    int SH = 96;
    while ((size_t)(3*SH+4)*49152 > pool && SH > 24) SH >>= 1;
    const size_t SB1SZ = (size_t)(SH+2)*98304;   // ushorts
    unsigned short* SB1u[2] = { (unsigned short*)POOL, (unsigned short*)POOL + SB1SZ };
    unsigned short* SB2u = (unsigned short*)POOL + 2*SB1SZ;
    int nStrips = HGT/SH;
    for (int b = 0; b < NB; ++b){
      auto launch_g = [&](int s){
        int r0 = s*SH;
        int prow0 = (b*HGT + r0 - 1)*WID;
        gemm2<2,false,true,false,true,false,4><<<dim3(2, (SH+2)*3), 256, 0, stream>>>(
            XT, L1W, l1_b, SB1u[s&1], 128, 512, 128,
            STATS, ln2_g, ln2_b, prow0, P-1);
      };
      launch_g(0);
      for (int s = 0; s < nStrips; ++s){
        if (s+1 < nStrips) launch_g(s+1);
        int r0 = s*SH;
        dwconv_strip<<<SH*384, 256, 0, stream>>>(SB1u[s&1], dw_w, dw_b, SB2u, r0);
        gemm2<0,true,false,true,false,false,2><<<dim3(1, SH*3), 256, 0, stream>>>(
            SB2u, L2W, l2_b, XT + ((size_t)(b*HGT + r0)*WID)*C_DIM,
            512, 128, 512, nullptr, nullptr, nullptr, 0, 0);
      }
    }
  }

  // ---- final transpose per batch: XT(BHWC, in d_out) -> POOL(BCHW) -> copy back ----
  for (int b = 0; b < NB; ++b){
    transpose_b_kernel<<<dim3(3,192), 256, 0, stream>>>(XT + (size_t)b*Sb, POOL);
    hipMemcpyAsync((float*)d_out + (size_t)b*Sb, POOL, Sb*sizeof(float),
                   hipMemcpyDeviceToDevice, stream);
  }
}

// Round 12
// 1622.135 us; speedup vs baseline: 6.4111x; 1.0398x over previous
//
#include <hip/hip_runtime.h>
#include <math.h>

// ---------------- constants ----------------
#define C_DIM 128
#define HGT 192
#define WID 192
#define NB 4
#define WFD 97   // 192/2+1

// TAB float region
#define T_BIAS  0                // 4*64*64 fp32
#define T_QKVB  16384            // 384 fp32 (q_b | kv_b)
#define TF_SZ   16896
// TAB bf16 region (ushort offsets, base = TAB + TF_SZ floats)
#define UT_MW    0               // [256][192]
#define UT_MHF   49152           // [384][384]
#define UT_MHI   196608          // [384][384]
#define UT_MWI   344064          // [192][224]
#define UT_QKVW  387072          // [384][128]
#define UT_PROJW 436224          // [128][128]
#define UT_FFT1W 452608          // [256][256]
#define UT_FFT2W 518144          // [256][256]
#define UT_L1W   583680          // [512][128]
#define UT_L2W   649216          // [128][512]
#define UT_TOT   714752
#define TAB_SZ   374272          // floats: TF_SZ + UT_TOT/2

typedef __attribute__((ext_vector_type(8))) short bf16x8;
typedef __attribute__((ext_vector_type(4))) float f32x4;

__device__ __forceinline__ float gelu_f(float v){
  return 0.5f*v*(1.0f + erff(v*0.70710678118654752440f));
}
__device__ __forceinline__ unsigned short f2bf(float f){
  unsigned int u = __float_as_uint(f);
  unsigned int r = (u + 0x7FFFu + ((u>>16)&1u)) >> 16;
  return (unsigned short)r;
}
__device__ __forceinline__ float bf2f(unsigned short u){
  unsigned int x = ((unsigned int)u)<<16;
  return __uint_as_float(x);
}
__device__ __forceinline__ void st8u(unsigned short* d, bf16x8 v){
  unsigned int* wp = (unsigned int*)&v;
  unsigned int* dp = (unsigned int*)d;
  dp[0]=wp[0]; dp[1]=wp[1]; dp[2]=wp[2]; dp[3]=wp[3];
}

// ---------------- table build (exact int mod-192 + float trig) ----------------
__global__ __launch_bounds__(256) void build_tables(float* __restrict__ tab,
        const float* __restrict__ rpb, const float* __restrict__ q_b, const float* __restrict__ kv_b,
        const float* __restrict__ q_w, const float* __restrict__ kv_w, const float* __restrict__ proj_w,
        const float* __restrict__ fft1_w, const float* __restrict__ fft2_w,
        const float* __restrict__ l1_w, const float* __restrict__ l2_w){
  int idx = blockIdx.x*256 + threadIdx.x;
  const float STEP = (float)(6.283185307179586476925286766559/192.0);
  if (idx < 16384){ // attn bias fp32: [head][n][m]
    int head = idx>>12, n = (idx>>6)&63, m = idx&63;
    int dh = n/16 - m/16 + 3;
    int dw = (n&15) - (m&15) + 15;
    tab[T_BIAS+idx] = rpb[(dh*31+dw)*4 + head];
    return;
  }
  idx -= 16384;
  if (idx < 384){ // QKV bias concat fp32
    tab[T_QKVB+idx] = (idx < 128) ? q_b[idx] : kv_b[idx-128];
    return;
  }
  idx -= 384;
  unsigned short* ut = (unsigned short*)(tab + TF_SZ);
  if (idx < 49152){ // MW [256][192]
    int r = idx/192, w = idx%192;
    float v = 0.f;
    if (r < 97){ int a = (r*w)%192; v = cosf(a*STEP); }
    else if (r < 194){ int a = ((r-97)*w)%192; v = -sinf(a*STEP); }
    ut[UT_MW+idx] = f2bf(v);
    return;
  }
  idx -= 49152;
  if (idx < 147456){ // MHF [384][384]
    int r = idx/384, j = idx%384;
    int hf = (r < 192) ? r : r-192;
    int h  = (j < 192) ? j : j-192;
    int a = (hf*h)%192;
    float c = cosf(a*STEP), s = sinf(a*STEP);
    float v;
    if (r < 192) v = (j < 192) ? c : s;
    else         v = (j < 192) ? -s : c;
    ut[UT_MHF+idx] = f2bf(v);
    return;
  }
  idx -= 147456;
  if (idx < 147456){ // MHI [384][384]
    int r = idx/384, j = idx%384;
    int h  = (r < 192) ? r : r-192;
    int hf = (j < 192) ? j : j-192;
    int a = (h*hf)%192;
    float c = cosf(a*STEP), s = sinf(a*STEP);
    float v;
    if (r < 192) v = (j < 192) ? c : -s;
    else         v = (j < 192) ? s : c;
    ut[UT_MHI+idx] = f2bf(v);
    return;
  }
  idx -= 147456;
  if (idx < 43008){ // MWI [192][224]
    int w = idx/224, j = idx%224;
    float v = 0.f;
    if (j < 97){
      int a = (j*w)%192;
      float sc = ((j==0 || j==96) ? 1.f : 2.f) / 36864.f;
      v = sc*cosf(a*STEP);
    } else if (j >= 112 && j < 209){
      int k = j-112;
      int a = (k*w)%192;
      float sc = ((k==0 || k==96) ? 1.f : 2.f) / 36864.f;
      v = -sc*sinf(a*STEP);
    }
    ut[UT_MWI+idx] = f2bf(v);
    return;
  }
  idx -= 43008;
  if (idx < 49152){ // QKVW [384][128]
    int n = idx/128, k = idx%128;
    float v = (n < 128) ? q_w[(size_t)k*128 + n] : kv_w[(size_t)k*256 + (n-128)];
    ut[UT_QKVW+idx] = f2bf(v);
    return;
  }
  idx -= 49152;
  if (idx < 16384){ // PROJW [128][128]
    int n = idx/128, k = idx%128;
    ut[UT_PROJW+idx] = f2bf(proj_w[(size_t)k*128 + n]);
    return;
  }
  idx -= 16384;
  if (idx < 65536){ // FFT1W [256][256]
    int n = idx/256, k = idx%256;
    ut[UT_FFT1W+idx] = f2bf(fft1_w[(size_t)k*256 + n]);
    return;
  }
  idx -= 65536;
  if (idx < 65536){ // FFT2W [256][256]
    int n = idx/256, k = idx%256;
    ut[UT_FFT2W+idx] = f2bf(fft2_w[(size_t)k*256 + n]);
    return;
  }
  idx -= 65536;
  if (idx < 65536){ // L1W [512][128]
    int n = idx/128, k = idx%128;
    ut[UT_L1W+idx] = f2bf(l1_w[(size_t)k*512 + n]);
    return;
  }
  idx -= 65536;
  if (idx < 65536){ // L2W [128][512]
    int n = idx/512, k = idx%512;
    ut[UT_L2W+idx] = f2bf(l2_w[(size_t)k*128 + n]);
  }
}

// ---------------- pos depthwise conv: 8h x 32w x 16c ----------------
__global__ __launch_bounds__(256) void posconv3_kernel(const float* __restrict__ x, const float* __restrict__ pw,
                               const float* __restrict__ pb, float* __restrict__ xt){
  __shared__ float rows_s[16*340];
  int w0 = blockIdx.x*32, h0 = blockIdx.y*8;
  int b = blockIdx.z >> 3, cb = (blockIdx.z & 7)*16;
  int tid = threadIdx.x;
  int hl = tid >> 5, wl = tid & 31;
  for (int e = tid; e < 16*340; e += 256){
    int c = e / 340; int rem = e - c*340;
    int r = rem / 34; int wc = rem - r*34;
    int gh = h0 - 1 + r, gw = w0 - 1 + wc;
    float v = 0.f;
    if (gh >= 0 && gh < HGT && gw >= 0 && gw < WID)
      v = x[((size_t)(b*C_DIM + cb + c))*(HGT*WID) + gh*WID + gw];
    rows_s[e] = v;
  }
  __syncthreads();
  float outr[16];
  #pragma unroll
  for (int c = 0; c < 16; ++c){
    const float* rs = &rows_s[c*340];
    float wreg[9];
    #pragma unroll
    for (int t9 = 0; t9 < 9; ++t9) wreg[t9] = pw[(cb+c)*27 + 9 + t9];
    float bias = pb[cb+c];
    float acc = rs[(hl+1)*34 + wl+1] + bias;
    #pragma unroll
    for (int ky = 0; ky < 3; ++ky)
      #pragma unroll
      for (int kx = 0; kx < 3; ++kx)
        acc += wreg[ky*3+kx]*rs[(hl+ky)*34 + wl+kx];
    outr[c] = acc;
  }
  __syncthreads();
  {
    int px = hl*32 + wl;
    #pragma unroll
    for (int c = 0; c < 16; ++c) rows_s[px*17 + c] = outr[c];
  }
  __syncthreads();
  for (int r = 0; r < 16; ++r){
    int e = r*256 + tid;
    int cl = e & 15, hw = e >> 4;
    int h = hw >> 5, w = hw & 31;
    xt[((size_t)(b*HGT + h0+h)*WID + (w0+w))*C_DIM + cb + cl] = rows_s[hw*17 + cl];
  }
}

// ---------------- LN row stats ----------------
__global__ __launch_bounds__(256) void ln_stats_kernel(const float* __restrict__ src, float* __restrict__ stats){
  int wave = threadIdx.x >> 6; int lane = threadIdx.x & 63;
  size_t p = (size_t)blockIdx.x*4 + wave;
  const float* s = src + p*C_DIM;
  float v0 = s[lane], v1 = s[lane+64];
  float sum = v0 + v1;
  #pragma unroll
  for (int o=1; o<64; o<<=1) sum += __shfl_xor(sum, o, 64);
  float m = sum * (1.0f/128.0f);
  float d0 = v0-m, d1 = v1-m;
  float vs = d0*d0 + d1*d1;
  #pragma unroll
  for (int o=1; o<64; o<<=1) vs += __shfl_xor(vs, o, 64);
  float rstd = rsqrtf(vs*(1.0f/128.0f) + 1e-5f);
  if (lane==0){ stats[2*p] = m; stats[2*p+1] = rstd; }
}

// ---------------- unified MFMA GEMM ----------------
template<int ACT, bool ADD, bool LNA, bool ABF, bool OBF, int NT>
__global__ __launch_bounds__(256) void gemm2(const void* __restrict__ A1v,
                            const unsigned short* __restrict__ WT, const float* __restrict__ bias,
                            void* __restrict__ dstv, int K, int N, int lda,
                            const float* __restrict__ stats, const float* __restrict__ lng,
                            const float* __restrict__ lnb, int prow0, int pmax){
  __shared__ __align__(16) unsigned short As[64*40];
  __shared__ __align__(16) unsigned short Bs[NT][64*40];
  int p0 = blockIdx.y*64, n00 = blockIdx.x*(64*NT);
  int tid = threadIdx.x;
  int wave = tid >> 6, lane = tid & 63;
  int wr = (wave>>1)*32, wc = (wave&1)*32;
  f32x4 acc[NT][4];
  #pragma unroll
  for (int nt=0; nt<NT; ++nt)
    #pragma unroll
    for (int q=0; q<4; ++q) acc[nt][q] = (f32x4){};
  int am = tid >> 2, ak = (tid & 3)*8;
  int brow = tid >> 2, bkk = (tid & 3)*8;
  for (int k0 = 0; k0 < K; k0 += 32){
    if constexpr (ABF){
      const unsigned short* A1u = (const unsigned short*)A1v;
      bf16x8 av = *(const bf16x8*)(A1u + (size_t)(p0+am)*lda + k0 + ak);
      st8u(&As[am*40 + ak], av);
    } else {
      int gp = p0 + am;
      float s0 = 0.f, s1 = 0.f;
      if (LNA){
        gp += prow0;
        gp = gp < 0 ? 0 : (gp > pmax ? pmax : gp);
        s0 = stats[2*gp]; s1 = stats[2*gp+1];
      }
      const float* src = (const float*)A1v + (size_t)gp*lda + k0 + ak;
      float4 aa = *(const float4*)src;
      float4 ab = *(const float4*)(src+4);
      float v[8] = {aa.x,aa.y,aa.z,aa.w,ab.x,ab.y,ab.z,ab.w};
      unsigned short* dp = &As[am*40 + ak];
      #pragma unroll
      for (int j=0;j<8;j++){
        float f = v[j];
        if (LNA) f = (f - s0)*s1*lng[k0+ak+j] + lnb[k0+ak+j];
        dp[j] = f2bf(f);
      }
    }
    #pragma unroll
    for (int nt=0; nt<NT; ++nt){
      bf16x8 wv = *(const bf16x8*)(WT + (size_t)(n00 + nt*64 + brow)*K + k0 + bkk);
      st8u(&Bs[nt][brow*40 + bkk], wv);
    }
    __syncthreads();
    int fm = lane & 15, kg = (lane>>4)*8;
    bf16x8 a0 = *(const bf16x8*)&As[(wr+fm)*40 + kg];
    bf16x8 a1 = *(const bf16x8*)&As[(wr+16+fm)*40 + kg];
    #pragma unroll
    for (int nt=0; nt<NT; ++nt){
      bf16x8 b0 = *(const bf16x8*)&Bs[nt][(wc+fm)*40 + kg];
      bf16x8 b1 = *(const bf16x8*)&Bs[nt][(wc+16+fm)*40 + kg];
      acc[nt][0] = __builtin_amdgcn_mfma_f32_16x16x32_bf16(a0, b0, acc[nt][0], 0,0,0);
      acc[nt][1] = __builtin_amdgcn_mfma_f32_16x16x32_bf16(a0, b1, acc[nt][1], 0,0,0);
      acc[nt][2] = __builtin_amdgcn_mfma_f32_16x16x32_bf16(a1, b0, acc[nt][2], 0,0,0);
      acc[nt][3] = __builtin_amdgcn_mfma_f32_16x16x32_bf16(a1, b1, acc[nt][3], 0,0,0);
    }
    __syncthreads();
  }
  int cn = lane & 15, rq = (lane>>4)*4;
  #pragma unroll
  for (int nt=0; nt<NT; ++nt){
    #pragma unroll
    for (int mi=0; mi<2; ++mi){
      #pragma unroll
      for (int ni=0; ni<2; ++ni){
        f32x4 a = acc[nt][mi*2+ni];
        int n = n00 + nt*64 + wc + ni*16 + cn;
        float bsv = bias[n];
        #pragma unroll
        for (int r=0; r<4; ++r){
          size_t row = (size_t)p0 + wr + mi*16 + rq + r;
          float v = a[r] + bsv;
          if (ACT==1) v = (v>=0.f) ? v : 0.01f*v;
          if (ACT==2) v = gelu_f(v);
          if constexpr (OBF){
            ((unsigned short*)dstv)[row*(size_t)N + n] = f2bf(v);
          } else {
            float* dst = (float*)dstv;
            if (ADD) v += dst[row*(size_t)N + n];
            dst[row*(size_t)N + n] = v;
          }
        }
      }
    }
  }
}

// ---------------- DFT-as-GEMM (bf16 tables / bf16 spectra) ----------------
template<int MODE>
__global__ __launch_bounds__(256) void dft_gemm(const unsigned short* __restrict__ Atab,
                            const void* __restrict__ W1v, const void* __restrict__ W2v,
                            void* __restrict__ D1v, void* __restrict__ D2v, int k0){
  constexpr int K      = (MODE==0)?192 : (MODE==3)?224 : 384;
  constexpr int MT     = (MODE==0)?4 : (MODE==3)?3 : 6;
  constexpr int MVALID = (MODE==0)?194 : (MODE==3)?192 : 384;
  __shared__ __align__(16) unsigned short As[64*40];
  __shared__ __align__(16) unsigned short Bs[64*40];
  int slab = blockIdx.y / MT;
  int p0 = (blockIdx.y % MT)*64, n0 = blockIdx.x*64;
  int tid = threadIdx.x;
  int wave = tid >> 6, lane = tid & 63;
  int wr = (wave>>1)*32, wc = (wave&1)*32;
  f32x4 acc00 = {}, acc01 = {}, acc10 = {}, acc11 = {};
  int am = tid >> 2, ak = (tid & 3)*8;
  int bk = tid >> 3, bn = (tid & 7)*8;
  for (int kk0 = 0; kk0 < K; kk0 += 32){
    {
      bf16x8 av = *(const bf16x8*)(Atab + (size_t)(p0+am)*K + kk0 + ak);
      st8u(&As[am*40 + ak], av);
    }
    {
      int r = kk0 + bk;
      if (MODE==0){
        const float* src = (const float*)W1v + (size_t)slab*24576 + (size_t)r*128 + n0 + bn;
        float4 wa = *(const float4*)src;
        float4 wb = *(const float4*)(src+4);
        float v[8] = {wa.x,wa.y,wa.z,wa.w,wb.x,wb.y,wb.z,wb.w};
        #pragma unroll
        for (int j=0;j<8;j++) Bs[(bn+j)*40 + bk] = f2bf(v[j]);
      } else {
        const unsigned short* src;
        if (MODE==1) src = (r<192) ? (const unsigned short*)W1v + (size_t)(k0+slab)*128 + (size_t)r*12416
                                   : (const unsigned short*)W2v + (size_t)(k0+slab)*128 + (size_t)(r-192)*12416;
        else if (MODE==2) src = (r<192) ? (const unsigned short*)W1v + (size_t)slab*49152 + (size_t)r*256
                                        : (const unsigned short*)W2v + (size_t)slab*49152 + (size_t)(r-192)*256;
        else src = (r<112) ? (const unsigned short*)W1v + (size_t)slab*24832 + (size_t)r*256
                           : (const unsigned short*)W2v + (size_t)slab*24832 + (size_t)(r-112)*256;
        src += n0 + bn;
        bf16x8 wv = *(const bf16x8*)src;
        #pragma unroll
        for (int j=0;j<8;j++) Bs[(bn+j)*40 + bk] = (unsigned short)wv[j];
      }
    }
    __syncthreads();
    int fm = lane & 15, kg = (lane>>4)*8;
    bf16x8 a0 = *(const bf16x8*)&As[(wr+fm)*40 + kg];
    bf16x8 a1 = *(const bf16x8*)&As[(wr+16+fm)*40 + kg];
    bf16x8 b0 = *(const bf16x8*)&Bs[(wc+fm)*40 + kg];
    bf16x8 b1 = *(const bf16x8*)&Bs[(wc+16+fm)*40 + kg];
    acc00 = __builtin_amdgcn_mfma_f32_16x16x32_bf16(a0, b0, acc00, 0,0,0);
    acc01 = __builtin_amdgcn_mfma_f32_16x16x32_bf16(a0, b1, acc01, 0,0,0);
    acc10 = __builtin_amdgcn_mfma_f32_16x16x32_bf16(a1, b0, acc10, 0,0,0);
    acc11 = __builtin_amdgcn_mfma_f32_16x16x32_bf16(a1, b1, acc11, 0,0,0);
    __syncthreads();
  }
  int cn = lane & 15, rq = (lane>>4)*4;
  #pragma unroll
  for (int mi=0; mi<2; ++mi){
    #pragma unroll
    for (int ni=0; ni<2; ++ni){
      f32x4 a = (mi==0) ? (ni==0?acc00:acc01) : (ni==0?acc10:acc11);
      int n = n0 + wc + ni*16 + cn;
      #pragma unroll
      for (int r=0; r<4; ++r){
        int p = p0 + wr + mi*16 + rq + r;
        if (p >= MVALID) continue;
        float v = a[r];
        if (MODE==0){
          unsigned short* D1 = (unsigned short*)D1v;
          unsigned short* D2 = (unsigned short*)D2v;
          if (p < 97) D1[(size_t)slab*12416 + (size_t)p*128 + n] = f2bf(v);
          else        D2[(size_t)slab*12416 + (size_t)(p-97)*128 + n] = f2bf(v);
        } else if (MODE==1){
          unsigned short* base = (unsigned short*)D1v + (size_t)slab*49152;
          if (p < 192) base[(size_t)p*256 + n] = f2bf(v);
          else         base[(size_t)(p-192)*256 + 128 + n] = f2bf(v);
        } else if (MODE==2){
          unsigned short* D1 = (unsigned short*)D1v;
          int kg2 = k0 + slab;
          if (p < 192) D1[((size_t)p*97 + kg2)*256 + n] = f2bf(v);
          else         D1[((size_t)(p-192)*97 + kg2)*256 + 128 + n] = f2bf(v);
        } else {
          ((float*)D1v)[(size_t)slab*24576 + (size_t)p*128 + n] += v;
        }
      }
    }
  }
}

// ---------------- fused attention: LN + QKV proj (MFMA) + window attn ----------------
// block = window, 4 waves = 4 heads. shm union: X_s | per-wave {Qw,Kw}(P alias) | per-wave Vt
#define XS_OFF  0                      // [64][136]
#define WQK_OFF 8704                   // + wave*5120 : Qw [64][40], Kw at +2560; P alias [64][72]
#define VT_OFF  29184                  // + wave*2304 : Vt [32][72]
#define SHM_TOT 38400
__global__ __launch_bounds__(256) void attn_fused2(
    const float* __restrict__ XT, const float* __restrict__ stats,
    const float* __restrict__ g1, const float* __restrict__ b1,
    const unsigned short* __restrict__ QKVW, const float* __restrict__ QKVB,
    const float* __restrict__ biasT, unsigned short* __restrict__ OUTc){
  __shared__ __align__(16) unsigned short shm[SHM_TOT];
  int win = blockIdx.x;
  int b = win/576, rem = win%576, whi = rem/12, wwi = rem%12;
  int tid = threadIdx.x, wave = tid>>6, lane = tid&63, head = wave;
  int fm = lane & 15, kg = (lane>>4)*8;
  size_t rowbase = (size_t)(b*HGT + whi*4)*WID + wwi*16;
  // 1. load + LN -> X_s bf16 [token][136]
  {
    int t = tid >> 2;
    int c0 = (tid & 3)*32;
    size_t grow = rowbase + (size_t)(t>>4)*WID + (t&15);
    const float* src = XT + grow*C_DIM + c0;
    float m = stats[2*grow], rs = stats[2*grow+1];
    unsigned short* dst = &shm[XS_OFF + t*136 + c0];
    #pragma unroll
    for (int j=0;j<32;j++){
      float f = (src[j]-m)*rs*g1[c0+j] + b1[c0+j];
      dst[j] = f2bf(f);
    }
  }
  __syncthreads();
  // 2. Q, K, V for this head (B-frags straight from L2-resident QKVW)
  unsigned short* Qw = &shm[WQK_OFF + wave*5120];
  unsigned short* Kw = Qw + 2560;
  unsigned short* Vt = &shm[VT_OFF + wave*2304];
  #pragma unroll
  for (int op=0; op<3; ++op){
    f32x4 acc[4][2];
    #pragma unroll
    for (int tf=0; tf<4; ++tf){ acc[tf][0] = (f32x4){}; acc[tf][1] = (f32x4){}; }
    int wrow0 = op*128 + head*32;
    #pragma unroll
    for (int kk0=0; kk0<128; kk0+=32){
      bf16x8 bfr0 = *(const bf16x8*)(QKVW + (size_t)(wrow0 + fm)*128 + kk0 + kg);
      bf16x8 bfr1 = *(const bf16x8*)(QKVW + (size_t)(wrow0 + 16 + fm)*128 + kk0 + kg);
      #pragma unroll
      for (int tf=0; tf<4; ++tf){
        bf16x8 af = *(const bf16x8*)&shm[XS_OFF + (tf*16+fm)*136 + kk0 + kg];
        acc[tf][0] = __builtin_amdgcn_mfma_f32_16x16x32_bf16(af, bfr0, acc[tf][0], 0,0,0);
        acc[tf][1] = __builtin_amdgcn_mfma_f32_16x16x32_bf16(af, bfr1, acc[tf][1], 0,0,0);
      }
    }
    #pragma unroll
    for (int tf=0; tf<4; ++tf){
      #pragma unroll
      for (int cf=0; cf<2; ++cf){
        int n = cf*16 + fm;
        float bsv = QKVB[op*128 + head*32 + n];
        #pragma unroll
        for (int r=0;r<4;r++){
          int token = tf*16 + (lane>>4)*4 + r;
          float v = acc[tf][cf][r] + bsv;
          if (op==0) v *= 0.17677669529663688f;
          unsigned short bv = f2bf(v);
          if (op==0)      Qw[token*40 + n] = bv;
          else if (op==1) Kw[token*40 + n] = bv;
          else            Vt[n*72 + token] = bv;
        }
      }
    }
  }
  __syncthreads();   // safe point: all Q/K/V staged (also fences P-alias below)
  // 3. S = QK^T (K-dim = 32)
  bf16x8 qf[4], kf[4];
  #pragma unroll
  for (int t4=0; t4<4; ++t4){
    qf[t4] = *(const bf16x8*)&Qw[(t4*16+fm)*40 + kg];
    kf[t4] = *(const bf16x8*)&Kw[(t4*16+fm)*40 + kg];
  }
  f32x4 s[4][4];
  #pragma unroll
  for (int ni=0; ni<4; ++ni)
    #pragma unroll
    for (int mj=0; mj<4; ++mj){
      f32x4 z = {};
      s[ni][mj] = __builtin_amdgcn_mfma_f32_16x16x32_bf16(qf[ni], kf[mj], z, 0,0,0);
    }
  const float* bp = biasT + head*4096;
  #pragma unroll
  for (int ni=0; ni<4; ++ni){
    int nbase = ni*16 + (lane>>4)*4;
    #pragma unroll
    for (int mj=0; mj<4; ++mj){
      int m = mj*16 + fm;
      #pragma unroll
      for (int r=0;r<4;r++)
        s[ni][mj][r] += bp[(nbase+r)*64 + m];
    }
  }
  float rs_[4][4];
  #pragma unroll
  for (int ni=0; ni<4; ++ni){
    #pragma unroll
    for (int r=0;r<4;r++){
      float t = fmaxf(fmaxf(s[ni][0][r], s[ni][1][r]), fmaxf(s[ni][2][r], s[ni][3][r]));
      #pragma unroll
      for (int o=1;o<16;o<<=1) t = fmaxf(t, __shfl_xor(t, o, 64));
      float sum = 0.f;
      #pragma unroll
      for (int mj=0; mj<4; ++mj){
        float e = expf(s[ni][mj][r] - t);
        s[ni][mj][r] = e;
        sum += e;
      }
      #pragma unroll
      for (int o=1;o<16;o<<=1) sum += __shfl_xor(sum, o, 64);
      rs_[ni][r] = sum;
    }
  }
  __syncthreads();   // all waves done reading Qw/Kw before P overwrites the region
  // 4. P (bf16, unnormalized) aliases Qw/Kw region: [64][72]
  unsigned short* Ps = Qw;
  #pragma unroll
  for (int ni=0; ni<4; ++ni){
    int nbase = ni*16 + (lane>>4)*4;
    #pragma unroll
    for (int mj=0; mj<4; ++mj){
      int m = mj*16 + fm;
      #pragma unroll
      for (int r=0;r<4;r++)
        Ps[(nbase+r)*72 + m] = f2bf(s[ni][mj][r]);
    }
  }
  // 5. O = P·V
  f32x4 o2[4][2];
  #pragma unroll
  for (int ni=0; ni<4; ++ni){ o2[ni][0] = (f32x4){}; o2[ni][1] = (f32x4){}; }
  #pragma unroll
  for (int ks=0; ks<2; ++ks){
    bf16x8 vb0 = *(const bf16x8*)&Vt[fm*72 + ks*32+kg];
    bf16x8 vb1 = *(const bf16x8*)&Vt[(16+fm)*72 + ks*32+kg];
    #pragma unroll
    for (int ni=0; ni<4; ++ni){
      bf16x8 pa = *(const bf16x8*)&Ps[(ni*16+fm)*72 + ks*32+kg];
      o2[ni][0] = __builtin_amdgcn_mfma_f32_16x16x32_bf16(pa, vb0, o2[ni][0], 0,0,0);
      o2[ni][1] = __builtin_amdgcn_mfma_f32_16x16x32_bf16(pa, vb1, o2[ni][1], 0,0,0);
    }
  }
  #pragma unroll
  for (int ni=0; ni<4; ++ni){
    #pragma unroll
    for (int r=0;r<4;r++){
      size_t l = rowbase + (size_t)ni*WID + (lane>>4)*4 + r;
      float inv = 1.0f / rs_[ni][r];
      unsigned short* op = OUTc + l*C_DIM + head*32;
      op[fm]    = f2bf(o2[ni][0][r]*inv);
      op[16+fm] = f2bf(o2[ni][1][r]*inv);
    }
  }
}

// ---------------- LeFF dwconv strip (bf16 in/out) ----------------
__global__ __launch_bounds__(256) void dwconv_strip(const unsigned short* __restrict__ SB1,
                                                    const float* __restrict__ dw,
                                                    const float* __restrict__ db,
                                                    unsigned short* __restrict__ SB2,
                                                    int r0){
  int id = blockIdx.x*256 + threadIdx.x;
  int ch = id & 511; int t = id >> 9; int w = t % 192; int hl = t / 192;
  int h = r0 + hl;
  float acc = db[ch];
  #pragma unroll
  for (int ky=0; ky<3; ky++){
    int hh = h+ky-1;
    if (hh<0 || hh>=HGT) continue;
    int br = hl + ky;
    #pragma unroll
    for (int kx=0; kx<3; kx++){
      int ww = w+kx-1;
      if (ww<0 || ww>=WID) continue;
      acc += dw[ch*9+ky*3+kx]*bf2f(SB1[((size_t)br*WID + ww)*512 + ch]);
    }
  }
  SB2[id] = f2bf(gelu_f(acc));
}

// ---------------- per-batch BHWC -> BCHW transpose ----------------
__global__ __launch_bounds__(256) void transpose_b_kernel(const float* __restrict__ src, float* __restrict__ dst){
  __shared__ float tile[128*65];
  int w0 = blockIdx.x*64, h = blockIdx.y;
  int tid = threadIdx.x;
  for (int r=0; r<32; r++){
    int e = tid + 256*r; int c = e & 127, wl = e >> 7;
    tile[c*65 + wl] = src[((size_t)h*WID + w0 + wl)*C_DIM + c];
  }
  __syncthreads();
  for (int r=0; r<32; r++){
    int e = tid + 256*r; int wl = e & 63, c = e >> 6;
    dst[((size_t)c*HGT + h)*WID + w0 + wl] = tile[c*65 + wl];
  }
}

// ---------------- host ----------------
extern "C" void kernel_launch(void* const* d_in, const int* in_sizes, int n_in,
                              void* d_out, int out_size, void* d_ws, size_t ws_size,
                              hipStream_t stream) {
  const float* x      = (const float*)d_in[0];
  const float* pos_w  = (const float*)d_in[1];
  const float* pos_b  = (const float*)d_in[2];
  const float* ln1_g  = (const float*)d_in[3];
  const float* ln1_b  = (const float*)d_in[4];
  const float* q_w    = (const float*)d_in[5];
  const float* q_b    = (const float*)d_in[6];
  const float* kv_w   = (const float*)d_in[7];
  const float* kv_b   = (const float*)d_in[8];
  const float* rpb    = (const float*)d_in[9];
  const float* proj_w = (const float*)d_in[10];
  const float* proj_b = (const float*)d_in[11];
  const float* fft1_w = (const float*)d_in[12];
  const float* fft1_b = (const float*)d_in[13];
  const float* fft2_w = (const float*)d_in[14];
  const float* fft2_b = (const float*)d_in[15];
  const float* ln2_g  = (const float*)d_in[16];
  const float* ln2_b  = (const float*)d_in[17];
  const float* l1_w   = (const float*)d_in[18];
  const float* l1_b   = (const float*)d_in[19];
  const float* dw_w   = (const float*)d_in[20];
  const float* dw_b   = (const float*)d_in[21];
  const float* l2_w   = (const float*)d_in[22];
  const float* l2_b   = (const float*)d_in[23];

  const size_t S   = (size_t)NB*HGT*WID*C_DIM;   // 18,874,368
  const size_t Sb  = S/NB;                       //  4,718,592
  const size_t SZb = (size_t)HGT*WFD*C_DIM;      //  2,383,872 (u16 per spectrum half)
  const size_t GSZ = (size_t)HGT*WFD*256;        //  4,767,744 (u16)
  const int    P   = (int)(NB*HGT*WID);          // 147,456

  float* ws    = (float*)d_ws;
  float* TAB   = ws;
  float* STATS = ws + TAB_SZ;
  float* POOL  = ws + TAB_SZ + 2*(size_t)P;
  size_t head  = TAB_SZ + 2*(size_t)P;
  size_t pool  = (ws_size/4 > head) ? (ws_size/4 - head) : 0;

  // XT placement: POOL-resident if workspace allows (drops final memcpy), else d_out
  bool xt_in_pool = (pool >= S + 11000000);
  float* XT     = xt_in_pool ? POOL : (float*)d_out;
  float* POOL2  = xt_in_pool ? POOL + S : POOL;
  size_t pool2  = xt_in_pool ? pool - S : pool;

  const float* biasT = TAB + T_BIAS;
  const float* QKVB  = TAB + T_QKVB;
  const unsigned short* UT = (const unsigned short*)(TAB + TF_SZ);
  const unsigned short* MW  = UT + UT_MW;
  const unsigned short* MHF = UT + UT_MHF;
  const unsigned short* MHI = UT + UT_MHI;
  const unsigned short* MWI = UT + UT_MWI;
  const unsigned short* QKVW  = UT + UT_QKVW;
  const unsigned short* PROJW = UT + UT_PROJW;
  const unsigned short* FFT1W = UT + UT_FFT1W;
  const unsigned short* FFT2W = UT + UT_FFT2W;
  const unsigned short* L1W   = UT + UT_L1W;
  const unsigned short* L2W   = UT + UT_L2W;

  build_tables<<<2858, 256, 0, stream>>>(TAB, rpb, q_b, kv_b, q_w, kv_w, proj_w,
                                         fft1_w, fft2_w, l1_w, l2_w);
  posconv3_kernel<<<dim3(6,24,32), 256, 0, stream>>>(x, pos_w, pos_b, XT);

  // ---- attention: LN1 stats -> fused(LN+QKV+attn) -> proj (full P, no chunks) ----
  ln_stats_kernel<<<P/4, 256, 0, stream>>>(XT, STATS);
  {
    unsigned short* OUTu = (unsigned short*)POOL2;   // P*128 u16 = 9.44M floats
    attn_fused2<<<2304, 256, 0, stream>>>(XT, STATS, ln1_g, ln1_b, QKVW, QKVB, biasT, OUTu);
    gemm2<0,true,false,true,false,2><<<dim3(1, P/64), 256, 0, stream>>>(
        OUTu, PROJW, proj_b, XT, 128, 128, 128, nullptr, nullptr, nullptr, 0, 0);
  }

  // ---- FFT residual branch: all-MFMA, bf16 spectra, chunked over k ----
  {
    unsigned short* FRu = (unsigned short*)POOL2;
    unsigned short* FIu = FRu + SZb;
    unsigned short* Gu  = FIu + SZb;
    size_t fixed = SZb + GSZ/2;                  // floats used by FR+FI+G
    int CK = 1;
    if (pool2 > fixed + 49152) CK = (int)((pool2 - fixed)/49152);
    if (CK < 1) CK = 1;
    if (CK > WFD) CK = WFD;
    unsigned short* FF0u = (unsigned short*)(POOL2 + fixed);
    unsigned short* FF1u = FF0u + (size_t)CK*49152;
    for (int b = 0; b < NB; ++b){
      float* XTb = XT + (size_t)b*Sb;
      dft_gemm<0><<<dim3(2, 192*4), 256, 0, stream>>>(MW, XTb, nullptr, FRu, FIu, 0);
      for (int k0 = 0; k0 < WFD; k0 += CK){
        int ck = (WFD - k0 < CK) ? (WFD - k0) : CK;
        int rows = ck*192;
        dft_gemm<1><<<dim3(2, ck*6), 256, 0, stream>>>(MHF, FRu, FIu, FF0u, nullptr, k0);
        gemm2<1,false,false,true,true,4><<<dim3(1, rows/64), 256, 0, stream>>>(
            FF0u, FFT1W, fft1_b, FF1u, 256, 256, 256, nullptr, nullptr, nullptr, 0, 0);
        gemm2<0,false,false,true,true,4><<<dim3(1, rows/64), 256, 0, stream>>>(
            FF1u, FFT2W, fft2_b, FF0u, 256, 256, 256, nullptr, nullptr, nullptr, 0, 0);
        dft_gemm<2><<<dim3(2, ck*6), 256, 0, stream>>>(MHI, FF0u, FF0u+128, Gu, nullptr, k0);
      }
      dft_gemm<3><<<dim3(2, 192*3), 256, 0, stream>>>(MWI, Gu, Gu+128, XTb, nullptr, 0);
    }
  }

  // ---- LN2 stats ----
  ln_stats_kernel<<<P/4, 256, 0, stream>>>(XT, STATS);

  // ---- LeFF: strip-mined l1 gemm(NT=4) -> dwconv+gelu -> l2 gemm(NT=2, +residual) ----
  {
    int SH = 96;
    while ((size_t)(3*SH+4)*49152 > pool2 && SH > 24) SH >>= 1;
    const size_t SB1SZ = (size_t)(SH+2)*98304;   // u16
    unsigned short* SB1u[2] = { (unsigned short*)POOL2, (unsigned short*)POOL2 + SB1SZ };
    unsigned short* SB2u = (unsigned short*)POOL2 + 2*SB1SZ;
    int nStrips = HGT/SH;
    for (int b = 0; b < NB; ++b){
      auto launch_g = [&](int s){
        int r0 = s*SH;
        int prow0 = (b*HGT + r0 - 1)*WID;
        gemm2<2,false,true,false,true,4><<<dim3(2, (SH+2)*3), 256, 0, stream>>>(
            XT, L1W, l1_b, SB1u[s&1], 128, 512, 128,
            STATS, ln2_g, ln2_b, prow0, P-1);
      };
      launch_g(0);
      for (int s = 0; s < nStrips; ++s){
        if (s+1 < nStrips) launch_g(s+1);
        int r0 = s*SH;
        dwconv_strip<<<SH*384, 256, 0, stream>>>(SB1u[s&1], dw_w, dw_b, SB2u, r0);
        gemm2<0,true,false,true,false,2><<<dim3(1, SH*3), 256, 0, stream>>>(
            SB2u, L2W, l2_b, XT + ((size_t)(b*HGT + r0)*WID)*C_DIM,
            512, 128, 512, nullptr, nullptr, nullptr, 0, 0);
      }
    }
  }

  // ---- final transpose per batch ----
  if (xt_in_pool){
    for (int b = 0; b < NB; ++b)
      transpose_b_kernel<<<dim3(3,192), 256, 0, stream>>>(XT + (size_t)b*Sb,
                                                          (float*)d_out + (size_t)b*Sb);
  } else {
    for (int b = 0; b < NB; ++b){
      transpose_b_kernel<<<dim3(3,192), 256, 0, stream>>>(XT + (size_t)b*Sb, POOL2);
      hipMemcpyAsync((float*)d_out + (size_t)b*Sb, POOL2, Sb*sizeof(float),
                     hipMemcpyDeviceToDevice, stream);
    }
  }
}